// Round 1
// baseline (2432.679 us; speedup 1.0000x reference)
//
#include <hip/hip_runtime.h>

#define N_NODES 50000

// ---------------- utility kernels ----------------

__global__ void fill_zero_kernel(float* __restrict__ p, size_t n) {
    size_t i = (size_t)blockIdx.x * blockDim.x + threadIdx.x;
    size_t stride = (size_t)gridDim.x * blockDim.x;
    for (; i < n; i += stride) p[i] = 0.0f;
}

__global__ void copy_neg_kernel(float* __restrict__ o, const float* __restrict__ s, size_t n) {
    size_t i = (size_t)blockIdx.x * blockDim.x + threadIdx.x;
    size_t stride = (size_t)gridDim.x * blockDim.x;
    for (; i < n; i += stride) o[i] = -s[i];
}

// ---------------- edge preprocessing ----------------

__global__ void deg_kernel(const int* __restrict__ src, const int* __restrict__ dst,
                           float* __restrict__ deg, int E) {
    int e = blockIdx.x * blockDim.x + threadIdx.x;
    if (e < E) {
        int s = src[e], d = dst[e];
        if (s != d) atomicAdd(&deg[s], 1.0f);
    }
}

__global__ void dinv_kernel(float* __restrict__ deg, int n) {
    int i = blockIdx.x * blockDim.x + threadIdx.x;
    if (i < n) {
        float dg = deg[i];
        deg[i] = dg > 0.0f ? rsqrtf(dg) : 0.0f;
    }
}

__global__ void wnorm_kernel(const int* __restrict__ src, const int* __restrict__ dst,
                             const float* __restrict__ dinv, float* __restrict__ wn, int E) {
    int e = blockIdx.x * blockDim.x + threadIdx.x;
    if (e < E) {
        int s = src[e], d = dst[e];
        wn[e] = (s != d) ? (-dinv[s] * dinv[d]) : 0.0f;
    }
}

// ---------------- sparse propagation (scatter-atomic) ----------------
// out[dst] += alpha * w_norm[e] * h[src]   (diag term is 0 since lambda_max=2)

template<int D>
__global__ void prop_scatter_kernel(const float* __restrict__ h,
                                    const int* __restrict__ src, const int* __restrict__ dst,
                                    const float* __restrict__ wn,
                                    float* __restrict__ out, int E, float alpha) {
    int gtid = blockIdx.x * blockDim.x + threadIdx.x;
    int wave = gtid >> 6;
    int lane = threadIdx.x & 63;
    int nwaves = (gridDim.x * blockDim.x) >> 6;
    for (int e = wave; e < E; e += nwaves) {
        float w = wn[e];
        if (w == 0.0f) continue;
        w *= alpha;
        int s = src[e], d = dst[e];
        const float* hs = h + (size_t)s * D;
        float* od = out + (size_t)d * D;
#pragma unroll
        for (int k = 0; k < D / 64; ++k)
            atomicAdd(&od[lane + 64 * k], w * hs[lane + 64 * k]);
    }
}

// ---------------- fp32 tiled GEMM: C[r,c] (+)= sum_k A[r,k]*B[k,c] (+bias on first) ----

__global__ __launch_bounds__(256) void gemm64_kernel(const float* __restrict__ A,
                                                     const float* __restrict__ B,
                                                     const float* __restrict__ bias,
                                                     float* __restrict__ C,
                                                     int N, int K, int Dout, int first) {
    __shared__ float As[16][68];
    __shared__ float Bs[16][68];
    int bx = blockIdx.x;  // col tile
    int by = blockIdx.y;  // row tile
    int tid = threadIdx.x;
    int tx = tid & 15, ty = tid >> 4;
    int r0 = by * 64 + ty * 4;
    int c0 = bx * 64 + tx * 4;

    float acc[4][4];
#pragma unroll
    for (int i = 0; i < 4; ++i)
#pragma unroll
        for (int j = 0; j < 4; ++j) acc[i][j] = 0.0f;

    for (int k0 = 0; k0 < K; k0 += 16) {
        // A tile: 64 rows x 16 k  (store transposed)
        {
            int row = tid >> 2;           // 0..63
            int kq = (tid & 3) * 4;       // 0,4,8,12
            int gr = by * 64 + row;
            float4 v = make_float4(0.f, 0.f, 0.f, 0.f);
            if (gr < N) v = *reinterpret_cast<const float4*>(A + (size_t)gr * K + k0 + kq);
            As[kq + 0][row] = v.x;
            As[kq + 1][row] = v.y;
            As[kq + 2][row] = v.z;
            As[kq + 3][row] = v.w;
        }
        // B tile: 16 k x 64 cols
        {
            int kk = tid >> 4;            // 0..15
            int cq = (tid & 15) * 4;      // 0..60
            float4 v = *reinterpret_cast<const float4*>(B + (size_t)(k0 + kk) * Dout + bx * 64 + cq);
            *reinterpret_cast<float4*>(&Bs[kk][cq]) = v;
        }
        __syncthreads();
#pragma unroll
        for (int kk = 0; kk < 16; ++kk) {
            float a[4], b[4];
#pragma unroll
            for (int i = 0; i < 4; ++i) a[i] = As[kk][ty * 4 + i];
#pragma unroll
            for (int j = 0; j < 4; ++j) b[j] = Bs[kk][tx * 4 + j];
#pragma unroll
            for (int i = 0; i < 4; ++i)
#pragma unroll
                for (int j = 0; j < 4; ++j) acc[i][j] += a[i] * b[j];
        }
        __syncthreads();
    }

#pragma unroll
    for (int i = 0; i < 4; ++i) {
        int r = r0 + i;
        if (r < N) {
#pragma unroll
            for (int j = 0; j < 4; ++j) {
                int c = c0 + j;
                float v = acc[i][j];
                if (first) v += bias[c];
                else v += C[(size_t)r * Dout + c];
                C[(size_t)r * Dout + c] = v;
            }
        }
    }
}

// ---------------- LayerNorm + ReLU (in place, one block per row) ----------------

template<int D>
__global__ void ln_relu_kernel(float* __restrict__ H, const float* __restrict__ g,
                               const float* __restrict__ bt, int n) {
    constexpr int NW = D / 64;
    __shared__ float sred[NW];
    int row = blockIdx.x;
    int tid = threadIdx.x;
    float* hr = H + (size_t)row * D;
    float v = hr[tid];

    float s = v;
#pragma unroll
    for (int o = 32; o > 0; o >>= 1) s += __shfl_down(s, o);
    int wid = tid >> 6, lane = tid & 63;
    if (lane == 0) sred[wid] = s;
    __syncthreads();
    float tot = 0.0f;
#pragma unroll
    for (int w = 0; w < NW; ++w) tot += sred[w];
    float mu = tot * (1.0f / D);

    float dv = v - mu;
    float q = dv * dv;
    __syncthreads();
#pragma unroll
    for (int o = 32; o > 0; o >>= 1) q += __shfl_down(q, o);
    if (lane == 0) sred[wid] = q;
    __syncthreads();
    float tot2 = 0.0f;
#pragma unroll
    for (int w = 0; w < NW; ++w) tot2 += sred[w];
    float var = tot2 * (1.0f / D);

    float y = dv * rsqrtf(var + 1e-5f) * g[tid] + bt[tid];
    hr[tid] = y > 0.0f ? y : 0.0f;
}

// ---------------- host launch ----------------

static inline size_t align64(size_t x) { return (x + 63) & ~size_t(63); }

extern "C" void kernel_launch(void* const* d_in, const int* in_sizes, int n_in,
                              void* d_out, int out_size, void* d_ws, size_t ws_size,
                              hipStream_t stream) {
    const int N = N_NODES;
    const float* x  = (const float*)d_in[0];
    const int*  ei  = (const int*)d_in[1];
    const float* W1 = (const float*)d_in[2];
    const float* b1 = (const float*)d_in[3];
    const float* g1 = (const float*)d_in[4];
    const float* bt1 = (const float*)d_in[5];
    const float* W2 = (const float*)d_in[6];
    const float* b2 = (const float*)d_in[7];
    const float* g2 = (const float*)d_in[8];
    const float* bt2 = (const float*)d_in[9];
    float* out = (float*)d_out;

    const int E = in_sizes[1] / 2;
    const int* src = ei;
    const int* dst = ei + E;

    // workspace layout (floats)
    float* ws = (float*)d_ws;
    size_t off = 0;
    float* deg = ws + off; off += align64((size_t)N);           // deg -> dinv in place
    float* wn  = ws + off; off += align64((size_t)E);
    float* Tx1 = ws + off; off += align64((size_t)N * 128);
    float* Tx2 = ws + off; off += align64((size_t)N * 128);
    float* h1  = ws + off; off += align64((size_t)N * 256);
    float* T1b = ws + off; off += align64((size_t)N * 256);
    float* T2b = ws + off; off += align64((size_t)N * 256);
    (void)ws_size;

    const int TPB = 256;
    const int gridE = (E + TPB - 1) / TPB;
    const int gridN = (N + TPB - 1) / TPB;

    // --- edge norm ---
    hipLaunchKernelGGL(fill_zero_kernel, dim3(256), dim3(TPB), 0, stream, deg, (size_t)N);
    hipLaunchKernelGGL(deg_kernel, dim3(gridE), dim3(TPB), 0, stream, src, dst, deg, E);
    hipLaunchKernelGGL(dinv_kernel, dim3(gridN), dim3(TPB), 0, stream, deg, N);
    hipLaunchKernelGGL(wnorm_kernel, dim3(gridE), dim3(TPB), 0, stream, src, dst, deg, wn, E);

    // --- layer 1 (D=128 -> 256) ---
    hipLaunchKernelGGL(fill_zero_kernel, dim3(2048), dim3(TPB), 0, stream, Tx1, (size_t)N * 128);
    hipLaunchKernelGGL((prop_scatter_kernel<128>), dim3(2048), dim3(TPB), 0, stream,
                       x, src, dst, wn, Tx1, E, 1.0f);
    hipLaunchKernelGGL(copy_neg_kernel, dim3(2048), dim3(TPB), 0, stream, Tx2, x, (size_t)N * 128);
    hipLaunchKernelGGL((prop_scatter_kernel<128>), dim3(2048), dim3(TPB), 0, stream,
                       Tx1, src, dst, wn, Tx2, E, 2.0f);

    dim3 g1d(256 / 64, (N + 63) / 64);
    hipLaunchKernelGGL(gemm64_kernel, g1d, dim3(256), 0, stream, x,   W1 + 0 * 128 * 256, b1, h1, N, 128, 256, 1);
    hipLaunchKernelGGL(gemm64_kernel, g1d, dim3(256), 0, stream, Tx1, W1 + 1 * 128 * 256, b1, h1, N, 128, 256, 0);
    hipLaunchKernelGGL(gemm64_kernel, g1d, dim3(256), 0, stream, Tx2, W1 + 2 * 128 * 256, b1, h1, N, 128, 256, 0);
    hipLaunchKernelGGL((ln_relu_kernel<256>), dim3(N), dim3(256), 0, stream, h1, g1, bt1, N);

    // --- layer 2 (D=256 -> 128) ---
    hipLaunchKernelGGL(fill_zero_kernel, dim3(2048), dim3(TPB), 0, stream, T1b, (size_t)N * 256);
    hipLaunchKernelGGL((prop_scatter_kernel<256>), dim3(2048), dim3(TPB), 0, stream,
                       h1, src, dst, wn, T1b, E, 1.0f);
    hipLaunchKernelGGL(copy_neg_kernel, dim3(2048), dim3(TPB), 0, stream, T2b, h1, (size_t)N * 256);
    hipLaunchKernelGGL((prop_scatter_kernel<256>), dim3(2048), dim3(TPB), 0, stream,
                       T1b, src, dst, wn, T2b, E, 2.0f);

    dim3 g2d(128 / 64, (N + 63) / 64);
    hipLaunchKernelGGL(gemm64_kernel, g2d, dim3(256), 0, stream, h1,  W2 + 0 * 256 * 128, b2, out, N, 256, 128, 1);
    hipLaunchKernelGGL(gemm64_kernel, g2d, dim3(256), 0, stream, T1b, W2 + 1 * 256 * 128, b2, out, N, 256, 128, 0);
    hipLaunchKernelGGL(gemm64_kernel, g2d, dim3(256), 0, stream, T2b, W2 + 2 * 256 * 128, b2, out, N, 256, 128, 0);
    hipLaunchKernelGGL((ln_relu_kernel<128>), dim3(N), dim3(128), 0, stream, out, g2, bt2, N);
}

// Round 2
// 883.353 us; speedup vs baseline: 2.7539x; 2.7539x over previous
//
#include <hip/hip_runtime.h>

#define N_NODES 50000

// ---------------- utility kernels ----------------

__global__ void fill_zero_int_kernel(int* __restrict__ p, size_t n) {
    size_t i = (size_t)blockIdx.x * blockDim.x + threadIdx.x;
    size_t stride = (size_t)gridDim.x * blockDim.x;
    for (; i < n; i += stride) p[i] = 0;
}

// ---------------- edge preprocessing: histograms ----------------

__global__ void hist_kernel(const int* __restrict__ src, const int* __restrict__ dst,
                            int* __restrict__ degi, int* __restrict__ cnt, int E) {
    int e = blockIdx.x * blockDim.x + threadIdx.x;
    if (e < E) {
        int s = src[e], d = dst[e];
        if (s != d) {
            atomicAdd(&degi[s], 1);   // degree by src (for sym norm)
            atomicAdd(&cnt[d], 1);    // bucket count by dst (for CSR)
        }
    }
}

__global__ void dinv_kernel(const int* __restrict__ degi, float* __restrict__ dinv, int n) {
    int i = blockIdx.x * blockDim.x + threadIdx.x;
    if (i < n) {
        int dg = degi[i];
        dinv[i] = dg > 0 ? rsqrtf((float)dg) : 0.0f;
    }
}

// single-block exclusive scan of cnt[0..n) -> rowptr[0..n], also copies to cursor
__global__ __launch_bounds__(1024) void scan_kernel(const int* __restrict__ cnt,
                                                    int* __restrict__ rowptr,
                                                    int* __restrict__ cursor, int n) {
    __shared__ int wsum[16];
    __shared__ int running;
    int tid = threadIdx.x, lane = tid & 63, wid = tid >> 6;
    if (tid == 0) running = 0;
    __syncthreads();
    for (int start = 0; start < n; start += 1024) {
        int i = start + tid;
        int v = (i < n) ? cnt[i] : 0;
        int x = v;
#pragma unroll
        for (int o = 1; o < 64; o <<= 1) { int y = __shfl_up(x, o); if (lane >= o) x += y; }
        if (lane == 63) wsum[wid] = x;
        __syncthreads();
        if (tid < 16) {
            int s = wsum[tid];
#pragma unroll
            for (int o = 1; o < 16; o <<= 1) { int y = __shfl_up(s, o); if (tid >= o) s += y; }
            wsum[tid] = s;
        }
        __syncthreads();
        int base = running + (wid > 0 ? wsum[wid - 1] : 0);
        if (i < n) { int e = base + x - v; rowptr[i] = e; cursor[i] = e; }
        __syncthreads();
        if (tid == 0) running += wsum[15];
        __syncthreads();
    }
    if (threadIdx.x == 0) rowptr[n] = running;
}

__global__ void csr_build_kernel(const int* __restrict__ src, const int* __restrict__ dst,
                                 const float* __restrict__ dinv, int* __restrict__ cursor,
                                 int* __restrict__ csr_src, float* __restrict__ csr_w, int E) {
    int e = blockIdx.x * blockDim.x + threadIdx.x;
    if (e < E) {
        int s = src[e], d = dst[e];
        if (s != d) {
            int pos = atomicAdd(&cursor[d], 1);
            csr_src[pos] = s;
            csr_w[pos] = -dinv[s] * dinv[d];
        }
    }
}

// ---------------- sparse propagation (CSR gather, one wave per node) ----------------
// out[d] = scale * sum_{e in CSR[d]} w_e * h[src_e]   ( - sub[d] if sub != null )

template<int D>
__global__ void prop_gather_kernel(const float* __restrict__ h,
                                   const int* __restrict__ rowptr,
                                   const int* __restrict__ csr_src,
                                   const float* __restrict__ csr_w,
                                   const float* __restrict__ sub,
                                   float* __restrict__ out, int n, float scale) {
    constexpr int V = D / 64;
    int wib = threadIdx.x >> 6;
    int lane = threadIdx.x & 63;
    int node = blockIdx.x * (blockDim.x >> 6) + wib;
    if (node >= n) return;

    float acc[V];
#pragma unroll
    for (int k = 0; k < V; ++k) acc[k] = 0.0f;

    int beg = rowptr[node], end = rowptr[node + 1];
    int i = beg;
    for (; i + 2 <= end; i += 2) {
        int s0 = csr_src[i], s1 = csr_src[i + 1];
        float w0 = csr_w[i], w1 = csr_w[i + 1];
        const float* h0 = h + (size_t)s0 * D;
        const float* h1p = h + (size_t)s1 * D;
#pragma unroll
        for (int k = 0; k < V; ++k) {
            acc[k] += w0 * h0[lane + 64 * k];
            acc[k] += w1 * h1p[lane + 64 * k];
        }
    }
    if (i < end) {
        int s0 = csr_src[i];
        float w0 = csr_w[i];
        const float* h0 = h + (size_t)s0 * D;
#pragma unroll
        for (int k = 0; k < V; ++k) acc[k] += w0 * h0[lane + 64 * k];
    }

    float* od = out + (size_t)node * D;
    if (sub) {
        const float* sd = sub + (size_t)node * D;
#pragma unroll
        for (int k = 0; k < V; ++k) od[lane + 64 * k] = scale * acc[k] - sd[lane + 64 * k];
    } else {
#pragma unroll
        for (int k = 0; k < V; ++k) od[lane + 64 * k] = scale * acc[k];
    }
}

// ---------------- fused fp32 GEMM: C = [A0|A1|A2] @ B(3K x Dout) + bias ----------------

__global__ __launch_bounds__(256) void gemm3_kernel(const float* __restrict__ A0,
                                                    const float* __restrict__ A1,
                                                    const float* __restrict__ A2,
                                                    const float* __restrict__ B,
                                                    const float* __restrict__ bias,
                                                    float* __restrict__ C,
                                                    int N, int K, int Dout) {
    __shared__ float As[16][68];
    __shared__ float Bs[16][68];
    int bx = blockIdx.x;  // col tile
    int by = blockIdx.y;  // row tile
    int tid = threadIdx.x;
    int tx = tid & 15, ty = tid >> 4;
    int r0 = by * 64 + ty * 4;
    int c0 = bx * 64 + tx * 4;

    float acc[4][4];
#pragma unroll
    for (int i = 0; i < 4; ++i)
#pragma unroll
        for (int j = 0; j < 4; ++j) acc[i][j] = 0.0f;

    const float* Aptr = A0;
    int seg = 0, kloc = 0;
    for (int kg = 0; kg < 3 * K; kg += 16) {
        // A tile: 64 rows x 16 k (store transposed)
        {
            int row = tid >> 2;
            int kq = (tid & 3) * 4;
            int gr = by * 64 + row;
            float4 v = make_float4(0.f, 0.f, 0.f, 0.f);
            if (gr < N) v = *reinterpret_cast<const float4*>(Aptr + (size_t)gr * K + kloc + kq);
            As[kq + 0][row] = v.x;
            As[kq + 1][row] = v.y;
            As[kq + 2][row] = v.z;
            As[kq + 3][row] = v.w;
        }
        // B tile: 16 k x 64 cols (B rows are global kg index, contiguous across segments)
        {
            int kk = tid >> 4;
            int cq = (tid & 15) * 4;
            float4 v = *reinterpret_cast<const float4*>(B + (size_t)(kg + kk) * Dout + bx * 64 + cq);
            *reinterpret_cast<float4*>(&Bs[kk][cq]) = v;
        }
        __syncthreads();
#pragma unroll
        for (int kk = 0; kk < 16; ++kk) {
            float a[4], b[4];
#pragma unroll
            for (int i = 0; i < 4; ++i) a[i] = As[kk][ty * 4 + i];
#pragma unroll
            for (int j = 0; j < 4; ++j) b[j] = Bs[kk][tx * 4 + j];
#pragma unroll
            for (int i = 0; i < 4; ++i)
#pragma unroll
                for (int j = 0; j < 4; ++j) acc[i][j] += a[i] * b[j];
        }
        __syncthreads();
        kloc += 16;
        if (kloc == K) { kloc = 0; ++seg; Aptr = (seg == 1) ? A1 : A2; }
    }

#pragma unroll
    for (int i = 0; i < 4; ++i) {
        int r = r0 + i;
        if (r < N) {
#pragma unroll
            for (int j = 0; j < 4; ++j) {
                int c = c0 + j;
                C[(size_t)r * Dout + c] = acc[i][j] + bias[c];
            }
        }
    }
}

// ---------------- LayerNorm + ReLU (in place, one block per row) ----------------

template<int D>
__global__ void ln_relu_kernel(float* __restrict__ H, const float* __restrict__ g,
                               const float* __restrict__ bt, int n) {
    constexpr int NW = D / 64;
    __shared__ float sred[NW];
    int row = blockIdx.x;
    int tid = threadIdx.x;
    float* hr = H + (size_t)row * D;
    float v = hr[tid];

    float s = v;
#pragma unroll
    for (int o = 32; o > 0; o >>= 1) s += __shfl_down(s, o);
    int wid = tid >> 6, lane = tid & 63;
    if (lane == 0) sred[wid] = s;
    __syncthreads();
    float tot = 0.0f;
#pragma unroll
    for (int w = 0; w < NW; ++w) tot += sred[w];
    float mu = tot * (1.0f / D);

    float dv = v - mu;
    float q = dv * dv;
    __syncthreads();
#pragma unroll
    for (int o = 32; o > 0; o >>= 1) q += __shfl_down(q, o);
    if (lane == 0) sred[wid] = q;
    __syncthreads();
    float tot2 = 0.0f;
#pragma unroll
    for (int w = 0; w < NW; ++w) tot2 += sred[w];
    float var = tot2 * (1.0f / D);

    float y = dv * rsqrtf(var + 1e-5f) * g[tid] + bt[tid];
    hr[tid] = y > 0.0f ? y : 0.0f;
}

// ---------------- host launch ----------------

static inline size_t align64(size_t x) { return (x + 63) & ~size_t(63); }

extern "C" void kernel_launch(void* const* d_in, const int* in_sizes, int n_in,
                              void* d_out, int out_size, void* d_ws, size_t ws_size,
                              hipStream_t stream) {
    const int N = N_NODES;
    const float* x  = (const float*)d_in[0];
    const int*  ei  = (const int*)d_in[1];
    const float* W1 = (const float*)d_in[2];
    const float* b1 = (const float*)d_in[3];
    const float* g1 = (const float*)d_in[4];
    const float* bt1 = (const float*)d_in[5];
    const float* W2 = (const float*)d_in[6];
    const float* b2 = (const float*)d_in[7];
    const float* g2 = (const float*)d_in[8];
    const float* bt2 = (const float*)d_in[9];
    float* out = (float*)d_out;

    const int E = in_sizes[1] / 2;
    const int* src = ei;
    const int* dst = ei + E;

    // workspace layout
    // int region: degi(N) cnt(N) rowptr(N+1) cursor(N) csr_src(E)
    int* ip = (int*)d_ws;
    int* degi    = ip;
    int* cnt     = degi + N;
    int* rowptr  = cnt + N;
    int* cursor  = rowptr + N + 1;
    int* csr_src = cursor + N;
    size_t int_elems = align64((size_t)4 * N + 1 + (size_t)E);
    // float region
    float* fp = (float*)d_ws + int_elems;
    size_t off = 0;
    float* dinv  = fp + off; off += align64((size_t)N);
    float* csr_w = fp + off; off += align64((size_t)E);
    float* Tx1 = fp + off; off += align64((size_t)N * 128);
    float* Tx2 = fp + off; off += align64((size_t)N * 128);
    float* h1  = fp + off; off += align64((size_t)N * 256);
    float* T1b = fp + off; off += align64((size_t)N * 256);
    float* T2b = fp + off; off += align64((size_t)N * 256);
    (void)ws_size;

    const int TPB = 256;
    const int gridE = (E + TPB - 1) / TPB;
    const int gridN = (N + TPB - 1) / TPB;

    // --- build normalization + CSR (bucketed by dst) ---
    hipLaunchKernelGGL(fill_zero_int_kernel, dim3(256), dim3(TPB), 0, stream, degi, (size_t)2 * N);
    hipLaunchKernelGGL(hist_kernel, dim3(gridE), dim3(TPB), 0, stream, src, dst, degi, cnt, E);
    hipLaunchKernelGGL(dinv_kernel, dim3(gridN), dim3(TPB), 0, stream, degi, dinv, N);
    hipLaunchKernelGGL(scan_kernel, dim3(1), dim3(1024), 0, stream, cnt, rowptr, cursor, N);
    hipLaunchKernelGGL(csr_build_kernel, dim3(gridE), dim3(TPB), 0, stream,
                       src, dst, dinv, cursor, csr_src, csr_w, E);

    const int gridW = (N + 3) / 4;  // 4 waves (nodes) per 256-thread block

    // --- layer 1 (D=128 -> 256) ---
    hipLaunchKernelGGL((prop_gather_kernel<128>), dim3(gridW), dim3(TPB), 0, stream,
                       x, rowptr, csr_src, csr_w, (const float*)nullptr, Tx1, N, 1.0f);
    hipLaunchKernelGGL((prop_gather_kernel<128>), dim3(gridW), dim3(TPB), 0, stream,
                       Tx1, rowptr, csr_src, csr_w, x, Tx2, N, 2.0f);

    dim3 g1d(256 / 64, (N + 63) / 64);
    hipLaunchKernelGGL(gemm3_kernel, g1d, dim3(256), 0, stream, x, Tx1, Tx2, W1, b1, h1, N, 128, 256);
    hipLaunchKernelGGL((ln_relu_kernel<256>), dim3(N), dim3(256), 0, stream, h1, g1, bt1, N);

    // --- layer 2 (D=256 -> 128) ---
    hipLaunchKernelGGL((prop_gather_kernel<256>), dim3(gridW), dim3(TPB), 0, stream,
                       h1, rowptr, csr_src, csr_w, (const float*)nullptr, T1b, N, 1.0f);
    hipLaunchKernelGGL((prop_gather_kernel<256>), dim3(gridW), dim3(TPB), 0, stream,
                       T1b, rowptr, csr_src, csr_w, h1, T2b, N, 2.0f);

    dim3 g2d(128 / 64, (N + 63) / 64);
    hipLaunchKernelGGL(gemm3_kernel, g2d, dim3(256), 0, stream, h1, T1b, T2b, W2, b2, out, N, 256, 128);
    hipLaunchKernelGGL((ln_relu_kernel<128>), dim3(N), dim3(128), 0, stream, out, g2, bt2, N);
}

// Round 4
// 542.602 us; speedup vs baseline: 4.4834x; 1.6280x over previous
//
#include <hip/hip_runtime.h>

#define N_NODES 50000

using f32x4  = __attribute__((ext_vector_type(4))) float;
using bf16x8 = __attribute__((ext_vector_type(8))) __bf16;

__device__ __forceinline__ unsigned short f2bf(float f) {
    unsigned int b = __float_as_uint(f);
    unsigned int r = (b + 0x7FFFu + ((b >> 16) & 1u)) >> 16;   // RNE
    return (unsigned short)r;
}
__device__ __forceinline__ float bf_lo(unsigned int u) { return __uint_as_float(u << 16); }
__device__ __forceinline__ float bf_hi(unsigned int u) { return __uint_as_float(u & 0xFFFF0000u); }

// ---------------- utility ----------------

__global__ void fill_zero_int_kernel(int* __restrict__ p, size_t n) {
    size_t i = (size_t)blockIdx.x * blockDim.x + threadIdx.x;
    size_t stride = (size_t)gridDim.x * blockDim.x;
    for (; i < n; i += stride) p[i] = 0;
}

__global__ void cvt_bf_kernel(const float* __restrict__ in, unsigned short* __restrict__ out, size_t n4) {
    size_t i = (size_t)blockIdx.x * blockDim.x + threadIdx.x;
    if (i < n4) {
        float4 v = *reinterpret_cast<const float4*>(in + i * 4);
        ushort4 o;
        o.x = f2bf(v.x); o.y = f2bf(v.y); o.z = f2bf(v.z); o.w = f2bf(v.w);
        *reinterpret_cast<ushort4*>(out + i * 4) = o;
    }
}

// W: [3][KSEG][Dout] f32 -> Bt: [Dout][3*KSEG] bf16
__global__ void wtrans_kernel(const float* __restrict__ W, unsigned short* __restrict__ Bt,
                              int KSEG, int Dout) {
    int i = blockIdx.x * blockDim.x + threadIdx.x;
    int tot = 3 * KSEG * Dout;
    if (i < tot) {
        int c = i % Dout;
        int kg = i / Dout;
        Bt[(size_t)c * (3 * KSEG) + kg] = f2bf(W[(size_t)kg * Dout + c]);
    }
}

// ---------------- edge preprocessing ----------------

__global__ void hist_kernel(const int* __restrict__ src, const int* __restrict__ dst,
                            int* __restrict__ degi, int* __restrict__ cnt, int E) {
    int e = blockIdx.x * blockDim.x + threadIdx.x;
    if (e < E) {
        int s = src[e], d = dst[e];
        if (s != d) {
            atomicAdd(&degi[s], 1);
            atomicAdd(&cnt[d], 1);
        }
    }
}

__global__ void dinv_kernel(const int* __restrict__ degi, float* __restrict__ dinv, int n) {
    int i = blockIdx.x * blockDim.x + threadIdx.x;
    if (i < n) {
        int dg = degi[i];
        dinv[i] = dg > 0 ? rsqrtf((float)dg) : 0.0f;
    }
}

__global__ __launch_bounds__(1024) void scan_kernel(const int* __restrict__ cnt,
                                                    int* __restrict__ rowptr,
                                                    int* __restrict__ cursor, int n) {
    __shared__ int wsum[16];
    __shared__ int running;
    int tid = threadIdx.x, lane = tid & 63, wid = tid >> 6;
    if (tid == 0) running = 0;
    __syncthreads();
    for (int start = 0; start < n; start += 1024) {
        int i = start + tid;
        int v = (i < n) ? cnt[i] : 0;
        int x = v;
#pragma unroll
        for (int o = 1; o < 64; o <<= 1) { int y = __shfl_up(x, o); if (lane >= o) x += y; }
        if (lane == 63) wsum[wid] = x;
        __syncthreads();
        if (tid < 16) {
            int s = wsum[tid];
#pragma unroll
            for (int o = 1; o < 16; o <<= 1) { int y = __shfl_up(s, o); if (tid >= o) s += y; }
            wsum[tid] = s;
        }
        __syncthreads();
        int base = running + (wid > 0 ? wsum[wid - 1] : 0);
        if (i < n) { int e = base + x - v; rowptr[i] = e; cursor[i] = e; }
        __syncthreads();
        if (tid == 0) running += wsum[15];
        __syncthreads();
    }
    if (threadIdx.x == 0) rowptr[n] = running;
}

__global__ void csr_build_kernel(const int* __restrict__ src, const int* __restrict__ dst,
                                 const float* __restrict__ dinv, int* __restrict__ cursor,
                                 int* __restrict__ csr_src, float* __restrict__ csr_w, int E) {
    int e = blockIdx.x * blockDim.x + threadIdx.x;
    if (e < E) {
        int s = src[e], d = dst[e];
        if (s != d) {
            int pos = atomicAdd(&cursor[d], 1);
            csr_src[pos] = s;
            csr_w[pos] = -dinv[s] * dinv[d];
        }
    }
}

// ---------------- CSR gather propagation, bf16 in/out, f32 accum ----------------
// out[d] = scale * sum_e w_e * h[src_e]  (- sub[d] if sub)

template<int D>
__global__ void prop_gather_bf_kernel(const unsigned short* __restrict__ h,
                                      const int* __restrict__ rowptr,
                                      const int* __restrict__ csr_src,
                                      const float* __restrict__ csr_w,
                                      const unsigned short* __restrict__ sub,
                                      unsigned short* __restrict__ out, int n, float scale) {
    constexpr int V = D / 128;   // uints per lane
    int wib = threadIdx.x >> 6;
    int lane = threadIdx.x & 63;
    int node = blockIdx.x * (blockDim.x >> 6) + wib;
    if (node >= n) return;

    float ax[V], ay[V];
#pragma unroll
    for (int k = 0; k < V; ++k) { ax[k] = 0.0f; ay[k] = 0.0f; }

    const unsigned int* H = (const unsigned int*)h;
    int beg = rowptr[node], end = rowptr[node + 1];
    int i = beg;
    for (; i + 2 <= end; i += 2) {
        int s0 = csr_src[i], s1 = csr_src[i + 1];
        float w0 = csr_w[i], w1 = csr_w[i + 1];
        const unsigned int* p0 = H + (size_t)s0 * (D / 2) + lane;
        const unsigned int* p1 = H + (size_t)s1 * (D / 2) + lane;
#pragma unroll
        for (int k = 0; k < V; ++k) {
            unsigned int u0 = p0[k * 64], u1 = p1[k * 64];
            ax[k] += w0 * bf_lo(u0) + w1 * bf_lo(u1);
            ay[k] += w0 * bf_hi(u0) + w1 * bf_hi(u1);
        }
    }
    if (i < end) {
        int s0 = csr_src[i];
        float w0 = csr_w[i];
        const unsigned int* p0 = H + (size_t)s0 * (D / 2) + lane;
#pragma unroll
        for (int k = 0; k < V; ++k) {
            unsigned int u0 = p0[k * 64];
            ax[k] += w0 * bf_lo(u0);
            ay[k] += w0 * bf_hi(u0);
        }
    }

    unsigned int* O = (unsigned int*)out + (size_t)node * (D / 2) + lane;
    if (sub) {
        const unsigned int* S = (const unsigned int*)sub + (size_t)node * (D / 2) + lane;
#pragma unroll
        for (int k = 0; k < V; ++k) {
            unsigned int su = S[k * 64];
            float vx = scale * ax[k] - bf_lo(su);
            float vy = scale * ay[k] - bf_hi(su);
            O[k * 64] = ((unsigned int)f2bf(vy) << 16) | f2bf(vx);
        }
    } else {
#pragma unroll
        for (int k = 0; k < V; ++k) {
            float vx = scale * ax[k];
            float vy = scale * ay[k];
            O[k * 64] = ((unsigned int)f2bf(vy) << 16) | f2bf(vx);
        }
    }
}

// ---------------- bf16 MFMA GEMM: C = [A0|A1|A2] @ Bt^T + bias ----------------
// A*: [N][KSEG] bf16.  Bt: [Dout][3*KSEG] bf16.  C: [N][Dout] f32.
// Block: 256 thr = 4 waves (2x2). Tile: BM=128 x BN=64, BK=32. Wave: 64x32.

template<int KSEG>
__global__ __launch_bounds__(256) void gemm3_mfma_kernel(
        const unsigned short* __restrict__ A0, const unsigned short* __restrict__ A1,
        const unsigned short* __restrict__ A2, const unsigned short* __restrict__ Bt,
        const float* __restrict__ bias, float* __restrict__ C,
        int N, int Dout, int ncol) {
    constexpr int BM = 128, BN = 64, BK = 32;
    constexpr int Ktot = 3 * KSEG;
    __shared__ __align__(16) unsigned short As[BM][BK];
    __shared__ __align__(16) unsigned short Bs[BN][BK];

    // bijective XCD swizzle (8 XCDs)
    int nwg = gridDim.x;
    int q = nwg >> 3, r = nwg & 7;
    int xcd = blockIdx.x & 7, idx = blockIdx.x >> 3;
    int wgid = (xcd < r ? xcd * (q + 1) : r * (q + 1) + (xcd - r) * q) + idx;

    int row0 = (wgid / ncol) * BM;
    int col0 = (wgid % ncol) * BN;

    int tid = threadIdx.x;
    int lane = tid & 63;
    int wave = tid >> 6;
    int wr = (wave >> 1) * 64;   // wave row offset
    int wc = (wave & 1) * 32;    // wave col offset

    f32x4 acc[4][2];
#pragma unroll
    for (int i = 0; i < 4; ++i)
#pragma unroll
        for (int j = 0; j < 2; ++j) acc[i][j] = (f32x4)0.0f;

    int srow = tid >> 2;           // 0..63
    int sch = (tid & 3) * 8;       // bf16 element offset within 32

    for (int ks = 0; ks < Ktot / BK; ++ks) {
        int kg = ks * BK;
        int seg = kg / KSEG;
        int kk = kg - seg * KSEG;
        const unsigned short* Aseg = (seg == 0) ? A0 : (seg == 1 ? A1 : A2);
#pragma unroll
        for (int p = 0; p < 2; ++p) {
            int rr = srow + p * 64;
            int gr = row0 + rr;
            uint4 v = make_uint4(0u, 0u, 0u, 0u);
            if (gr < N) v = *reinterpret_cast<const uint4*>(Aseg + (size_t)gr * KSEG + kk + sch);
            *reinterpret_cast<uint4*>(&As[rr][sch]) = v;
        }
        {
            int gc = col0 + srow;  // Dout multiple of 64 -> in range
            uint4 v = *reinterpret_cast<const uint4*>(Bt + (size_t)gc * Ktot + kg + sch);
            *reinterpret_cast<uint4*>(&Bs[srow][sch]) = v;
        }
        __syncthreads();

        int fr = lane & 15;
        int kh = (lane >> 4) * 8;
        bf16x8 af[4], bfj[2];
#pragma unroll
        for (int i = 0; i < 4; ++i)
            af[i] = *reinterpret_cast<const bf16x8*>(&As[wr + i * 16 + fr][kh]);
#pragma unroll
        for (int j = 0; j < 2; ++j)
            bfj[j] = *reinterpret_cast<const bf16x8*>(&Bs[wc + j * 16 + fr][kh]);
#pragma unroll
        for (int i = 0; i < 4; ++i)
#pragma unroll
            for (int j = 0; j < 2; ++j)
                acc[i][j] = __builtin_amdgcn_mfma_f32_16x16x32_bf16(af[i], bfj[j], acc[i][j], 0, 0, 0);
        __syncthreads();
    }

    // epilogue: C/D layout col = lane&15, row = (lane>>4)*4 + reg
    int fc = lane & 15;
    int frr = (lane >> 4) * 4;
#pragma unroll
    for (int j = 0; j < 2; ++j) {
        int gc = col0 + wc + j * 16 + fc;
        float bv = bias[gc];
#pragma unroll
        for (int i = 0; i < 4; ++i) {
#pragma unroll
            for (int v = 0; v < 4; ++v) {
                int gr = row0 + wr + i * 16 + frr + v;
                if (gr < N) C[(size_t)gr * Dout + gc] = acc[i][j][v] + bv;
            }
        }
    }
}

// ---------------- LayerNorm + ReLU (f32 in, f32 or bf16 out) ----------------

template<int D, typename OUT>
__global__ void ln_relu_kernel(const float* __restrict__ H, OUT* __restrict__ O,
                               const float* __restrict__ g, const float* __restrict__ bt, int n) {
    constexpr int NW = D / 64;
    __shared__ float sred[NW];
    int row = blockIdx.x;
    int tid = threadIdx.x;
    const float* hr = H + (size_t)row * D;
    float v = hr[tid];

    float s = v;
#pragma unroll
    for (int o = 32; o > 0; o >>= 1) s += __shfl_down(s, o);
    int wid = tid >> 6, lane = tid & 63;
    if (lane == 0) sred[wid] = s;
    __syncthreads();
    float tot = 0.0f;
#pragma unroll
    for (int w = 0; w < NW; ++w) tot += sred[w];
    float mu = tot * (1.0f / D);

    float dv = v - mu;
    float qv = dv * dv;
    __syncthreads();
#pragma unroll
    for (int o = 32; o > 0; o >>= 1) qv += __shfl_down(qv, o);
    if (lane == 0) sred[wid] = qv;
    __syncthreads();
    float tot2 = 0.0f;
#pragma unroll
    for (int w = 0; w < NW; ++w) tot2 += sred[w];
    float var = tot2 * (1.0f / D);

    float y = dv * rsqrtf(var + 1e-5f) * g[tid] + bt[tid];
    y = y > 0.0f ? y : 0.0f;
    OUT* orow = O + (size_t)row * D;
    if constexpr (sizeof(OUT) == 2) orow[tid] = (OUT)f2bf(y);
    else orow[tid] = (OUT)y;
}

// ---------------- host launch ----------------

extern "C" void kernel_launch(void* const* d_in, const int* in_sizes, int n_in,
                              void* d_out, int out_size, void* d_ws, size_t ws_size,
                              hipStream_t stream) {
    const int N = N_NODES;
    const float* x  = (const float*)d_in[0];
    const int*  ei  = (const int*)d_in[1];
    const float* W1 = (const float*)d_in[2];
    const float* b1 = (const float*)d_in[3];
    const float* g1 = (const float*)d_in[4];
    const float* bt1 = (const float*)d_in[5];
    const float* W2 = (const float*)d_in[6];
    const float* b2 = (const float*)d_in[7];
    const float* g2 = (const float*)d_in[8];
    const float* bt2 = (const float*)d_in[9];
    float* out = (float*)d_out;

    const int E = in_sizes[1] / 2;
    const int* src = ei;
    const int* dst = ei + E;

    // workspace carve (256B aligned)
    char* w = (char*)d_ws;
    auto alloc = [&](size_t bytes) { char* p = w; w += (bytes + 255) & ~(size_t)255; return p; };
    int* degi    = (int*)alloc((size_t)N * 4);
    int* cnt     = (int*)alloc((size_t)N * 4);
    int* rowptr  = (int*)alloc((size_t)(N + 1) * 4);
    int* cursor  = (int*)alloc((size_t)N * 4);
    int* csr_src = (int*)alloc((size_t)E * 4);
    float* dinv  = (float*)alloc((size_t)N * 4);
    float* csr_w = (float*)alloc((size_t)E * 4);
    unsigned short* xb  = (unsigned short*)alloc((size_t)N * 128 * 2);
    unsigned short* Tx1 = (unsigned short*)alloc((size_t)N * 128 * 2);
    unsigned short* Tx2 = (unsigned short*)alloc((size_t)N * 128 * 2);
    float* h1           = (float*)alloc((size_t)N * 256 * 4);
    unsigned short* h1b = (unsigned short*)alloc((size_t)N * 256 * 2);
    unsigned short* T1b = (unsigned short*)alloc((size_t)N * 256 * 2);
    unsigned short* T2b = (unsigned short*)alloc((size_t)N * 256 * 2);
    float* o2f          = (float*)alloc((size_t)N * 128 * 4);
    unsigned short* Bt1 = (unsigned short*)alloc((size_t)384 * 256 * 2);
    unsigned short* Bt2 = (unsigned short*)alloc((size_t)768 * 128 * 2);
    (void)ws_size;

    const int TPB = 256;
    const int gridE = (E + TPB - 1) / TPB;
    const int gridN = (N + TPB - 1) / TPB;

    // --- preprocessing ---
    // NOTE: degi and cnt are NOT contiguous (256B-aligned carve) — zero each
    // with its exact range. A combined fill over 2*N left cnt's tail poisoned
    // (0xAA), which wrecked the scan and caused OOB csr writes (round-3 abort).
    hipLaunchKernelGGL(fill_zero_int_kernel, dim3(128), dim3(TPB), 0, stream, degi, (size_t)N);
    hipLaunchKernelGGL(fill_zero_int_kernel, dim3(128), dim3(TPB), 0, stream, cnt, (size_t)N);
    hipLaunchKernelGGL(hist_kernel, dim3(gridE), dim3(TPB), 0, stream, src, dst, degi, cnt, E);
    hipLaunchKernelGGL(dinv_kernel, dim3(gridN), dim3(TPB), 0, stream, degi, dinv, N);
    hipLaunchKernelGGL(scan_kernel, dim3(1), dim3(1024), 0, stream, cnt, rowptr, cursor, N);
    hipLaunchKernelGGL(csr_build_kernel, dim3(gridE), dim3(TPB), 0, stream,
                       src, dst, dinv, cursor, csr_src, csr_w, E);
    hipLaunchKernelGGL(cvt_bf_kernel, dim3((N * 128 / 4 + TPB - 1) / TPB), dim3(TPB), 0, stream,
                       x, xb, (size_t)N * 128 / 4);
    hipLaunchKernelGGL(wtrans_kernel, dim3((3 * 128 * 256 + TPB - 1) / TPB), dim3(TPB), 0, stream,
                       W1, Bt1, 128, 256);
    hipLaunchKernelGGL(wtrans_kernel, dim3((3 * 256 * 128 + TPB - 1) / TPB), dim3(TPB), 0, stream,
                       W2, Bt2, 256, 128);

    const int gridW = (N + 3) / 4;

    // --- layer 1: D=128 -> 256 ---
    hipLaunchKernelGGL((prop_gather_bf_kernel<128>), dim3(gridW), dim3(TPB), 0, stream,
                       xb, rowptr, csr_src, csr_w, (const unsigned short*)nullptr, Tx1, N, 1.0f);
    hipLaunchKernelGGL((prop_gather_bf_kernel<128>), dim3(gridW), dim3(TPB), 0, stream,
                       Tx1, rowptr, csr_src, csr_w, xb, Tx2, N, 2.0f);
    {
        int nrow = (N + 127) / 128, ncol = 256 / 64;
        hipLaunchKernelGGL((gemm3_mfma_kernel<128>), dim3(nrow * ncol), dim3(256), 0, stream,
                           xb, Tx1, Tx2, Bt1, b1, h1, N, 256, ncol);
    }
    hipLaunchKernelGGL((ln_relu_kernel<256, unsigned short>), dim3(N), dim3(256), 0, stream,
                       h1, h1b, g1, bt1, N);

    // --- layer 2: D=256 -> 128 ---
    hipLaunchKernelGGL((prop_gather_bf_kernel<256>), dim3(gridW), dim3(TPB), 0, stream,
                       h1b, rowptr, csr_src, csr_w, (const unsigned short*)nullptr, T1b, N, 1.0f);
    hipLaunchKernelGGL((prop_gather_bf_kernel<256>), dim3(gridW), dim3(TPB), 0, stream,
                       T1b, rowptr, csr_src, csr_w, h1b, T2b, N, 2.0f);
    {
        int nrow = (N + 127) / 128, ncol = 128 / 64;
        hipLaunchKernelGGL((gemm3_mfma_kernel<256>), dim3(nrow * ncol), dim3(256), 0, stream,
                           h1b, T1b, T2b, Bt2, b2, o2f, N, 128, ncol);
    }
    hipLaunchKernelGGL((ln_relu_kernel<128, float>), dim3(N), dim3(128), 0, stream,
                       o2f, out, g2, bt2, N);
}

// Round 5
// 429.654 us; speedup vs baseline: 5.6620x; 1.2629x over previous
//
#include <hip/hip_runtime.h>

#define N_NODES 50000

using f32x4  = __attribute__((ext_vector_type(4))) float;
using bf16x8 = __attribute__((ext_vector_type(8))) __bf16;

__device__ __forceinline__ unsigned short f2bf(float f) {
    unsigned int b = __float_as_uint(f);
    unsigned int r = (b + 0x7FFFu + ((b >> 16) & 1u)) >> 16;   // RNE
    return (unsigned short)r;
}
__device__ __forceinline__ float bf_lo(unsigned int u) { return __uint_as_float(u << 16); }
__device__ __forceinline__ float bf_hi(unsigned int u) { return __uint_as_float(u & 0xFFFF0000u); }
__device__ __forceinline__ unsigned int packbf(float x, float y) {
    return ((unsigned int)f2bf(y) << 16) | f2bf(x);
}

// ---------------- utility ----------------

__global__ void fill_zero_int_kernel(int* __restrict__ p, size_t n) {
    size_t i = (size_t)blockIdx.x * blockDim.x + threadIdx.x;
    size_t stride = (size_t)gridDim.x * blockDim.x;
    for (; i < n; i += stride) p[i] = 0;
}

__global__ void cvt_bf_kernel(const float* __restrict__ in, unsigned short* __restrict__ out, size_t n4) {
    size_t i = (size_t)blockIdx.x * blockDim.x + threadIdx.x;
    if (i < n4) {
        float4 v = *reinterpret_cast<const float4*>(in + i * 4);
        ushort4 o;
        o.x = f2bf(v.x); o.y = f2bf(v.y); o.z = f2bf(v.z); o.w = f2bf(v.w);
        *reinterpret_cast<ushort4*>(out + i * 4) = o;
    }
}

// W1: [3][128][256] f32 -> Bt1: [256][384] bf16  (row = out col, col = concat k)
__global__ void wtrans1_kernel(const float* __restrict__ W, unsigned short* __restrict__ Bt) {
    int i = blockIdx.x * blockDim.x + threadIdx.x;
    if (i < 3 * 128 * 256) {
        int c = i % 256;
        int kg = i / 256;          // 0..383
        Bt[(size_t)c * 384 + kg] = f2bf(W[(size_t)kg * 256 + c]);
    }
}

// W2: [3][256][128] f32 -> Btc: [384][256] bf16 with cols [W0-W2 | W1 | 2*W2]
__global__ void wtrans2_kernel(const float* __restrict__ W, unsigned short* __restrict__ Btc) {
    int i = blockIdx.x * blockDim.x + threadIdx.x;
    if (i < 384 * 256) {
        int k = i % 256;
        int cc = i / 256;          // 0..383
        int seg = cc >> 7, c = cc & 127;
        float v;
        if (seg == 0)      v = W[(size_t)k * 128 + c] - W[(size_t)(2 * 256 + k) * 128 + c];
        else if (seg == 1) v = W[(size_t)(256 + k) * 128 + c];
        else               v = 2.0f * W[(size_t)(2 * 256 + k) * 128 + c];
        Btc[(size_t)cc * 256 + k] = f2bf(v);
    }
}

// ---------------- edge preprocessing ----------------

__global__ void hist_kernel(const int* __restrict__ src, const int* __restrict__ dst,
                            int* __restrict__ degi, int* __restrict__ cnt, int E) {
    int e = blockIdx.x * blockDim.x + threadIdx.x;
    if (e < E) {
        int s = src[e], d = dst[e];
        if (s != d) {
            atomicAdd(&degi[s], 1);
            atomicAdd(&cnt[d], 1);
        }
    }
}

__global__ void dinv_kernel(const int* __restrict__ degi, float* __restrict__ dinv, int n) {
    int i = blockIdx.x * blockDim.x + threadIdx.x;
    if (i < n) {
        int dg = degi[i];
        dinv[i] = dg > 0 ? rsqrtf((float)dg) : 0.0f;
    }
}

// --- 3-phase scan: per-block exclusive scan, block-sum scan, add-back ---

__global__ __launch_bounds__(1024) void scan1_kernel(const int* __restrict__ cnt,
                                                     int* __restrict__ excl,
                                                     int* __restrict__ bsum, int n) {
    __shared__ int wsum[16];
    int tid = threadIdx.x, lane = tid & 63, wid = tid >> 6;
    int i = blockIdx.x * 1024 + tid;
    int v = (i < n) ? cnt[i] : 0;
    int x = v;
#pragma unroll
    for (int o = 1; o < 64; o <<= 1) { int y = __shfl_up(x, o); if (lane >= o) x += y; }
    if (lane == 63) wsum[wid] = x;
    __syncthreads();
    if (tid < 16) {
        int s = wsum[tid];
#pragma unroll
        for (int o = 1; o < 16; o <<= 1) { int y = __shfl_up(s, o); if (tid >= o) s += y; }
        wsum[tid] = s;
    }
    __syncthreads();
    int base = (wid > 0 ? wsum[wid - 1] : 0);
    if (i < n) excl[i] = base + x - v;
    if (tid == 0) bsum[blockIdx.x] = wsum[15];
}

__global__ void scan2_kernel(int* __restrict__ bsum, int nb) {
    int t = threadIdx.x;                   // single wave, nb <= 64
    int v = (t < nb) ? bsum[t] : 0;
    int x = v;
#pragma unroll
    for (int o = 1; o < 64; o <<= 1) { int y = __shfl_up(x, o); if (t >= o) x += y; }
    if (t < nb) bsum[t] = x - v;           // exclusive
}

__global__ __launch_bounds__(1024) void scan3_kernel(const int* __restrict__ excl,
                                                     const int* __restrict__ bsum,
                                                     const int* __restrict__ cnt,
                                                     int* __restrict__ rowptr,
                                                     int* __restrict__ cursor, int n) {
    int i = blockIdx.x * 1024 + threadIdx.x;
    if (i < n) {
        int rp = excl[i] + bsum[blockIdx.x];
        rowptr[i] = rp;
        cursor[i] = rp;
        if (i == n - 1) rowptr[n] = rp + cnt[i];
    }
}

__global__ void csr_build_kernel(const int* __restrict__ src, const int* __restrict__ dst,
                                 const float* __restrict__ dinv, int* __restrict__ cursor,
                                 int* __restrict__ csr_src, float* __restrict__ csr_w, int E) {
    int e = blockIdx.x * blockDim.x + threadIdx.x;
    if (e < E) {
        int s = src[e], d = dst[e];
        if (s != d) {
            int pos = atomicAdd(&cursor[d], 1);
            csr_src[pos] = s;
            csr_w[pos] = -dinv[s] * dinv[d];
        }
    }
}

// ---------------- CSR gather propagation, D=128 bf16, f32 accum ----------------
// out[node] = scale * sum_e w_e * H[src_e]  + coef * add[node]
// H stride hs (u32 units), add stride as_ (u32 units), out stride 64.

__global__ void prop_kernel(const unsigned int* __restrict__ H, int hs,
                            const int* __restrict__ rowptr,
                            const int* __restrict__ csr_src,
                            const float* __restrict__ csr_w,
                            const unsigned int* __restrict__ add, int as_,
                            float scale, float coef,
                            unsigned int* __restrict__ out, int n) {
    int wib = threadIdx.x >> 6;
    int lane = threadIdx.x & 63;
    int node = blockIdx.x * (blockDim.x >> 6) + wib;
    if (node >= n) return;

    float ax = 0.0f, ay = 0.0f;
    int beg = rowptr[node], end = rowptr[node + 1];
    int i = beg;
    for (; i + 2 <= end; i += 2) {
        int s0 = csr_src[i], s1 = csr_src[i + 1];
        float w0 = csr_w[i], w1 = csr_w[i + 1];
        unsigned int u0 = H[(size_t)s0 * hs + lane];
        unsigned int u1 = H[(size_t)s1 * hs + lane];
        ax += w0 * bf_lo(u0) + w1 * bf_lo(u1);
        ay += w0 * bf_hi(u0) + w1 * bf_hi(u1);
    }
    if (i < end) {
        int s0 = csr_src[i];
        float w0 = csr_w[i];
        unsigned int u0 = H[(size_t)s0 * hs + lane];
        ax += w0 * bf_lo(u0);
        ay += w0 * bf_hi(u0);
    }

    float vx = scale * ax, vy = scale * ay;
    if (add) {
        unsigned int au = add[(size_t)node * as_ + lane];
        vx += coef * bf_lo(au);
        vy += coef * bf_hi(au);
    }
    out[(size_t)node * 64 + lane] = packbf(vx, vy);
}

// final prop + bias + LayerNorm + ReLU -> f32 out.  V stride 64, U0 stride 192.
__global__ void prop_ln_kernel(const unsigned int* __restrict__ V,
                               const int* __restrict__ rowptr,
                               const int* __restrict__ csr_src,
                               const float* __restrict__ csr_w,
                               const unsigned int* __restrict__ U0,
                               const float* __restrict__ b,
                               const float* __restrict__ g,
                               const float* __restrict__ bt,
                               float* __restrict__ out, int n) {
    int wib = threadIdx.x >> 6;
    int lane = threadIdx.x & 63;
    int node = blockIdx.x * (blockDim.x >> 6) + wib;
    if (node >= n) return;

    float ax = 0.0f, ay = 0.0f;
    int beg = rowptr[node], end = rowptr[node + 1];
    int i = beg;
    for (; i + 2 <= end; i += 2) {
        int s0 = csr_src[i], s1 = csr_src[i + 1];
        float w0 = csr_w[i], w1 = csr_w[i + 1];
        unsigned int u0 = V[(size_t)s0 * 64 + lane];
        unsigned int u1 = V[(size_t)s1 * 64 + lane];
        ax += w0 * bf_lo(u0) + w1 * bf_lo(u1);
        ay += w0 * bf_hi(u0) + w1 * bf_hi(u1);
    }
    if (i < end) {
        int s0 = csr_src[i];
        float w0 = csr_w[i];
        unsigned int u0 = V[(size_t)s0 * 64 + lane];
        ax += w0 * bf_lo(u0);
        ay += w0 * bf_hi(u0);
    }

    unsigned int au = U0[(size_t)node * 192 + lane];
    float px = ax + bf_lo(au) + b[2 * lane];
    float py = ay + bf_hi(au) + b[2 * lane + 1];

    float s = px + py;
#pragma unroll
    for (int o = 1; o < 64; o <<= 1) s += __shfl_xor(s, o);
    float mu = s * (1.0f / 128.0f);
    float dx = px - mu, dy = py - mu;
    float q = dx * dx + dy * dy;
#pragma unroll
    for (int o = 1; o < 64; o <<= 1) q += __shfl_xor(q, o);
    float rs = rsqrtf(q * (1.0f / 128.0f) + 1e-5f);

    float yx = dx * rs * g[2 * lane] + bt[2 * lane];
    float yy = dy * rs * g[2 * lane + 1] + bt[2 * lane + 1];
    yx = yx > 0.0f ? yx : 0.0f;
    yy = yy > 0.0f ? yy : 0.0f;
    float2 o2 = make_float2(yx, yy);
    *reinterpret_cast<float2*>(out + (size_t)node * 128 + 2 * lane) = o2;
}

// ---------------- gemm1: [x|T1|T2] @ Bt1^T + b1 -> LN -> ReLU -> bf16 h1 ----------------
// A*: [N][128] bf16.  Bt1: [256][384] bf16.  Hout: [N][256] bf16.
// BM=128, BN=256 (full width), BK=32. 4 waves 2x2, wave tile 64x128.

__global__ __launch_bounds__(256) void gemm1_ln_kernel(
        const unsigned short* __restrict__ A0, const unsigned short* __restrict__ A1,
        const unsigned short* __restrict__ A2, const unsigned short* __restrict__ Bt,
        const float* __restrict__ bias, const float* __restrict__ g,
        const float* __restrict__ bt, unsigned short* __restrict__ Hout, int N) {
    __shared__ __align__(16) unsigned short As[128][40];
    __shared__ __align__(16) unsigned short Bs[256][40];
    __shared__ float redS[2][2][64];
    __shared__ float redQ[2][2][64];

    int row0 = blockIdx.x * 128;
    int tid = threadIdx.x;
    int lane = tid & 63;
    int wave = tid >> 6;
    int wrh = wave >> 1;            // row half
    int wch = wave & 1;             // col half
    int wr = wrh * 64;
    int wc = wch * 128;

    f32x4 acc[4][8];
#pragma unroll
    for (int i = 0; i < 4; ++i)
#pragma unroll
        for (int j = 0; j < 8; ++j) acc[i][j] = (f32x4)0.0f;

    int srow = tid >> 2;
    int sch = (tid & 3) * 8;

    for (int ks = 0; ks < 12; ++ks) {
        int kg = ks * 32;
        int seg = kg >> 7;
        int kk = kg & 127;
        const unsigned short* Aseg = (seg == 0) ? A0 : (seg == 1 ? A1 : A2);
#pragma unroll
        for (int p = 0; p < 2; ++p) {
            int rr = p * 64 + srow;
            int gr = row0 + rr;
            uint4 v = make_uint4(0u, 0u, 0u, 0u);
            if (gr < N) v = *reinterpret_cast<const uint4*>(Aseg + (size_t)gr * 128 + kk + sch);
            *reinterpret_cast<uint4*>(&As[rr][sch]) = v;
        }
#pragma unroll
        for (int p = 0; p < 4; ++p) {
            int rr = p * 64 + srow;
            uint4 v = *reinterpret_cast<const uint4*>(Bt + (size_t)rr * 384 + kg + sch);
            *reinterpret_cast<uint4*>(&Bs[rr][sch]) = v;
        }
        __syncthreads();

        int fr = lane & 15;
        int kh = (lane >> 4) * 8;
        bf16x8 af[4], bfr[8];
#pragma unroll
        for (int i = 0; i < 4; ++i)
            af[i] = *reinterpret_cast<const bf16x8*>(&As[wr + i * 16 + fr][kh]);
#pragma unroll
        for (int j = 0; j < 8; ++j)
            bfr[j] = *reinterpret_cast<const bf16x8*>(&Bs[wc + j * 16 + fr][kh]);
#pragma unroll
        for (int i = 0; i < 4; ++i)
#pragma unroll
            for (int j = 0; j < 8; ++j)
                acc[i][j] = __builtin_amdgcn_mfma_f32_16x16x32_bf16(af[i], bfr[j], acc[i][j], 0, 0, 0);
        __syncthreads();
    }

    // ---- epilogue: bias, LN stats, normalize, relu, bf16 store ----
    int fc = lane & 15;
    int fq = lane >> 4;
    float bcol[8], gcol[8], btcol[8];
#pragma unroll
    for (int j = 0; j < 8; ++j) {
        int c = wc + j * 16 + fc;
        bcol[j] = bias[c];
        gcol[j] = g[c];
        btcol[j] = bt[c];
    }
#pragma unroll
    for (int i = 0; i < 4; ++i)
#pragma unroll
        for (int j = 0; j < 8; ++j)
#pragma unroll
            for (int v = 0; v < 4; ++v) acc[i][j][v] += bcol[j];

    // per-row partial sums over this wave's 128 cols
#pragma unroll
    for (int i = 0; i < 4; ++i) {
#pragma unroll
        for (int v = 0; v < 4; ++v) {
            float s = 0.0f, q = 0.0f;
#pragma unroll
            for (int j = 0; j < 8; ++j) {
                float val = acc[i][j][v];
                s += val;
                q += val * val;
            }
#pragma unroll
            for (int o = 1; o < 16; o <<= 1) {
                s += __shfl_xor(s, o);
                q += __shfl_xor(q, o);
            }
            if (fc == 0) {
                int r = i * 16 + fq * 4 + v;
                redS[wrh][wch][r] = s;
                redQ[wrh][wch][r] = q;
            }
        }
    }
    __syncthreads();

#pragma unroll
    for (int i = 0; i < 4; ++i) {
#pragma unroll
        for (int v = 0; v < 4; ++v) {
            int r = i * 16 + fq * 4 + v;
            float S = redS[wrh][0][r] + redS[wrh][1][r];
            float Q = redQ[wrh][0][r] + redQ[wrh][1][r];
            float mu = S * (1.0f / 256.0f);
            float var = Q * (1.0f / 256.0f) - mu * mu;
            float rsg = rsqrtf(var + 1e-5f);
            int gr = row0 + wr + r;
            if (gr < N) {
#pragma unroll
                for (int j = 0; j < 8; ++j) {
                    float y = (acc[i][j][v] - mu) * rsg * gcol[j] + btcol[j];
                    y = y > 0.0f ? y : 0.0f;
                    Hout[(size_t)gr * 256 + wc + j * 16 + fc] = f2bf(y);
                }
            }
        }
    }
}

// ---------------- gemm2: h1 @ Btc^T -> U [N][384] bf16 (no bias) ----------------
// A: [N][256] bf16.  Btc: [384][256] bf16.  BM=128, BN=128, BK=32, 4 waves 2x2.

__global__ __launch_bounds__(256) void gemm2_kernel(
        const unsigned short* __restrict__ A, const unsigned short* __restrict__ Btc,
        unsigned short* __restrict__ U, int N, int ncol) {
    __shared__ __align__(16) unsigned short As[128][40];
    __shared__ __align__(16) unsigned short Bs[128][40];

    int nwg = gridDim.x;
    int q = nwg >> 3, r = nwg & 7;
    int xcd = blockIdx.x & 7, idx = blockIdx.x >> 3;
    int wgid = (xcd < r ? xcd * (q + 1) : r * (q + 1) + (xcd - r) * q) + idx;

    int row0 = (wgid / ncol) * 128;
    int col0 = (wgid % ncol) * 128;

    int tid = threadIdx.x;
    int lane = tid & 63;
    int wave = tid >> 6;
    int wr = (wave >> 1) * 64;
    int wc = (wave & 1) * 64;

    f32x4 acc[4][4];
#pragma unroll
    for (int i = 0; i < 4; ++i)
#pragma unroll
        for (int j = 0; j < 4; ++j) acc[i][j] = (f32x4)0.0f;

    int srow = tid >> 2;
    int sch = (tid & 3) * 8;

    for (int ks = 0; ks < 8; ++ks) {
        int kg = ks * 32;
#pragma unroll
        for (int p = 0; p < 2; ++p) {
            int rr = p * 64 + srow;
            int gr = row0 + rr;
            uint4 v = make_uint4(0u, 0u, 0u, 0u);
            if (gr < N) v = *reinterpret_cast<const uint4*>(A + (size_t)gr * 256 + kg + sch);
            *reinterpret_cast<uint4*>(&As[rr][sch]) = v;
        }
#pragma unroll
        for (int p = 0; p < 2; ++p) {
            int rr = p * 64 + srow;
            uint4 v = *reinterpret_cast<const uint4*>(Btc + (size_t)(col0 + rr) * 256 + kg + sch);
            *reinterpret_cast<uint4*>(&Bs[rr][sch]) = v;
        }
        __syncthreads();

        int fr = lane & 15;
        int kh = (lane >> 4) * 8;
        bf16x8 af[4], bfr[4];
#pragma unroll
        for (int i = 0; i < 4; ++i)
            af[i] = *reinterpret_cast<const bf16x8*>(&As[wr + i * 16 + fr][kh]);
#pragma unroll
        for (int j = 0; j < 4; ++j)
            bfr[j] = *reinterpret_cast<const bf16x8*>(&Bs[wc + j * 16 + fr][kh]);
#pragma unroll
        for (int i = 0; i < 4; ++i)
#pragma unroll
            for (int j = 0; j < 4; ++j)
                acc[i][j] = __builtin_amdgcn_mfma_f32_16x16x32_bf16(af[i], bfr[j], acc[i][j], 0, 0, 0);
        __syncthreads();
    }

    int fc = lane & 15;
    int frr = (lane >> 4) * 4;
#pragma unroll
    for (int i = 0; i < 4; ++i) {
#pragma unroll
        for (int v = 0; v < 4; ++v) {
            int gr = row0 + wr + i * 16 + frr + v;
            if (gr < N) {
#pragma unroll
                for (int j = 0; j < 4; ++j) {
                    int gc = col0 + wc + j * 16 + fc;
                    U[(size_t)gr * 384 + gc] = f2bf(acc[i][j][v]);
                }
            }
        }
    }
}

// ---------------- host launch ----------------

extern "C" void kernel_launch(void* const* d_in, const int* in_sizes, int n_in,
                              void* d_out, int out_size, void* d_ws, size_t ws_size,
                              hipStream_t stream) {
    const int N = N_NODES;
    const float* x  = (const float*)d_in[0];
    const int*  ei  = (const int*)d_in[1];
    const float* W1 = (const float*)d_in[2];
    const float* b1 = (const float*)d_in[3];
    const float* g1 = (const float*)d_in[4];
    const float* bt1 = (const float*)d_in[5];
    const float* W2 = (const float*)d_in[6];
    const float* b2 = (const float*)d_in[7];
    const float* g2 = (const float*)d_in[8];
    const float* bt2 = (const float*)d_in[9];
    float* out = (float*)d_out;

    const int E = in_sizes[1] / 2;
    const int* src = ei;
    const int* dst = ei + E;

    // workspace carve (256B aligned)
    char* w = (char*)d_ws;
    auto alloc = [&](size_t bytes) { char* p = w; w += (bytes + 255) & ~(size_t)255; return p; };
    int* degi    = (int*)alloc((size_t)N * 4);
    int* cnt     = (int*)alloc((size_t)N * 4);
    int* excl    = (int*)alloc((size_t)N * 4);
    int* bsum    = (int*)alloc(64 * 4);
    int* rowptr  = (int*)alloc((size_t)(N + 1) * 4);
    int* cursor  = (int*)alloc((size_t)N * 4);
    int* csr_src = (int*)alloc((size_t)E * 4);
    float* dinv  = (float*)alloc((size_t)N * 4);
    float* csr_w = (float*)alloc((size_t)E * 4);
    unsigned short* xb  = (unsigned short*)alloc((size_t)N * 128 * 2);
    unsigned short* T1  = (unsigned short*)alloc((size_t)N * 128 * 2);
    unsigned short* T2  = (unsigned short*)alloc((size_t)N * 128 * 2);
    unsigned short* h1b = (unsigned short*)alloc((size_t)N * 256 * 2);
    unsigned short* U   = (unsigned short*)alloc((size_t)N * 384 * 2);
    unsigned short* V   = (unsigned short*)alloc((size_t)N * 128 * 2);
    unsigned short* Bt1 = (unsigned short*)alloc((size_t)256 * 384 * 2);
    unsigned short* Btc = (unsigned short*)alloc((size_t)384 * 256 * 2);
    (void)ws_size;

    const int TPB = 256;
    const int gridE = (E + TPB - 1) / TPB;
    const int gridN = (N + TPB - 1) / TPB;
    const int NB = (N + 1023) / 1024;

    // --- preprocessing ---
    hipLaunchKernelGGL(fill_zero_int_kernel, dim3(128), dim3(TPB), 0, stream, degi, (size_t)N);
    hipLaunchKernelGGL(fill_zero_int_kernel, dim3(128), dim3(TPB), 0, stream, cnt, (size_t)N);
    hipLaunchKernelGGL(hist_kernel, dim3(gridE), dim3(TPB), 0, stream, src, dst, degi, cnt, E);
    hipLaunchKernelGGL(dinv_kernel, dim3(gridN), dim3(TPB), 0, stream, degi, dinv, N);
    hipLaunchKernelGGL(scan1_kernel, dim3(NB), dim3(1024), 0, stream, cnt, excl, bsum, N);
    hipLaunchKernelGGL(scan2_kernel, dim3(1), dim3(64), 0, stream, bsum, NB);
    hipLaunchKernelGGL(scan3_kernel, dim3(NB), dim3(1024), 0, stream, excl, bsum, cnt, rowptr, cursor, N);
    hipLaunchKernelGGL(csr_build_kernel, dim3(gridE), dim3(TPB), 0, stream,
                       src, dst, dinv, cursor, csr_src, csr_w, E);
    hipLaunchKernelGGL(cvt_bf_kernel, dim3((N * 128 / 4 + TPB - 1) / TPB), dim3(TPB), 0, stream,
                       x, xb, (size_t)N * 128 / 4);
    hipLaunchKernelGGL(wtrans1_kernel, dim3((3 * 128 * 256 + TPB - 1) / TPB), dim3(TPB), 0, stream, W1, Bt1);
    hipLaunchKernelGGL(wtrans2_kernel, dim3((384 * 256 + TPB - 1) / TPB), dim3(TPB), 0, stream, W2, Btc);

    const int gridW = (N + 3) / 4;   // 4 waves per block, 1 node per wave

    // --- layer 1: props (D=128) then GEMM+LN ---
    hipLaunchKernelGGL(prop_kernel, dim3(gridW), dim3(TPB), 0, stream,
                       (const unsigned int*)xb, 64, rowptr, csr_src, csr_w,
                       (const unsigned int*)nullptr, 0, 1.0f, 0.0f,
                       (unsigned int*)T1, N);
    hipLaunchKernelGGL(prop_kernel, dim3(gridW), dim3(TPB), 0, stream,
                       (const unsigned int*)T1, 64, rowptr, csr_src, csr_w,
                       (const unsigned int*)xb, 64, 2.0f, -1.0f,
                       (unsigned int*)T2, N);
    hipLaunchKernelGGL(gemm1_ln_kernel, dim3((N + 127) / 128), dim3(256), 0, stream,
                       xb, T1, T2, Bt1, b1, g1, bt1, h1b, N);

    // --- layer 2: GEMM first, then props in 128-dim ---
    {
        int nrow = (N + 127) / 128, ncol = 3;
        hipLaunchKernelGGL(gemm2_kernel, dim3(nrow * ncol), dim3(256), 0, stream,
                           h1b, Btc, U, N, ncol);
    }
    // v = L(u2) + u1   (u2 = U cols 256..383, u1 = U cols 128..255)
    hipLaunchKernelGGL(prop_kernel, dim3(gridW), dim3(TPB), 0, stream,
                       (const unsigned int*)U + 128, 192, rowptr, csr_src, csr_w,
                       (const unsigned int*)U + 64, 192, 1.0f, 1.0f,
                       (unsigned int*)V, N);
    // out = LN(L(v) + u0 + b2) -> relu
    hipLaunchKernelGGL(prop_ln_kernel, dim3(gridW), dim3(TPB), 0, stream,
                       (const unsigned int*)V, rowptr, csr_src, csr_w,
                       (const unsigned int*)U, b2, g2, bt2, out, N);
}

// Round 6
// 369.563 us; speedup vs baseline: 6.5826x; 1.1626x over previous
//
#include <hip/hip_runtime.h>

#define N_NODES 50000

using f32x4  = __attribute__((ext_vector_type(4))) float;
using bf16x8 = __attribute__((ext_vector_type(8))) __bf16;

__device__ __forceinline__ unsigned short f2bf(float f) {
    unsigned int b = __float_as_uint(f);
    unsigned int r = (b + 0x7FFFu + ((b >> 16) & 1u)) >> 16;   // RNE
    return (unsigned short)r;
}
__device__ __forceinline__ float bf_lo(unsigned int u) { return __uint_as_float(u << 16); }
__device__ __forceinline__ float bf_hi(unsigned int u) { return __uint_as_float(u & 0xFFFF0000u); }
__device__ __forceinline__ unsigned int packbf(float x, float y) {
    return ((unsigned int)f2bf(y) << 16) | f2bf(x);
}

// ---------------- utility ----------------

__global__ void fill_zero_int_kernel(int* __restrict__ p, size_t n) {
    size_t i = (size_t)blockIdx.x * blockDim.x + threadIdx.x;
    size_t stride = (size_t)gridDim.x * blockDim.x;
    for (; i < n; i += stride) p[i] = 0;
}

__global__ void cvt_bf_kernel(const float* __restrict__ in, unsigned short* __restrict__ out, size_t n4) {
    size_t i = (size_t)blockIdx.x * blockDim.x + threadIdx.x;
    if (i < n4) {
        float4 v = *reinterpret_cast<const float4*>(in + i * 4);
        ushort4 o;
        o.x = f2bf(v.x); o.y = f2bf(v.y); o.z = f2bf(v.z); o.w = f2bf(v.w);
        *reinterpret_cast<ushort4*>(out + i * 4) = o;
    }
}

// W1: [3][128][256] f32 -> Bt1: [256][384] bf16  (row = out col, col = concat k)
__global__ void wtrans1_kernel(const float* __restrict__ W, unsigned short* __restrict__ Bt) {
    int i = blockIdx.x * blockDim.x + threadIdx.x;
    if (i < 3 * 128 * 256) {
        int c = i % 256;
        int kg = i / 256;          // 0..383
        Bt[(size_t)c * 384 + kg] = f2bf(W[(size_t)kg * 256 + c]);
    }
}

// W2: [3][256][128] f32 -> Btc: [384][256] bf16 with cols [W0-W2 | W1 | 2*W2]
__global__ void wtrans2_kernel(const float* __restrict__ W, unsigned short* __restrict__ Btc) {
    int i = blockIdx.x * blockDim.x + threadIdx.x;
    if (i < 384 * 256) {
        int k = i % 256;
        int cc = i / 256;          // 0..383
        int seg = cc >> 7, c = cc & 127;
        float v;
        if (seg == 0)      v = W[(size_t)k * 128 + c] - W[(size_t)(2 * 256 + k) * 128 + c];
        else if (seg == 1) v = W[(size_t)(256 + k) * 128 + c];
        else               v = 2.0f * W[(size_t)(2 * 256 + k) * 128 + c];
        Btc[(size_t)cc * 256 + k] = f2bf(v);
    }
}

// ---------------- edge preprocessing ----------------

__global__ void hist_kernel(const int* __restrict__ src, const int* __restrict__ dst,
                            int* __restrict__ degi, int* __restrict__ cnt, int E) {
    int e = blockIdx.x * blockDim.x + threadIdx.x;
    if (e < E) {
        int s = src[e], d = dst[e];
        if (s != d) {
            atomicAdd(&degi[s], 1);
            atomicAdd(&cnt[d], 1);
        }
    }
}

__global__ void dinv_kernel(const int* __restrict__ degi, float* __restrict__ dinv, int n) {
    int i = blockIdx.x * blockDim.x + threadIdx.x;
    if (i < n) {
        int dg = degi[i];
        dinv[i] = dg > 0 ? rsqrtf((float)dg) : 0.0f;
    }
}

// --- 3-phase scan ---

__global__ __launch_bounds__(1024) void scan1_kernel(const int* __restrict__ cnt,
                                                     int* __restrict__ excl,
                                                     int* __restrict__ bsum, int n) {
    __shared__ int wsum[16];
    int tid = threadIdx.x, lane = tid & 63, wid = tid >> 6;
    int i = blockIdx.x * 1024 + tid;
    int v = (i < n) ? cnt[i] : 0;
    int x = v;
#pragma unroll
    for (int o = 1; o < 64; o <<= 1) { int y = __shfl_up(x, o); if (lane >= o) x += y; }
    if (lane == 63) wsum[wid] = x;
    __syncthreads();
    if (tid < 16) {
        int s = wsum[tid];
#pragma unroll
        for (int o = 1; o < 16; o <<= 1) { int y = __shfl_up(s, o); if (tid >= o) s += y; }
        wsum[tid] = s;
    }
    __syncthreads();
    int base = (wid > 0 ? wsum[wid - 1] : 0);
    if (i < n) excl[i] = base + x - v;
    if (tid == 0) bsum[blockIdx.x] = wsum[15];
}

__global__ void scan2_kernel(int* __restrict__ bsum, int nb) {
    int t = threadIdx.x;                   // single wave, nb <= 64
    int v = (t < nb) ? bsum[t] : 0;
    int x = v;
#pragma unroll
    for (int o = 1; o < 64; o <<= 1) { int y = __shfl_up(x, o); if (t >= o) x += y; }
    if (t < nb) bsum[t] = x - v;           // exclusive
}

__global__ __launch_bounds__(1024) void scan3_kernel(const int* __restrict__ excl,
                                                     const int* __restrict__ bsum,
                                                     const int* __restrict__ cnt,
                                                     int* __restrict__ rowptr,
                                                     int* __restrict__ cursor, int n) {
    int i = blockIdx.x * 1024 + threadIdx.x;
    if (i < n) {
        int rp = excl[i] + bsum[blockIdx.x];
        rowptr[i] = rp;
        cursor[i] = rp;
        if (i == n - 1) rowptr[n] = rp + cnt[i];
    }
}

__global__ void csr_build_kernel(const int* __restrict__ src, const int* __restrict__ dst,
                                 const float* __restrict__ dinv, int* __restrict__ cursor,
                                 int* __restrict__ csr_src, float* __restrict__ csr_w, int E) {
    int e = blockIdx.x * blockDim.x + threadIdx.x;
    if (e < E) {
        int s = src[e], d = dst[e];
        if (s != d) {
            int pos = atomicAdd(&cursor[d], 1);
            csr_src[pos] = s;
            csr_w[pos] = -dinv[s] * dinv[d];
        }
    }
}

// ---------------- CSR gather propagation, D=128 bf16, f32 accum ----------------
// out[node] = scale * sum_e w_e * H[src_e]  + coef * add[node]
// 4-wide edge unroll keeps 4 independent gathers in flight (LLC-latency bound).

__global__ void prop_kernel(const unsigned int* __restrict__ H, int hs,
                            const int* __restrict__ rowptr,
                            const int* __restrict__ csr_src,
                            const float* __restrict__ csr_w,
                            const unsigned int* __restrict__ add, int as_,
                            float scale, float coef,
                            unsigned int* __restrict__ out, int n) {
    int wib = threadIdx.x >> 6;
    int lane = threadIdx.x & 63;
    int node = blockIdx.x * (blockDim.x >> 6) + wib;
    if (node >= n) return;

    float ax = 0.0f, ay = 0.0f;
    int beg = rowptr[node], end = rowptr[node + 1];
    int i = beg;
    for (; i + 4 <= end; i += 4) {
        int s0 = csr_src[i], s1 = csr_src[i + 1], s2 = csr_src[i + 2], s3 = csr_src[i + 3];
        float w0 = csr_w[i], w1 = csr_w[i + 1], w2 = csr_w[i + 2], w3 = csr_w[i + 3];
        unsigned int u0 = H[(size_t)s0 * hs + lane];
        unsigned int u1 = H[(size_t)s1 * hs + lane];
        unsigned int u2 = H[(size_t)s2 * hs + lane];
        unsigned int u3 = H[(size_t)s3 * hs + lane];
        ax += w0 * bf_lo(u0) + w1 * bf_lo(u1) + w2 * bf_lo(u2) + w3 * bf_lo(u3);
        ay += w0 * bf_hi(u0) + w1 * bf_hi(u1) + w2 * bf_hi(u2) + w3 * bf_hi(u3);
    }
    for (; i < end; ++i) {
        int s0 = csr_src[i];
        float w0 = csr_w[i];
        unsigned int u0 = H[(size_t)s0 * hs + lane];
        ax += w0 * bf_lo(u0);
        ay += w0 * bf_hi(u0);
    }

    float vx = scale * ax, vy = scale * ay;
    if (add) {
        unsigned int au = add[(size_t)node * as_ + lane];
        vx += coef * bf_lo(au);
        vy += coef * bf_hi(au);
    }
    out[(size_t)node * 64 + lane] = packbf(vx, vy);
}

// final prop + bias + LayerNorm + ReLU -> f32 out.  V stride 64, U0 stride 192.
__global__ void prop_ln_kernel(const unsigned int* __restrict__ V,
                               const int* __restrict__ rowptr,
                               const int* __restrict__ csr_src,
                               const float* __restrict__ csr_w,
                               const unsigned int* __restrict__ U0,
                               const float* __restrict__ b,
                               const float* __restrict__ g,
                               const float* __restrict__ bt,
                               float* __restrict__ out, int n) {
    int wib = threadIdx.x >> 6;
    int lane = threadIdx.x & 63;
    int node = blockIdx.x * (blockDim.x >> 6) + wib;
    if (node >= n) return;

    float ax = 0.0f, ay = 0.0f;
    int beg = rowptr[node], end = rowptr[node + 1];
    int i = beg;
    for (; i + 4 <= end; i += 4) {
        int s0 = csr_src[i], s1 = csr_src[i + 1], s2 = csr_src[i + 2], s3 = csr_src[i + 3];
        float w0 = csr_w[i], w1 = csr_w[i + 1], w2 = csr_w[i + 2], w3 = csr_w[i + 3];
        unsigned int u0 = V[(size_t)s0 * 64 + lane];
        unsigned int u1 = V[(size_t)s1 * 64 + lane];
        unsigned int u2 = V[(size_t)s2 * 64 + lane];
        unsigned int u3 = V[(size_t)s3 * 64 + lane];
        ax += w0 * bf_lo(u0) + w1 * bf_lo(u1) + w2 * bf_lo(u2) + w3 * bf_lo(u3);
        ay += w0 * bf_hi(u0) + w1 * bf_hi(u1) + w2 * bf_hi(u2) + w3 * bf_hi(u3);
    }
    for (; i < end; ++i) {
        int s0 = csr_src[i];
        float w0 = csr_w[i];
        unsigned int u0 = V[(size_t)s0 * 64 + lane];
        ax += w0 * bf_lo(u0);
        ay += w0 * bf_hi(u0);
    }

    unsigned int au = U0[(size_t)node * 192 + lane];
    float px = ax + bf_lo(au) + b[2 * lane];
    float py = ay + bf_hi(au) + b[2 * lane + 1];

    float s = px + py;
#pragma unroll
    for (int o = 1; o < 64; o <<= 1) s += __shfl_xor(s, o);
    float mu = s * (1.0f / 128.0f);
    float dx = px - mu, dy = py - mu;
    float q = dx * dx + dy * dy;
#pragma unroll
    for (int o = 1; o < 64; o <<= 1) q += __shfl_xor(q, o);
    float rs = rsqrtf(q * (1.0f / 128.0f) + 1e-5f);

    float yx = dx * rs * g[2 * lane] + bt[2 * lane];
    float yy = dy * rs * g[2 * lane + 1] + bt[2 * lane + 1];
    yx = yx > 0.0f ? yx : 0.0f;
    yy = yy > 0.0f ? yy : 0.0f;
    float2 o2 = make_float2(yx, yy);
    *reinterpret_cast<float2*>(out + (size_t)node * 128 + 2 * lane) = o2;
}

// ---------------- gemm1: [x|T1|T2] @ Bt1^T + b1 -> LN -> ReLU -> bf16 h1 ----------------
// BM=64, BN=256 (full width). 4 waves; wave w owns cols [w*64, w*64+64) for all 64 rows.
// acc[4][4] = 64 VGPR/thread (round-5's 128-acc variant hit VGPR=196 -> 9% occupancy).

__global__ __launch_bounds__(256) void gemm1_ln_kernel(
        const unsigned short* __restrict__ A0, const unsigned short* __restrict__ A1,
        const unsigned short* __restrict__ A2, const unsigned short* __restrict__ Bt,
        const float* __restrict__ bias, const float* __restrict__ g,
        const float* __restrict__ bt, unsigned short* __restrict__ Hout, int N) {
    __shared__ __align__(16) unsigned short As[64][40];
    __shared__ __align__(16) unsigned short Bs[256][40];
    __shared__ float redS[4][64];
    __shared__ float redQ[4][64];

    int row0 = blockIdx.x * 64;
    int tid = threadIdx.x;
    int lane = tid & 63;
    int wave = tid >> 6;
    int wc = wave * 64;

    f32x4 acc[4][4];
#pragma unroll
    for (int i = 0; i < 4; ++i)
#pragma unroll
        for (int j = 0; j < 4; ++j) acc[i][j] = (f32x4)0.0f;

    int srow = tid >> 2;           // 0..63
    int sch = (tid & 3) * 8;       // bf16 col offset within 32

    for (int ks = 0; ks < 12; ++ks) {
        int kg = ks * 32;
        int seg = kg >> 7;
        int kk = kg & 127;
        const unsigned short* Aseg = (seg == 0) ? A0 : (seg == 1 ? A1 : A2);
        {
            int gr = row0 + srow;
            uint4 v = make_uint4(0u, 0u, 0u, 0u);
            if (gr < N) v = *reinterpret_cast<const uint4*>(Aseg + (size_t)gr * 128 + kk + sch);
            *reinterpret_cast<uint4*>(&As[srow][sch]) = v;
        }
#pragma unroll
        for (int p = 0; p < 4; ++p) {
            int rr = p * 64 + srow;
            uint4 v = *reinterpret_cast<const uint4*>(Bt + (size_t)rr * 384 + kg + sch);
            *reinterpret_cast<uint4*>(&Bs[rr][sch]) = v;
        }
        __syncthreads();

        int fr = lane & 15;
        int kh = (lane >> 4) * 8;
        bf16x8 af[4], bfr[4];
#pragma unroll
        for (int i = 0; i < 4; ++i)
            af[i] = *reinterpret_cast<const bf16x8*>(&As[i * 16 + fr][kh]);
#pragma unroll
        for (int j = 0; j < 4; ++j)
            bfr[j] = *reinterpret_cast<const bf16x8*>(&Bs[wc + j * 16 + fr][kh]);
#pragma unroll
        for (int i = 0; i < 4; ++i)
#pragma unroll
            for (int j = 0; j < 4; ++j)
                acc[i][j] = __builtin_amdgcn_mfma_f32_16x16x32_bf16(af[i], bfr[j], acc[i][j], 0, 0, 0);
        __syncthreads();
    }

    // ---- epilogue: bias, LN stats (4-wave reduce), normalize, relu, bf16 store ----
    int fc = lane & 15;
    int fq = lane >> 4;
    float bcol[4], gcol[4], btcol[4];
#pragma unroll
    for (int j = 0; j < 4; ++j) {
        int c = wc + j * 16 + fc;
        bcol[j] = bias[c];
        gcol[j] = g[c];
        btcol[j] = bt[c];
    }
#pragma unroll
    for (int i = 0; i < 4; ++i)
#pragma unroll
        for (int j = 0; j < 4; ++j)
#pragma unroll
            for (int v = 0; v < 4; ++v) acc[i][j][v] += bcol[j];

    // per-row partials over this wave's 64 cols; rows for (i,v) = i*16 + fq*4 + v
#pragma unroll
    for (int i = 0; i < 4; ++i) {
#pragma unroll
        for (int v = 0; v < 4; ++v) {
            float s = 0.0f, q = 0.0f;
#pragma unroll
            for (int j = 0; j < 4; ++j) {
                float val = acc[i][j][v];
                s += val;
                q += val * val;
            }
#pragma unroll
            for (int o = 1; o < 16; o <<= 1) {
                s += __shfl_xor(s, o);
                q += __shfl_xor(q, o);
            }
            if (fc == 0) {
                int r = i * 16 + fq * 4 + v;
                redS[wave][r] = s;
                redQ[wave][r] = q;
            }
        }
    }
    __syncthreads();

#pragma unroll
    for (int i = 0; i < 4; ++i) {
#pragma unroll
        for (int v = 0; v < 4; ++v) {
            int r = i * 16 + fq * 4 + v;
            float S = redS[0][r] + redS[1][r] + redS[2][r] + redS[3][r];
            float Q = redQ[0][r] + redQ[1][r] + redQ[2][r] + redQ[3][r];
            float mu = S * (1.0f / 256.0f);
            float var = Q * (1.0f / 256.0f) - mu * mu;
            float rsg = rsqrtf(var + 1e-5f);
            int gr = row0 + r;
            if (gr < N) {
#pragma unroll
                for (int j = 0; j < 4; ++j) {
                    float y = (acc[i][j][v] - mu) * rsg * gcol[j] + btcol[j];
                    y = y > 0.0f ? y : 0.0f;
                    Hout[(size_t)gr * 256 + wc + j * 16 + fc] = f2bf(y);
                }
            }
        }
    }
}

// ---------------- gemm2: h1 @ Btc^T -> U [N][384] bf16 (no bias) ----------------
// BM=64, BN=128, BK=32, 4 waves each 64 rows x 32 cols (acc[4][2]).

__global__ __launch_bounds__(256) void gemm2_kernel(
        const unsigned short* __restrict__ A, const unsigned short* __restrict__ Btc,
        unsigned short* __restrict__ U, int N, int ncol) {
    __shared__ __align__(16) unsigned short As[64][40];
    __shared__ __align__(16) unsigned short Bs[128][40];

    int nwg = gridDim.x;
    int q = nwg >> 3, r = nwg & 7;
    int xcd = blockIdx.x & 7, idx = blockIdx.x >> 3;
    int wgid = (xcd < r ? xcd * (q + 1) : r * (q + 1) + (xcd - r) * q) + idx;

    int row0 = (wgid / ncol) * 64;
    int col0 = (wgid % ncol) * 128;

    int tid = threadIdx.x;
    int lane = tid & 63;
    int wave = tid >> 6;
    int wc = wave * 32;

    f32x4 acc[4][2];
#pragma unroll
    for (int i = 0; i < 4; ++i)
#pragma unroll
        for (int j = 0; j < 2; ++j) acc[i][j] = (f32x4)0.0f;

    int srow = tid >> 2;
    int sch = (tid & 3) * 8;

    for (int ks = 0; ks < 8; ++ks) {
        int kg = ks * 32;
        {
            int gr = row0 + srow;
            uint4 v = make_uint4(0u, 0u, 0u, 0u);
            if (gr < N) v = *reinterpret_cast<const uint4*>(A + (size_t)gr * 256 + kg + sch);
            *reinterpret_cast<uint4*>(&As[srow][sch]) = v;
        }
#pragma unroll
        for (int p = 0; p < 2; ++p) {
            int rr = p * 64 + srow;
            uint4 v = *reinterpret_cast<const uint4*>(Btc + (size_t)(col0 + rr) * 256 + kg + sch);
            *reinterpret_cast<uint4*>(&Bs[rr][sch]) = v;
        }
        __syncthreads();

        int fr = lane & 15;
        int kh = (lane >> 4) * 8;
        bf16x8 af[4], bfr[2];
#pragma unroll
        for (int i = 0; i < 4; ++i)
            af[i] = *reinterpret_cast<const bf16x8*>(&As[i * 16 + fr][kh]);
#pragma unroll
        for (int j = 0; j < 2; ++j)
            bfr[j] = *reinterpret_cast<const bf16x8*>(&Bs[wc + j * 16 + fr][kh]);
#pragma unroll
        for (int i = 0; i < 4; ++i)
#pragma unroll
            for (int j = 0; j < 2; ++j)
                acc[i][j] = __builtin_amdgcn_mfma_f32_16x16x32_bf16(af[i], bfr[j], acc[i][j], 0, 0, 0);
        __syncthreads();
    }

    int fc = lane & 15;
    int frr = (lane >> 4) * 4;
#pragma unroll
    for (int i = 0; i < 4; ++i) {
#pragma unroll
        for (int v = 0; v < 4; ++v) {
            int gr = row0 + i * 16 + frr + v;
            if (gr < N) {
#pragma unroll
                for (int j = 0; j < 2; ++j) {
                    int gc = col0 + wc + j * 16 + fc;
                    U[(size_t)gr * 384 + gc] = f2bf(acc[i][j][v]);
                }
            }
        }
    }
}

// ---------------- host launch ----------------

extern "C" void kernel_launch(void* const* d_in, const int* in_sizes, int n_in,
                              void* d_out, int out_size, void* d_ws, size_t ws_size,
                              hipStream_t stream) {
    const int N = N_NODES;
    const float* x  = (const float*)d_in[0];
    const int*  ei  = (const int*)d_in[1];
    const float* W1 = (const float*)d_in[2];
    const float* b1 = (const float*)d_in[3];
    const float* g1 = (const float*)d_in[4];
    const float* bt1 = (const float*)d_in[5];
    const float* W2 = (const float*)d_in[6];
    const float* b2 = (const float*)d_in[7];
    const float* g2 = (const float*)d_in[8];
    const float* bt2 = (const float*)d_in[9];
    float* out = (float*)d_out;

    const int E = in_sizes[1] / 2;
    const int* src = ei;
    const int* dst = ei + E;

    // workspace carve (256B aligned)
    char* w = (char*)d_ws;
    auto alloc = [&](size_t bytes) { char* p = w; w += (bytes + 255) & ~(size_t)255; return p; };
    int* degi    = (int*)alloc((size_t)N * 4);
    int* cnt     = (int*)alloc((size_t)N * 4);
    int* excl    = (int*)alloc((size_t)N * 4);
    int* bsum    = (int*)alloc(64 * 4);
    int* rowptr  = (int*)alloc((size_t)(N + 1) * 4);
    int* cursor  = (int*)alloc((size_t)N * 4);
    int* csr_src = (int*)alloc((size_t)E * 4);
    float* dinv  = (float*)alloc((size_t)N * 4);
    float* csr_w = (float*)alloc((size_t)E * 4);
    unsigned short* xb  = (unsigned short*)alloc((size_t)N * 128 * 2);
    unsigned short* T1  = (unsigned short*)alloc((size_t)N * 128 * 2);
    unsigned short* T2  = (unsigned short*)alloc((size_t)N * 128 * 2);
    unsigned short* h1b = (unsigned short*)alloc((size_t)N * 256 * 2);
    unsigned short* U   = (unsigned short*)alloc((size_t)N * 384 * 2);
    unsigned short* V   = (unsigned short*)alloc((size_t)N * 128 * 2);
    unsigned short* Bt1 = (unsigned short*)alloc((size_t)256 * 384 * 2);
    unsigned short* Btc = (unsigned short*)alloc((size_t)384 * 256 * 2);
    (void)ws_size;

    const int TPB = 256;
    const int gridE = (E + TPB - 1) / TPB;
    const int gridN = (N + TPB - 1) / TPB;
    const int NB = (N + 1023) / 1024;

    // --- preprocessing ---
    hipLaunchKernelGGL(fill_zero_int_kernel, dim3(128), dim3(TPB), 0, stream, degi, (size_t)N);
    hipLaunchKernelGGL(fill_zero_int_kernel, dim3(128), dim3(TPB), 0, stream, cnt, (size_t)N);
    hipLaunchKernelGGL(hist_kernel, dim3(gridE), dim3(TPB), 0, stream, src, dst, degi, cnt, E);
    hipLaunchKernelGGL(dinv_kernel, dim3(gridN), dim3(TPB), 0, stream, degi, dinv, N);
    hipLaunchKernelGGL(scan1_kernel, dim3(NB), dim3(1024), 0, stream, cnt, excl, bsum, N);
    hipLaunchKernelGGL(scan2_kernel, dim3(1), dim3(64), 0, stream, bsum, NB);
    hipLaunchKernelGGL(scan3_kernel, dim3(NB), dim3(1024), 0, stream, excl, bsum, cnt, rowptr, cursor, N);
    hipLaunchKernelGGL(csr_build_kernel, dim3(gridE), dim3(TPB), 0, stream,
                       src, dst, dinv, cursor, csr_src, csr_w, E);
    hipLaunchKernelGGL(cvt_bf_kernel, dim3((N * 128 / 4 + TPB - 1) / TPB), dim3(TPB), 0, stream,
                       x, xb, (size_t)N * 128 / 4);
    hipLaunchKernelGGL(wtrans1_kernel, dim3((3 * 128 * 256 + TPB - 1) / TPB), dim3(TPB), 0, stream, W1, Bt1);
    hipLaunchKernelGGL(wtrans2_kernel, dim3((384 * 256 + TPB - 1) / TPB), dim3(TPB), 0, stream, W2, Btc);

    const int gridW = (N + 3) / 4;   // 4 waves per block, 1 node per wave

    // --- layer 1: props (D=128) then GEMM+LN ---
    hipLaunchKernelGGL(prop_kernel, dim3(gridW), dim3(TPB), 0, stream,
                       (const unsigned int*)xb, 64, rowptr, csr_src, csr_w,
                       (const unsigned int*)nullptr, 0, 1.0f, 0.0f,
                       (unsigned int*)T1, N);
    hipLaunchKernelGGL(prop_kernel, dim3(gridW), dim3(TPB), 0, stream,
                       (const unsigned int*)T1, 64, rowptr, csr_src, csr_w,
                       (const unsigned int*)xb, 64, 2.0f, -1.0f,
                       (unsigned int*)T2, N);
    hipLaunchKernelGGL(gemm1_ln_kernel, dim3((N + 63) / 64), dim3(256), 0, stream,
                       xb, T1, T2, Bt1, b1, g1, bt1, h1b, N);

    // --- layer 2: GEMM first, then props in 128-dim ---
    {
        int nrow = (N + 63) / 64, ncol = 3;
        hipLaunchKernelGGL(gemm2_kernel, dim3(nrow * ncol), dim3(256), 0, stream,
                           h1b, Btc, U, N, ncol);
    }
    // v = L(u2) + u1   (u2 = U cols 256..383, u1 = U cols 128..255)
    hipLaunchKernelGGL(prop_kernel, dim3(gridW), dim3(TPB), 0, stream,
                       (const unsigned int*)U + 128, 192, rowptr, csr_src, csr_w,
                       (const unsigned int*)U + 64, 192, 1.0f, 1.0f,
                       (unsigned int*)V, N);
    // out = LN(L(v) + u0 + b2) -> relu
    hipLaunchKernelGGL(prop_ln_kernel, dim3(gridW), dim3(TPB), 0, stream,
                       (const unsigned int*)V, rowptr, csr_src, csr_w,
                       (const unsigned int*)U, b2, g2, bt2, out, N);
}

// Round 7
// 281.634 us; speedup vs baseline: 8.6377x; 1.3122x over previous
//
#include <hip/hip_runtime.h>

#define N_NODES 50000
#define NRANGE 8
#define RNG 6400          // NRANGE*RNG = 51200 >= N
#define TOTR (NRANGE * RNG)
#define NCHUNK 32

using f32x4  = __attribute__((ext_vector_type(4))) float;
using bf16x8 = __attribute__((ext_vector_type(8))) __bf16;

__device__ __forceinline__ unsigned short f2bf(float f) {
    unsigned int b = __float_as_uint(f);
    unsigned int r = (b + 0x7FFFu + ((b >> 16) & 1u)) >> 16;   // RNE
    return (unsigned short)r;
}
__device__ __forceinline__ float bf_lo(unsigned int u) { return __uint_as_float(u << 16); }
__device__ __forceinline__ float bf_hi(unsigned int u) { return __uint_as_float(u & 0xFFFF0000u); }
__device__ __forceinline__ unsigned int packbf(float x, float y) {
    return ((unsigned int)f2bf(y) << 16) | f2bf(x);
}

// ---------------- utility ----------------

__global__ void cvt_bf_kernel(const float* __restrict__ in, unsigned short* __restrict__ out, size_t n4) {
    size_t i = (size_t)blockIdx.x * blockDim.x + threadIdx.x;
    if (i < n4) {
        float4 v = *reinterpret_cast<const float4*>(in + i * 4);
        ushort4 o;
        o.x = f2bf(v.x); o.y = f2bf(v.y); o.z = f2bf(v.z); o.w = f2bf(v.w);
        *reinterpret_cast<ushort4*>(out + i * 4) = o;
    }
}

// W1: [3][128][256] f32 -> Bt1: [256][384] bf16
__global__ void wtrans1_kernel(const float* __restrict__ W, unsigned short* __restrict__ Bt) {
    int i = blockIdx.x * blockDim.x + threadIdx.x;
    if (i < 3 * 128 * 256) {
        int c = i % 256;
        int kg = i / 256;
        Bt[(size_t)c * 384 + kg] = f2bf(W[(size_t)kg * 256 + c]);
    }
}

// W2: [3][256][128] f32 -> Btc: [384][256] bf16 with cols [W0-W2 | W1 | 2*W2]
__global__ void wtrans2_kernel(const float* __restrict__ W, unsigned short* __restrict__ Btc) {
    int i = blockIdx.x * blockDim.x + threadIdx.x;
    if (i < 384 * 256) {
        int k = i % 256;
        int cc = i / 256;
        int seg = cc >> 7, c = cc & 127;
        float v;
        if (seg == 0)      v = W[(size_t)k * 128 + c] - W[(size_t)(2 * 256 + k) * 128 + c];
        else if (seg == 1) v = W[(size_t)(256 + k) * 128 + c];
        else               v = 2.0f * W[(size_t)(2 * 256 + k) * 128 + c];
        Btc[(size_t)cc * 256 + k] = f2bf(v);
    }
}

// ---------------- edge preprocessing: privatized LDS histograms ----------------
// Global scattered atomics run at ~24G/s memory-side (round-6: hist 66us,
// WRITE_SIZE 1.6M x 32B). LDS-privatize instead: grid [NCHUNK][NRANGE], each
// block histograms its edge chunk for its node range in LDS, flushes
// non-atomically to per-chunk partials.

__global__ __launch_bounds__(1024) void hist_priv_kernel(
        const int* __restrict__ src, const int* __restrict__ dst, int E, int chunk,
        int* __restrict__ pd, int* __restrict__ pc) {     // [NCHUNK][TOTR] each
    __shared__ int lhS[RNG];
    __shared__ int lhD[RNG];
    int r = blockIdx.x & (NRANGE - 1);
    int c = blockIdx.x >> 3;               // NRANGE == 8
    int lo = r * RNG;
    for (int i = threadIdx.x; i < RNG; i += 1024) { lhS[i] = 0; lhD[i] = 0; }
    __syncthreads();
    int e0 = c * chunk, e1 = min(e0 + chunk, E);
    for (int e = e0 + threadIdx.x; e < e1; e += 1024) {
        int s = src[e], d = dst[e];
        if (s != d) {
            unsigned int sr = (unsigned int)(s - lo);
            unsigned int dr = (unsigned int)(d - lo);
            if (sr < RNG) atomicAdd(&lhS[sr], 1);
            if (dr < RNG) atomicAdd(&lhD[dr], 1);
        }
    }
    __syncthreads();
    int base = c * TOTR + lo;
    for (int i = threadIdx.x; i < RNG; i += 1024) {
        pd[base + i] = lhS[i];
        pc[base + i] = lhD[i];
    }
}

// Per node: sum partial deg -> dinv; exclusive-scan partial dst-counts across
// chunks in place (pc[c][i] becomes chunk c's slot offset for node i) -> cnt.
__global__ void reduce_chunks_kernel(int* __restrict__ pd, int* __restrict__ pc,
                                     float* __restrict__ dinv, int* __restrict__ cnt, int n) {
    int i = blockIdx.x * blockDim.x + threadIdx.x;
    if (i >= TOTR) return;
    int degs = 0;
#pragma unroll 8
    for (int c = 0; c < NCHUNK; ++c) degs += pd[c * TOTR + i];
    int run = 0;
#pragma unroll 8
    for (int c = 0; c < NCHUNK; ++c) {
        int v = pc[c * TOTR + i];
        pc[c * TOTR + i] = run;
        run += v;
    }
    if (i < n) {
        dinv[i] = degs > 0 ? rsqrtf((float)degs) : 0.0f;
        cnt[i] = run;
    }
}

// --- 3-phase scan over cnt -> rowptr ---

__global__ __launch_bounds__(1024) void scan1_kernel(const int* __restrict__ cnt,
                                                     int* __restrict__ excl,
                                                     int* __restrict__ bsum, int n) {
    __shared__ int wsum[16];
    int tid = threadIdx.x, lane = tid & 63, wid = tid >> 6;
    int i = blockIdx.x * 1024 + tid;
    int v = (i < n) ? cnt[i] : 0;
    int x = v;
#pragma unroll
    for (int o = 1; o < 64; o <<= 1) { int y = __shfl_up(x, o); if (lane >= o) x += y; }
    if (lane == 63) wsum[wid] = x;
    __syncthreads();
    if (tid < 16) {
        int s = wsum[tid];
#pragma unroll
        for (int o = 1; o < 16; o <<= 1) { int y = __shfl_up(s, o); if (tid >= o) s += y; }
        wsum[tid] = s;
    }
    __syncthreads();
    int base = (wid > 0 ? wsum[wid - 1] : 0);
    if (i < n) excl[i] = base + x - v;
    if (tid == 0) bsum[blockIdx.x] = wsum[15];
}

__global__ void scan2_kernel(int* __restrict__ bsum, int nb) {
    int t = threadIdx.x;                   // single wave, nb <= 64
    int v = (t < nb) ? bsum[t] : 0;
    int x = v;
#pragma unroll
    for (int o = 1; o < 64; o <<= 1) { int y = __shfl_up(x, o); if (t >= o) x += y; }
    if (t < nb) bsum[t] = x - v;           // exclusive
}

__global__ __launch_bounds__(1024) void scan3_kernel(const int* __restrict__ excl,
                                                     const int* __restrict__ bsum,
                                                     const int* __restrict__ cnt,
                                                     int* __restrict__ rowptr, int n) {
    int i = blockIdx.x * 1024 + threadIdx.x;
    if (i < n) {
        int rp = excl[i] + bsum[blockIdx.x];
        rowptr[i] = rp;
        if (i == n - 1) rowptr[n] = rp + cnt[i];
    }
}

// CSR placement with LDS cursors: block (range r, chunk c) places its chunk's
// edges whose dst is in range, at rowptr[d] + pc[c][d] + LDS-local rank.
__global__ __launch_bounds__(1024) void csr_place_kernel(
        const int* __restrict__ src, const int* __restrict__ dst, int E, int chunk,
        const int* __restrict__ pc, const int* __restrict__ rowptr,
        const float* __restrict__ dinv,
        int* __restrict__ csr_src, float* __restrict__ csr_w, int n) {
    __shared__ int cur[RNG];
    __shared__ float dloc[RNG];
    int r = blockIdx.x & (NRANGE - 1);
    int c = blockIdx.x >> 3;
    int lo = r * RNG;
    for (int i = threadIdx.x; i < RNG; i += 1024) {
        int node = lo + i;
        if (node < n) {
            cur[i] = rowptr[node] + pc[c * TOTR + node];
            dloc[i] = dinv[node];
        }
    }
    __syncthreads();
    int e0 = c * chunk, e1 = min(e0 + chunk, E);
    for (int e = e0 + threadIdx.x; e < e1; e += 1024) {
        int s = src[e], d = dst[e];
        unsigned int dr = (unsigned int)(d - lo);
        if (s != d && dr < RNG) {
            int pos = atomicAdd(&cur[dr], 1);
            csr_src[pos] = s;
            csr_w[pos] = -dinv[s] * dloc[dr];
        }
    }
}

// ---------------- CSR gather propagation, D=128 bf16, f32 accum ----------------

__global__ void prop_kernel(const unsigned int* __restrict__ H, int hs,
                            const int* __restrict__ rowptr,
                            const int* __restrict__ csr_src,
                            const float* __restrict__ csr_w,
                            const unsigned int* __restrict__ add, int as_,
                            float scale, float coef,
                            unsigned int* __restrict__ out, int n) {
    int wib = threadIdx.x >> 6;
    int lane = threadIdx.x & 63;
    int node = blockIdx.x * (blockDim.x >> 6) + wib;
    if (node >= n) return;

    float ax = 0.0f, ay = 0.0f;
    int beg = rowptr[node], end = rowptr[node + 1];
    int i = beg;
    for (; i + 4 <= end; i += 4) {
        int s0 = csr_src[i], s1 = csr_src[i + 1], s2 = csr_src[i + 2], s3 = csr_src[i + 3];
        float w0 = csr_w[i], w1 = csr_w[i + 1], w2 = csr_w[i + 2], w3 = csr_w[i + 3];
        unsigned int u0 = H[(size_t)s0 * hs + lane];
        unsigned int u1 = H[(size_t)s1 * hs + lane];
        unsigned int u2 = H[(size_t)s2 * hs + lane];
        unsigned int u3 = H[(size_t)s3 * hs + lane];
        ax += w0 * bf_lo(u0) + w1 * bf_lo(u1) + w2 * bf_lo(u2) + w3 * bf_lo(u3);
        ay += w0 * bf_hi(u0) + w1 * bf_hi(u1) + w2 * bf_hi(u2) + w3 * bf_hi(u3);
    }
    for (; i < end; ++i) {
        int s0 = csr_src[i];
        float w0 = csr_w[i];
        unsigned int u0 = H[(size_t)s0 * hs + lane];
        ax += w0 * bf_lo(u0);
        ay += w0 * bf_hi(u0);
    }

    float vx = scale * ax, vy = scale * ay;
    if (add) {
        unsigned int au = add[(size_t)node * as_ + lane];
        vx += coef * bf_lo(au);
        vy += coef * bf_hi(au);
    }
    out[(size_t)node * 64 + lane] = packbf(vx, vy);
}

// final prop + bias + LayerNorm + ReLU -> f32 out.  V stride 64, U0 stride 192.
__global__ void prop_ln_kernel(const unsigned int* __restrict__ V,
                               const int* __restrict__ rowptr,
                               const int* __restrict__ csr_src,
                               const float* __restrict__ csr_w,
                               const unsigned int* __restrict__ U0,
                               const float* __restrict__ b,
                               const float* __restrict__ g,
                               const float* __restrict__ bt,
                               float* __restrict__ out, int n) {
    int wib = threadIdx.x >> 6;
    int lane = threadIdx.x & 63;
    int node = blockIdx.x * (blockDim.x >> 6) + wib;
    if (node >= n) return;

    float ax = 0.0f, ay = 0.0f;
    int beg = rowptr[node], end = rowptr[node + 1];
    int i = beg;
    for (; i + 4 <= end; i += 4) {
        int s0 = csr_src[i], s1 = csr_src[i + 1], s2 = csr_src[i + 2], s3 = csr_src[i + 3];
        float w0 = csr_w[i], w1 = csr_w[i + 1], w2 = csr_w[i + 2], w3 = csr_w[i + 3];
        unsigned int u0 = V[(size_t)s0 * 64 + lane];
        unsigned int u1 = V[(size_t)s1 * 64 + lane];
        unsigned int u2 = V[(size_t)s2 * 64 + lane];
        unsigned int u3 = V[(size_t)s3 * 64 + lane];
        ax += w0 * bf_lo(u0) + w1 * bf_lo(u1) + w2 * bf_lo(u2) + w3 * bf_lo(u3);
        ay += w0 * bf_hi(u0) + w1 * bf_hi(u1) + w2 * bf_hi(u2) + w3 * bf_hi(u3);
    }
    for (; i < end; ++i) {
        int s0 = csr_src[i];
        float w0 = csr_w[i];
        unsigned int u0 = V[(size_t)s0 * 64 + lane];
        ax += w0 * bf_lo(u0);
        ay += w0 * bf_hi(u0);
    }

    unsigned int au = U0[(size_t)node * 192 + lane];
    float px = ax + bf_lo(au) + b[2 * lane];
    float py = ay + bf_hi(au) + b[2 * lane + 1];

    float s = px + py;
#pragma unroll
    for (int o = 1; o < 64; o <<= 1) s += __shfl_xor(s, o);
    float mu = s * (1.0f / 128.0f);
    float dx = px - mu, dy = py - mu;
    float q = dx * dx + dy * dy;
#pragma unroll
    for (int o = 1; o < 64; o <<= 1) q += __shfl_xor(q, o);
    float rs = rsqrtf(q * (1.0f / 128.0f) + 1e-5f);

    float yx = dx * rs * g[2 * lane] + bt[2 * lane];
    float yy = dy * rs * g[2 * lane + 1] + bt[2 * lane + 1];
    yx = yx > 0.0f ? yx : 0.0f;
    yy = yy > 0.0f ? yy : 0.0f;
    float2 o2 = make_float2(yx, yy);
    *reinterpret_cast<float2*>(out + (size_t)node * 128 + 2 * lane) = o2;
}

// ---------------- gemm1: [x|T1|T2] @ Bt1^T + b1 -> LN -> ReLU -> bf16 h1 ----------------
// BM=64, BN=256. 4 waves; wave w owns cols [w*64, w*64+64).

__global__ __launch_bounds__(256) void gemm1_ln_kernel(
        const unsigned short* __restrict__ A0, const unsigned short* __restrict__ A1,
        const unsigned short* __restrict__ A2, const unsigned short* __restrict__ Bt,
        const float* __restrict__ bias, const float* __restrict__ g,
        const float* __restrict__ bt, unsigned short* __restrict__ Hout, int N) {
    __shared__ __align__(16) unsigned short As[64][40];
    __shared__ __align__(16) unsigned short Bs[256][40];
    __shared__ float redS[4][64];
    __shared__ float redQ[4][64];

    int row0 = blockIdx.x * 64;
    int tid = threadIdx.x;
    int lane = tid & 63;
    int wave = tid >> 6;
    int wc = wave * 64;

    f32x4 acc[4][4];
#pragma unroll
    for (int i = 0; i < 4; ++i)
#pragma unroll
        for (int j = 0; j < 4; ++j) acc[i][j] = (f32x4)0.0f;

    int srow = tid >> 2;
    int sch = (tid & 3) * 8;

    for (int ks = 0; ks < 12; ++ks) {
        int kg = ks * 32;
        int seg = kg >> 7;
        int kk = kg & 127;
        const unsigned short* Aseg = (seg == 0) ? A0 : (seg == 1 ? A1 : A2);
        {
            int gr = row0 + srow;
            uint4 v = make_uint4(0u, 0u, 0u, 0u);
            if (gr < N) v = *reinterpret_cast<const uint4*>(Aseg + (size_t)gr * 128 + kk + sch);
            *reinterpret_cast<uint4*>(&As[srow][sch]) = v;
        }
#pragma unroll
        for (int p = 0; p < 4; ++p) {
            int rr = p * 64 + srow;
            uint4 v = *reinterpret_cast<const uint4*>(Bt + (size_t)rr * 384 + kg + sch);
            *reinterpret_cast<uint4*>(&Bs[rr][sch]) = v;
        }
        __syncthreads();

        int fr = lane & 15;
        int kh = (lane >> 4) * 8;
        bf16x8 af[4], bfr[4];
#pragma unroll
        for (int i = 0; i < 4; ++i)
            af[i] = *reinterpret_cast<const bf16x8*>(&As[i * 16 + fr][kh]);
#pragma unroll
        for (int j = 0; j < 4; ++j)
            bfr[j] = *reinterpret_cast<const bf16x8*>(&Bs[wc + j * 16 + fr][kh]);
#pragma unroll
        for (int i = 0; i < 4; ++i)
#pragma unroll
            for (int j = 0; j < 4; ++j)
                acc[i][j] = __builtin_amdgcn_mfma_f32_16x16x32_bf16(af[i], bfr[j], acc[i][j], 0, 0, 0);
        __syncthreads();
    }

    int fc = lane & 15;
    int fq = lane >> 4;
    float bcol[4], gcol[4], btcol[4];
#pragma unroll
    for (int j = 0; j < 4; ++j) {
        int c = wc + j * 16 + fc;
        bcol[j] = bias[c];
        gcol[j] = g[c];
        btcol[j] = bt[c];
    }
#pragma unroll
    for (int i = 0; i < 4; ++i)
#pragma unroll
        for (int j = 0; j < 4; ++j)
#pragma unroll
            for (int v = 0; v < 4; ++v) acc[i][j][v] += bcol[j];

#pragma unroll
    for (int i = 0; i < 4; ++i) {
#pragma unroll
        for (int v = 0; v < 4; ++v) {
            float s = 0.0f, q = 0.0f;
#pragma unroll
            for (int j = 0; j < 4; ++j) {
                float val = acc[i][j][v];
                s += val;
                q += val * val;
            }
#pragma unroll
            for (int o = 1; o < 16; o <<= 1) {
                s += __shfl_xor(s, o);
                q += __shfl_xor(q, o);
            }
            if (fc == 0) {
                int r = i * 16 + fq * 4 + v;
                redS[wave][r] = s;
                redQ[wave][r] = q;
            }
        }
    }
    __syncthreads();

#pragma unroll
    for (int i = 0; i < 4; ++i) {
#pragma unroll
        for (int v = 0; v < 4; ++v) {
            int r = i * 16 + fq * 4 + v;
            float S = redS[0][r] + redS[1][r] + redS[2][r] + redS[3][r];
            float Q = redQ[0][r] + redQ[1][r] + redQ[2][r] + redQ[3][r];
            float mu = S * (1.0f / 256.0f);
            float var = Q * (1.0f / 256.0f) - mu * mu;
            float rsg = rsqrtf(var + 1e-5f);
            int gr = row0 + r;
            if (gr < N) {
#pragma unroll
                for (int j = 0; j < 4; ++j) {
                    float y = (acc[i][j][v] - mu) * rsg * gcol[j] + btcol[j];
                    y = y > 0.0f ? y : 0.0f;
                    Hout[(size_t)gr * 256 + wc + j * 16 + fc] = f2bf(y);
                }
            }
        }
    }
}

// ---------------- gemm2: h1 @ Btc^T -> U [N][384] bf16 ----------------

__global__ __launch_bounds__(256) void gemm2_kernel(
        const unsigned short* __restrict__ A, const unsigned short* __restrict__ Btc,
        unsigned short* __restrict__ U, int N, int ncol) {
    __shared__ __align__(16) unsigned short As[64][40];
    __shared__ __align__(16) unsigned short Bs[128][40];

    int nwg = gridDim.x;
    int q = nwg >> 3, r = nwg & 7;
    int xcd = blockIdx.x & 7, idx = blockIdx.x >> 3;
    int wgid = (xcd < r ? xcd * (q + 1) : r * (q + 1) + (xcd - r) * q) + idx;

    int row0 = (wgid / ncol) * 64;
    int col0 = (wgid % ncol) * 128;

    int tid = threadIdx.x;
    int lane = tid & 63;
    int wave = tid >> 6;
    int wc = wave * 32;

    f32x4 acc[4][2];
#pragma unroll
    for (int i = 0; i < 4; ++i)
#pragma unroll
        for (int j = 0; j < 2; ++j) acc[i][j] = (f32x4)0.0f;

    int srow = tid >> 2;
    int sch = (tid & 3) * 8;

    for (int ks = 0; ks < 8; ++ks) {
        int kg = ks * 32;
        {
            int gr = row0 + srow;
            uint4 v = make_uint4(0u, 0u, 0u, 0u);
            if (gr < N) v = *reinterpret_cast<const uint4*>(A + (size_t)gr * 256 + kg + sch);
            *reinterpret_cast<uint4*>(&As[srow][sch]) = v;
        }
#pragma unroll
        for (int p = 0; p < 2; ++p) {
            int rr = p * 64 + srow;
            uint4 v = *reinterpret_cast<const uint4*>(Btc + (size_t)(col0 + rr) * 256 + kg + sch);
            *reinterpret_cast<uint4*>(&Bs[rr][sch]) = v;
        }
        __syncthreads();

        int fr = lane & 15;
        int kh = (lane >> 4) * 8;
        bf16x8 af[4], bfr[2];
#pragma unroll
        for (int i = 0; i < 4; ++i)
            af[i] = *reinterpret_cast<const bf16x8*>(&As[i * 16 + fr][kh]);
#pragma unroll
        for (int j = 0; j < 2; ++j)
            bfr[j] = *reinterpret_cast<const bf16x8*>(&Bs[wc + j * 16 + fr][kh]);
#pragma unroll
        for (int i = 0; i < 4; ++i)
#pragma unroll
            for (int j = 0; j < 2; ++j)
                acc[i][j] = __builtin_amdgcn_mfma_f32_16x16x32_bf16(af[i], bfr[j], acc[i][j], 0, 0, 0);
        __syncthreads();
    }

    int fc = lane & 15;
    int frr = (lane >> 4) * 4;
#pragma unroll
    for (int i = 0; i < 4; ++i) {
#pragma unroll
        for (int v = 0; v < 4; ++v) {
            int gr = row0 + i * 16 + frr + v;
            if (gr < N) {
#pragma unroll
                for (int j = 0; j < 2; ++j) {
                    int gc = col0 + wc + j * 16 + fc;
                    U[(size_t)gr * 384 + gc] = f2bf(acc[i][j][v]);
                }
            }
        }
    }
}

// ---------------- host launch ----------------

extern "C" void kernel_launch(void* const* d_in, const int* in_sizes, int n_in,
                              void* d_out, int out_size, void* d_ws, size_t ws_size,
                              hipStream_t stream) {
    const int N = N_NODES;
    const float* x  = (const float*)d_in[0];
    const int*  ei  = (const int*)d_in[1];
    const float* W1 = (const float*)d_in[2];
    const float* b1 = (const float*)d_in[3];
    const float* g1 = (const float*)d_in[4];
    const float* bt1 = (const float*)d_in[5];
    const float* W2 = (const float*)d_in[6];
    const float* b2 = (const float*)d_in[7];
    const float* g2 = (const float*)d_in[8];
    const float* bt2 = (const float*)d_in[9];
    float* out = (float*)d_out;

    const int E = in_sizes[1] / 2;
    const int* src = ei;
    const int* dst = ei + E;
    const int chunk = (E + NCHUNK - 1) / NCHUNK;

    // workspace carve (256B aligned)
    char* w = (char*)d_ws;
    auto alloc = [&](size_t bytes) { char* p = w; w += (bytes + 255) & ~(size_t)255; return p; };
    int* pd      = (int*)alloc((size_t)NCHUNK * TOTR * 4);
    int* pc      = (int*)alloc((size_t)NCHUNK * TOTR * 4);
    int* cnt     = (int*)alloc((size_t)N * 4);
    int* excl    = (int*)alloc((size_t)N * 4);
    int* bsum    = (int*)alloc(64 * 4);
    int* rowptr  = (int*)alloc((size_t)(N + 1) * 4);
    int* csr_src = (int*)alloc((size_t)E * 4);
    float* dinv  = (float*)alloc((size_t)N * 4);
    float* csr_w = (float*)alloc((size_t)E * 4);
    unsigned short* xb  = (unsigned short*)alloc((size_t)N * 128 * 2);
    unsigned short* T1  = (unsigned short*)alloc((size_t)N * 128 * 2);
    unsigned short* T2  = (unsigned short*)alloc((size_t)N * 128 * 2);
    unsigned short* h1b = (unsigned short*)alloc((size_t)N * 256 * 2);
    unsigned short* U   = (unsigned short*)alloc((size_t)N * 384 * 2);
    unsigned short* V   = (unsigned short*)alloc((size_t)N * 128 * 2);
    unsigned short* Bt1 = (unsigned short*)alloc((size_t)256 * 384 * 2);
    unsigned short* Btc = (unsigned short*)alloc((size_t)384 * 256 * 2);
    (void)ws_size;

    const int TPB = 256;
    const int NB = (N + 1023) / 1024;

    // --- preprocessing: privatized histograms + atomic-free CSR placement ---
    hipLaunchKernelGGL(hist_priv_kernel, dim3(NCHUNK * NRANGE), dim3(1024), 0, stream,
                       src, dst, E, chunk, pd, pc);
    hipLaunchKernelGGL(reduce_chunks_kernel, dim3((TOTR + TPB - 1) / TPB), dim3(TPB), 0, stream,
                       pd, pc, dinv, cnt, N);
    hipLaunchKernelGGL(scan1_kernel, dim3(NB), dim3(1024), 0, stream, cnt, excl, bsum, N);
    hipLaunchKernelGGL(scan2_kernel, dim3(1), dim3(64), 0, stream, bsum, NB);
    hipLaunchKernelGGL(scan3_kernel, dim3(NB), dim3(1024), 0, stream, excl, bsum, cnt, rowptr, N);
    hipLaunchKernelGGL(csr_place_kernel, dim3(NCHUNK * NRANGE), dim3(1024), 0, stream,
                       src, dst, E, chunk, pc, rowptr, dinv, csr_src, csr_w, N);
    hipLaunchKernelGGL(cvt_bf_kernel, dim3((N * 128 / 4 + TPB - 1) / TPB), dim3(TPB), 0, stream,
                       x, xb, (size_t)N * 128 / 4);
    hipLaunchKernelGGL(wtrans1_kernel, dim3((3 * 128 * 256 + TPB - 1) / TPB), dim3(TPB), 0, stream, W1, Bt1);
    hipLaunchKernelGGL(wtrans2_kernel, dim3((384 * 256 + TPB - 1) / TPB), dim3(TPB), 0, stream, W2, Btc);

    const int gridW = (N + 3) / 4;   // 4 waves per block, 1 node per wave

    // --- layer 1: props (D=128) then GEMM+LN ---
    hipLaunchKernelGGL(prop_kernel, dim3(gridW), dim3(TPB), 0, stream,
                       (const unsigned int*)xb, 64, rowptr, csr_src, csr_w,
                       (const unsigned int*)nullptr, 0, 1.0f, 0.0f,
                       (unsigned int*)T1, N);
    hipLaunchKernelGGL(prop_kernel, dim3(gridW), dim3(TPB), 0, stream,
                       (const unsigned int*)T1, 64, rowptr, csr_src, csr_w,
                       (const unsigned int*)xb, 64, 2.0f, -1.0f,
                       (unsigned int*)T2, N);
    hipLaunchKernelGGL(gemm1_ln_kernel, dim3((N + 63) / 64), dim3(256), 0, stream,
                       xb, T1, T2, Bt1, b1, g1, bt1, h1b, N);

    // --- layer 2: GEMM first, then props in 128-dim ---
    {
        int nrow = (N + 63) / 64, ncol = 3;
        hipLaunchKernelGGL(gemm2_kernel, dim3(nrow * ncol), dim3(256), 0, stream,
                           h1b, Btc, U, N, ncol);
    }
    // v = L(u2) + u1
    hipLaunchKernelGGL(prop_kernel, dim3(gridW), dim3(TPB), 0, stream,
                       (const unsigned int*)U + 128, 192, rowptr, csr_src, csr_w,
                       (const unsigned int*)U + 64, 192, 1.0f, 1.0f,
                       (unsigned int*)V, N);
    // out = LN(L(v) + u0 + b2) -> relu
    hipLaunchKernelGGL(prop_ln_kernel, dim3(gridW), dim3(TPB), 0, stream,
                       (const unsigned int*)V, rowptr, csr_src, csr_w,
                       (const unsigned int*)U, b2, g2, bt2, out, N);
}

// Round 8
// 278.019 us; speedup vs baseline: 8.7500x; 1.0130x over previous
//
#include <hip/hip_runtime.h>

#define N_NODES 50000
#define NRANGE 8
#define RNG 6400          // NRANGE*RNG = 51200 >= N
#define TOTR (NRANGE * RNG)
#define NCHUNK 32

using f32x4  = __attribute__((ext_vector_type(4))) float;
using bf16x8 = __attribute__((ext_vector_type(8))) __bf16;

__device__ __forceinline__ unsigned short f2bf(float f) {
    unsigned int b = __float_as_uint(f);
    unsigned int r = (b + 0x7FFFu + ((b >> 16) & 1u)) >> 16;   // RNE
    return (unsigned short)r;
}
__device__ __forceinline__ float bf_lo(unsigned int u) { return __uint_as_float(u << 16); }
__device__ __forceinline__ float bf_hi(unsigned int u) { return __uint_as_float(u & 0xFFFF0000u); }
__device__ __forceinline__ unsigned int packbf(float x, float y) {
    return ((unsigned int)f2bf(y) << 16) | f2bf(x);
}

// ---------------- utility ----------------

__global__ void cvt_bf_kernel(const float* __restrict__ in, unsigned short* __restrict__ out, size_t n4) {
    size_t i = (size_t)blockIdx.x * blockDim.x + threadIdx.x;
    if (i < n4) {
        float4 v = *reinterpret_cast<const float4*>(in + i * 4);
        ushort4 o;
        o.x = f2bf(v.x); o.y = f2bf(v.y); o.z = f2bf(v.z); o.w = f2bf(v.w);
        *reinterpret_cast<ushort4*>(out + i * 4) = o;
    }
}

// W1: [3][128][256] f32 -> Bt1: [256][384] bf16
__global__ void wtrans1_kernel(const float* __restrict__ W, unsigned short* __restrict__ Bt) {
    int i = blockIdx.x * blockDim.x + threadIdx.x;
    if (i < 3 * 128 * 256) {
        int c = i % 256;
        int kg = i / 256;
        Bt[(size_t)c * 384 + kg] = f2bf(W[(size_t)kg * 256 + c]);
    }
}

// W2: [3][256][128] f32 -> Btc: [384][256] bf16 with cols [W0-W2 | W1 | 2*W2]
__global__ void wtrans2_kernel(const float* __restrict__ W, unsigned short* __restrict__ Btc) {
    int i = blockIdx.x * blockDim.x + threadIdx.x;
    if (i < 384 * 256) {
        int k = i % 256;
        int cc = i / 256;
        int seg = cc >> 7, c = cc & 127;
        float v;
        if (seg == 0)      v = W[(size_t)k * 128 + c] - W[(size_t)(2 * 256 + k) * 128 + c];
        else if (seg == 1) v = W[(size_t)(256 + k) * 128 + c];
        else               v = 2.0f * W[(size_t)(2 * 256 + k) * 128 + c];
        Btc[(size_t)cc * 256 + k] = f2bf(v);
    }
}

// ---------------- edge preprocessing: privatized LDS histograms ----------------

__global__ __launch_bounds__(1024) void hist_priv_kernel(
        const int* __restrict__ src, const int* __restrict__ dst, int E, int chunk,
        int* __restrict__ pd, int* __restrict__ pc) {     // [NCHUNK][TOTR] each
    __shared__ int lhS[RNG];
    __shared__ int lhD[RNG];
    int r = blockIdx.x & (NRANGE - 1);
    int c = blockIdx.x >> 3;               // NRANGE == 8
    int lo = r * RNG;
    for (int i = threadIdx.x; i < RNG; i += 1024) { lhS[i] = 0; lhD[i] = 0; }
    __syncthreads();
    int e0 = c * chunk, e1 = min(e0 + chunk, E);
    for (int e = e0 + threadIdx.x; e < e1; e += 1024) {
        int s = src[e], d = dst[e];
        if (s != d) {
            unsigned int sr = (unsigned int)(s - lo);
            unsigned int dr = (unsigned int)(d - lo);
            if (sr < RNG) atomicAdd(&lhS[sr], 1);
            if (dr < RNG) atomicAdd(&lhD[dr], 1);
        }
    }
    __syncthreads();
    int base = c * TOTR + lo;
    for (int i = threadIdx.x; i < RNG; i += 1024) {
        pd[base + i] = lhS[i];
        pc[base + i] = lhD[i];
    }
}

__global__ void reduce_chunks_kernel(int* __restrict__ pd, int* __restrict__ pc,
                                     float* __restrict__ dinv, int* __restrict__ cnt, int n) {
    int i = blockIdx.x * blockDim.x + threadIdx.x;
    if (i >= TOTR) return;
    int degs = 0;
#pragma unroll 8
    for (int c = 0; c < NCHUNK; ++c) degs += pd[c * TOTR + i];
    int run = 0;
#pragma unroll 8
    for (int c = 0; c < NCHUNK; ++c) {
        int v = pc[c * TOTR + i];
        pc[c * TOTR + i] = run;
        run += v;
    }
    if (i < n) {
        dinv[i] = degs > 0 ? rsqrtf((float)degs) : 0.0f;
        cnt[i] = run;
    }
}

// --- 3-phase scan over cnt -> rowptr ---

__global__ __launch_bounds__(1024) void scan1_kernel(const int* __restrict__ cnt,
                                                     int* __restrict__ excl,
                                                     int* __restrict__ bsum, int n) {
    __shared__ int wsum[16];
    int tid = threadIdx.x, lane = tid & 63, wid = tid >> 6;
    int i = blockIdx.x * 1024 + tid;
    int v = (i < n) ? cnt[i] : 0;
    int x = v;
#pragma unroll
    for (int o = 1; o < 64; o <<= 1) { int y = __shfl_up(x, o); if (lane >= o) x += y; }
    if (lane == 63) wsum[wid] = x;
    __syncthreads();
    if (tid < 16) {
        int s = wsum[tid];
#pragma unroll
        for (int o = 1; o < 16; o <<= 1) { int y = __shfl_up(s, o); if (tid >= o) s += y; }
        wsum[tid] = s;
    }
    __syncthreads();
    int base = (wid > 0 ? wsum[wid - 1] : 0);
    if (i < n) excl[i] = base + x - v;
    if (tid == 0) bsum[blockIdx.x] = wsum[15];
}

__global__ void scan2_kernel(int* __restrict__ bsum, int nb) {
    int t = threadIdx.x;                   // single wave, nb <= 64
    int v = (t < nb) ? bsum[t] : 0;
    int x = v;
#pragma unroll
    for (int o = 1; o < 64; o <<= 1) { int y = __shfl_up(x, o); if (t >= o) x += y; }
    if (t < nb) bsum[t] = x - v;           // exclusive
}

__global__ __launch_bounds__(1024) void scan3_kernel(const int* __restrict__ excl,
                                                     const int* __restrict__ bsum,
                                                     const int* __restrict__ cnt,
                                                     int* __restrict__ rowptr, int n) {
    int i = blockIdx.x * 1024 + threadIdx.x;
    if (i < n) {
        int rp = excl[i] + bsum[blockIdx.x];
        rowptr[i] = rp;
        if (i == n - 1) rowptr[n] = rp + cnt[i];
    }
}

// CSR placement with LDS cursors. csr packed as int2 {src, bitcast(w)}.
__global__ __launch_bounds__(1024) void csr_place_kernel(
        const int* __restrict__ src, const int* __restrict__ dst, int E, int chunk,
        const int* __restrict__ pc, const int* __restrict__ rowptr,
        const float* __restrict__ dinv,
        int2* __restrict__ csr, int n) {
    __shared__ int cur[RNG];
    __shared__ float dloc[RNG];
    int r = blockIdx.x & (NRANGE - 1);
    int c = blockIdx.x >> 3;
    int lo = r * RNG;
    for (int i = threadIdx.x; i < RNG; i += 1024) {
        int node = lo + i;
        if (node < n) {
            cur[i] = rowptr[node] + pc[c * TOTR + node];
            dloc[i] = dinv[node];
        }
    }
    __syncthreads();
    int e0 = c * chunk, e1 = min(e0 + chunk, E);
    for (int e = e0 + threadIdx.x; e < e1; e += 1024) {
        int s = src[e], d = dst[e];
        unsigned int dr = (unsigned int)(d - lo);
        if (s != d && dr < RNG) {
            int pos = atomicAdd(&cur[dr], 1);
            csr[pos] = make_int2(s, __float_as_int(-dinv[s] * dloc[dr]));
        }
    }
}

// ---------------- CSR gather propagation, D=128 bf16, f32 accum ----------------

__global__ void prop_kernel(const unsigned int* __restrict__ H, int hs,
                            const int* __restrict__ rowptr,
                            const int2* __restrict__ csr,
                            const unsigned int* __restrict__ add, int as_,
                            float scale, float coef,
                            unsigned int* __restrict__ out, int n) {
    int wib = threadIdx.x >> 6;
    int lane = threadIdx.x & 63;
    int node = blockIdx.x * (blockDim.x >> 6) + wib;
    if (node >= n) return;

    float ax = 0.0f, ay = 0.0f;
    int beg = rowptr[node], end = rowptr[node + 1];
    int i = beg;
    for (; i + 4 <= end; i += 4) {
        int2 e0 = csr[i], e1 = csr[i + 1], e2 = csr[i + 2], e3 = csr[i + 3];
        unsigned int u0 = H[(size_t)e0.x * hs + lane];
        unsigned int u1 = H[(size_t)e1.x * hs + lane];
        unsigned int u2 = H[(size_t)e2.x * hs + lane];
        unsigned int u3 = H[(size_t)e3.x * hs + lane];
        float w0 = __int_as_float(e0.y), w1 = __int_as_float(e1.y);
        float w2 = __int_as_float(e2.y), w3 = __int_as_float(e3.y);
        ax += w0 * bf_lo(u0) + w1 * bf_lo(u1) + w2 * bf_lo(u2) + w3 * bf_lo(u3);
        ay += w0 * bf_hi(u0) + w1 * bf_hi(u1) + w2 * bf_hi(u2) + w3 * bf_hi(u3);
    }
    for (; i < end; ++i) {
        int2 e0 = csr[i];
        unsigned int u0 = H[(size_t)e0.x * hs + lane];
        float w0 = __int_as_float(e0.y);
        ax += w0 * bf_lo(u0);
        ay += w0 * bf_hi(u0);
    }

    float vx = scale * ax, vy = scale * ay;
    if (add) {
        unsigned int au = add[(size_t)node * as_ + lane];
        vx += coef * bf_lo(au);
        vy += coef * bf_hi(au);
    }
    out[(size_t)node * 64 + lane] = packbf(vx, vy);
}

// final prop + bias + LayerNorm + ReLU -> f32 out.  V stride 64, U0 stride 192.
__global__ void prop_ln_kernel(const unsigned int* __restrict__ V,
                               const int* __restrict__ rowptr,
                               const int2* __restrict__ csr,
                               const unsigned int* __restrict__ U0,
                               const float* __restrict__ b,
                               const float* __restrict__ g,
                               const float* __restrict__ bt,
                               float* __restrict__ out, int n) {
    int wib = threadIdx.x >> 6;
    int lane = threadIdx.x & 63;
    int node = blockIdx.x * (blockDim.x >> 6) + wib;
    if (node >= n) return;

    float ax = 0.0f, ay = 0.0f;
    int beg = rowptr[node], end = rowptr[node + 1];
    int i = beg;
    for (; i + 4 <= end; i += 4) {
        int2 e0 = csr[i], e1 = csr[i + 1], e2 = csr[i + 2], e3 = csr[i + 3];
        unsigned int u0 = V[(size_t)e0.x * 64 + lane];
        unsigned int u1 = V[(size_t)e1.x * 64 + lane];
        unsigned int u2 = V[(size_t)e2.x * 64 + lane];
        unsigned int u3 = V[(size_t)e3.x * 64 + lane];
        float w0 = __int_as_float(e0.y), w1 = __int_as_float(e1.y);
        float w2 = __int_as_float(e2.y), w3 = __int_as_float(e3.y);
        ax += w0 * bf_lo(u0) + w1 * bf_lo(u1) + w2 * bf_lo(u2) + w3 * bf_lo(u3);
        ay += w0 * bf_hi(u0) + w1 * bf_hi(u1) + w2 * bf_hi(u2) + w3 * bf_hi(u3);
    }
    for (; i < end; ++i) {
        int2 e0 = csr[i];
        unsigned int u0 = V[(size_t)e0.x * 64 + lane];
        float w0 = __int_as_float(e0.y);
        ax += w0 * bf_lo(u0);
        ay += w0 * bf_hi(u0);
    }

    unsigned int au = U0[(size_t)node * 192 + lane];
    float px = ax + bf_lo(au) + b[2 * lane];
    float py = ay + bf_hi(au) + b[2 * lane + 1];

    float s = px + py;
#pragma unroll
    for (int o = 1; o < 64; o <<= 1) s += __shfl_xor(s, o);
    float mu = s * (1.0f / 128.0f);
    float dx = px - mu, dy = py - mu;
    float q = dx * dx + dy * dy;
#pragma unroll
    for (int o = 1; o < 64; o <<= 1) q += __shfl_xor(q, o);
    float rs = rsqrtf(q * (1.0f / 128.0f) + 1e-5f);

    float yx = dx * rs * g[2 * lane] + bt[2 * lane];
    float yy = dy * rs * g[2 * lane + 1] + bt[2 * lane + 1];
    yx = yx > 0.0f ? yx : 0.0f;
    yy = yy > 0.0f ? yy : 0.0f;
    float2 o2 = make_float2(yx, yy);
    *reinterpret_cast<float2*>(out + (size_t)node * 128 + 2 * lane) = o2;
}

// ---------------- gemm1: [x|T1|T2] @ Bt1^T + b1 -> LN -> ReLU -> bf16 h1 ----------------
// BM=64, BN=256, BK=32, 4 waves (wave w owns cols w*64..w*64+63).
// 2-phase double-buffered prefetch: one barrier per K-tile; tile t+1's global
// loads issue right after the barrier and their latency hides under the
// ds_read+MFMA phase of tile t (round-7 was vmcnt(0)-drain-per-tile: 12
// exposed-latency stalls at 3 blocks/CU -> MfmaUtil 5.6%).

__global__ __launch_bounds__(256) void gemm1_ln_kernel(
        const unsigned short* __restrict__ A0, const unsigned short* __restrict__ A1,
        const unsigned short* __restrict__ A2, const unsigned short* __restrict__ Bt,
        const float* __restrict__ bias, const float* __restrict__ g,
        const float* __restrict__ bt, unsigned short* __restrict__ Hout, int N) {
    __shared__ __align__(16) unsigned short As[2][64][40];
    __shared__ __align__(16) unsigned short Bs[2][256][40];
    __shared__ float redS[4][64];
    __shared__ float redQ[4][64];

    int row0 = blockIdx.x * 64;
    int tid = threadIdx.x;
    int lane = tid & 63;
    int wave = tid >> 6;
    int wc = wave * 64;

    f32x4 acc[4][4];
#pragma unroll
    for (int i = 0; i < 4; ++i)
#pragma unroll
        for (int j = 0; j < 4; ++j) acc[i][j] = (f32x4)0.0f;

    int srow = tid >> 2;
    int sch = (tid & 3) * 8;
    int gra = min(row0 + srow, N - 1);   // clamp: OOB rows computed, never stored

    uint4 ra, rb0, rb1, rb2, rb3;
    auto issue = [&](int ks) {
        int kg = ks * 32;
        int seg = kg >> 7;
        int kk = kg & 127;
        const unsigned short* Aseg = (seg == 0) ? A0 : (seg == 1 ? A1 : A2);
        ra = *reinterpret_cast<const uint4*>(Aseg + (size_t)gra * 128 + kk + sch);
        const unsigned short* bp = Bt + (size_t)srow * 384 + kg + sch;
        rb0 = *reinterpret_cast<const uint4*>(bp);
        rb1 = *reinterpret_cast<const uint4*>(bp + (size_t)64 * 384);
        rb2 = *reinterpret_cast<const uint4*>(bp + (size_t)128 * 384);
        rb3 = *reinterpret_cast<const uint4*>(bp + (size_t)192 * 384);
    };

    issue(0);
    for (int ks = 0; ks < 12; ++ks) {
        int cb = ks & 1;
        *reinterpret_cast<uint4*>(&As[cb][srow][sch]) = ra;
        *reinterpret_cast<uint4*>(&Bs[cb][srow][sch]) = rb0;
        *reinterpret_cast<uint4*>(&Bs[cb][64 + srow][sch]) = rb1;
        *reinterpret_cast<uint4*>(&Bs[cb][128 + srow][sch]) = rb2;
        *reinterpret_cast<uint4*>(&Bs[cb][192 + srow][sch]) = rb3;
        __syncthreads();
        if (ks < 11) issue(ks + 1);     // overlaps with frag reads + MFMA below

        int fr = lane & 15;
        int kh = (lane >> 4) * 8;
        bf16x8 af[4], bfr[4];
#pragma unroll
        for (int i = 0; i < 4; ++i)
            af[i] = *reinterpret_cast<const bf16x8*>(&As[cb][i * 16 + fr][kh]);
#pragma unroll
        for (int j = 0; j < 4; ++j)
            bfr[j] = *reinterpret_cast<const bf16x8*>(&Bs[cb][wc + j * 16 + fr][kh]);
#pragma unroll
        for (int i = 0; i < 4; ++i)
#pragma unroll
            for (int j = 0; j < 4; ++j)
                acc[i][j] = __builtin_amdgcn_mfma_f32_16x16x32_bf16(af[i], bfr[j], acc[i][j], 0, 0, 0);
        // no trailing barrier: double buffer + the single barrier above order
        // write(t+2,buf) after read(t,buf) across waves.
    }

    int fc = lane & 15;
    int fq = lane >> 4;
    float bcol[4], gcol[4], btcol[4];
#pragma unroll
    for (int j = 0; j < 4; ++j) {
        int c = wc + j * 16 + fc;
        bcol[j] = bias[c];
        gcol[j] = g[c];
        btcol[j] = bt[c];
    }
#pragma unroll
    for (int i = 0; i < 4; ++i)
#pragma unroll
        for (int j = 0; j < 4; ++j)
#pragma unroll
            for (int v = 0; v < 4; ++v) acc[i][j][v] += bcol[j];

#pragma unroll
    for (int i = 0; i < 4; ++i) {
#pragma unroll
        for (int v = 0; v < 4; ++v) {
            float s = 0.0f, q = 0.0f;
#pragma unroll
            for (int j = 0; j < 4; ++j) {
                float val = acc[i][j][v];
                s += val;
                q += val * val;
            }
#pragma unroll
            for (int o = 1; o < 16; o <<= 1) {
                s += __shfl_xor(s, o);
                q += __shfl_xor(q, o);
            }
            if (fc == 0) {
                int r = i * 16 + fq * 4 + v;
                redS[wave][r] = s;
                redQ[wave][r] = q;
            }
        }
    }
    __syncthreads();

#pragma unroll
    for (int i = 0; i < 4; ++i) {
#pragma unroll
        for (int v = 0; v < 4; ++v) {
            int r = i * 16 + fq * 4 + v;
            float S = redS[0][r] + redS[1][r] + redS[2][r] + redS[3][r];
            float Q = redQ[0][r] + redQ[1][r] + redQ[2][r] + redQ[3][r];
            float mu = S * (1.0f / 256.0f);
            float var = Q * (1.0f / 256.0f) - mu * mu;
            float rsg = rsqrtf(var + 1e-5f);
            int gr = row0 + r;
            if (gr < N) {
#pragma unroll
                for (int j = 0; j < 4; ++j) {
                    float y = (acc[i][j][v] - mu) * rsg * gcol[j] + btcol[j];
                    y = y > 0.0f ? y : 0.0f;
                    Hout[(size_t)gr * 256 + wc + j * 16 + fc] = f2bf(y);
                }
            }
        }
    }
}

// ---------------- gemm2: h1 @ Btc^T -> U [N][384] bf16 (2-phase prefetch) ----------------

__global__ __launch_bounds__(256) void gemm2_kernel(
        const unsigned short* __restrict__ A, const unsigned short* __restrict__ Btc,
        unsigned short* __restrict__ U, int N, int ncol) {
    __shared__ __align__(16) unsigned short As[2][64][40];
    __shared__ __align__(16) unsigned short Bs[2][128][40];

    int nwg = gridDim.x;
    int q = nwg >> 3, r = nwg & 7;
    int xcd = blockIdx.x & 7, idx = blockIdx.x >> 3;
    int wgid = (xcd < r ? xcd * (q + 1) : r * (q + 1) + (xcd - r) * q) + idx;

    int row0 = (wgid / ncol) * 64;
    int col0 = (wgid % ncol) * 128;

    int tid = threadIdx.x;
    int lane = tid & 63;
    int wave = tid >> 6;
    int wc = wave * 32;

    f32x4 acc[4][2];
#pragma unroll
    for (int i = 0; i < 4; ++i)
#pragma unroll
        for (int j = 0; j < 2; ++j) acc[i][j] = (f32x4)0.0f;

    int srow = tid >> 2;
    int sch = (tid & 3) * 8;
    int gra = min(row0 + srow, N - 1);

    uint4 ra, rb0, rb1;
    auto issue = [&](int ks) {
        int kg = ks * 32;
        ra = *reinterpret_cast<const uint4*>(A + (size_t)gra * 256 + kg + sch);
        const unsigned short* bp = Btc + (size_t)(col0 + srow) * 256 + kg + sch;
        rb0 = *reinterpret_cast<const uint4*>(bp);
        rb1 = *reinterpret_cast<const uint4*>(bp + (size_t)64 * 256);
    };

    issue(0);
    for (int ks = 0; ks < 8; ++ks) {
        int cb = ks & 1;
        *reinterpret_cast<uint4*>(&As[cb][srow][sch]) = ra;
        *reinterpret_cast<uint4*>(&Bs[cb][srow][sch]) = rb0;
        *reinterpret_cast<uint4*>(&Bs[cb][64 + srow][sch]) = rb1;
        __syncthreads();
        if (ks < 7) issue(ks + 1);

        int fr = lane & 15;
        int kh = (lane >> 4) * 8;
        bf16x8 af[4], bfr[2];
#pragma unroll
        for (int i = 0; i < 4; ++i)
            af[i] = *reinterpret_cast<const bf16x8*>(&As[cb][i * 16 + fr][kh]);
#pragma unroll
        for (int j = 0; j < 2; ++j)
            bfr[j] = *reinterpret_cast<const bf16x8*>(&Bs[cb][wc + j * 16 + fr][kh]);
#pragma unroll
        for (int i = 0; i < 4; ++i)
#pragma unroll
            for (int j = 0; j < 2; ++j)
                acc[i][j] = __builtin_amdgcn_mfma_f32_16x16x32_bf16(af[i], bfr[j], acc[i][j], 0, 0, 0);
    }

    int fc = lane & 15;
    int frr = (lane >> 4) * 4;
#pragma unroll
    for (int i = 0; i < 4; ++i) {
#pragma unroll
        for (int v = 0; v < 4; ++v) {
            int gr = row0 + i * 16 + frr + v;
            if (gr < N) {
#pragma unroll
                for (int j = 0; j < 2; ++j) {
                    int gc = col0 + wc + j * 16 + fc;
                    U[(size_t)gr * 384 + gc] = f2bf(acc[i][j][v]);
                }
            }
        }
    }
}

// ---------------- host launch ----------------

extern "C" void kernel_launch(void* const* d_in, const int* in_sizes, int n_in,
                              void* d_out, int out_size, void* d_ws, size_t ws_size,
                              hipStream_t stream) {
    const int N = N_NODES;
    const float* x  = (const float*)d_in[0];
    const int*  ei  = (const int*)d_in[1];
    const float* W1 = (const float*)d_in[2];
    const float* b1 = (const float*)d_in[3];
    const float* g1 = (const float*)d_in[4];
    const float* bt1 = (const float*)d_in[5];
    const float* W2 = (const float*)d_in[6];
    const float* b2 = (const float*)d_in[7];
    const float* g2 = (const float*)d_in[8];
    const float* bt2 = (const float*)d_in[9];
    float* out = (float*)d_out;

    const int E = in_sizes[1] / 2;
    const int* src = ei;
    const int* dst = ei + E;
    const int chunk = (E + NCHUNK - 1) / NCHUNK;

    // workspace carve (256B aligned)
    char* w = (char*)d_ws;
    auto alloc = [&](size_t bytes) { char* p = w; w += (bytes + 255) & ~(size_t)255; return p; };
    int* pd      = (int*)alloc((size_t)NCHUNK * TOTR * 4);
    int* pc      = (int*)alloc((size_t)NCHUNK * TOTR * 4);
    int* cnt     = (int*)alloc((size_t)N * 4);
    int* excl    = (int*)alloc((size_t)N * 4);
    int* bsum    = (int*)alloc(64 * 4);
    int* rowptr  = (int*)alloc((size_t)(N + 1) * 4);
    int2* csr    = (int2*)alloc((size_t)E * 8);
    float* dinv  = (float*)alloc((size_t)N * 4);
    unsigned short* xb  = (unsigned short*)alloc((size_t)N * 128 * 2);
    unsigned short* T1  = (unsigned short*)alloc((size_t)N * 128 * 2);
    unsigned short* T2  = (unsigned short*)alloc((size_t)N * 128 * 2);
    unsigned short* h1b = (unsigned short*)alloc((size_t)N * 256 * 2);
    unsigned short* U   = (unsigned short*)alloc((size_t)N * 384 * 2);
    unsigned short* V   = (unsigned short*)alloc((size_t)N * 128 * 2);
    unsigned short* Bt1 = (unsigned short*)alloc((size_t)256 * 384 * 2);
    unsigned short* Btc = (unsigned short*)alloc((size_t)384 * 256 * 2);
    (void)ws_size;

    const int TPB = 256;
    const int NB = (N + 1023) / 1024;

    // --- preprocessing: privatized histograms + atomic-free CSR placement ---
    hipLaunchKernelGGL(hist_priv_kernel, dim3(NCHUNK * NRANGE), dim3(1024), 0, stream,
                       src, dst, E, chunk, pd, pc);
    hipLaunchKernelGGL(reduce_chunks_kernel, dim3((TOTR + TPB - 1) / TPB), dim3(TPB), 0, stream,
                       pd, pc, dinv, cnt, N);
    hipLaunchKernelGGL(scan1_kernel, dim3(NB), dim3(1024), 0, stream, cnt, excl, bsum, N);
    hipLaunchKernelGGL(scan2_kernel, dim3(1), dim3(64), 0, stream, bsum, NB);
    hipLaunchKernelGGL(scan3_kernel, dim3(NB), dim3(1024), 0, stream, excl, bsum, cnt, rowptr, N);
    hipLaunchKernelGGL(csr_place_kernel, dim3(NCHUNK * NRANGE), dim3(1024), 0, stream,
                       src, dst, E, chunk, pc, rowptr, dinv, csr, N);
    hipLaunchKernelGGL(cvt_bf_kernel, dim3((N * 128 / 4 + TPB - 1) / TPB), dim3(TPB), 0, stream,
                       x, xb, (size_t)N * 128 / 4);
    hipLaunchKernelGGL(wtrans1_kernel, dim3((3 * 128 * 256 + TPB - 1) / TPB), dim3(TPB), 0, stream, W1, Bt1);
    hipLaunchKernelGGL(wtrans2_kernel, dim3((384 * 256 + TPB - 1) / TPB), dim3(TPB), 0, stream, W2, Btc);

    const int gridW = (N + 3) / 4;   // 4 waves per block, 1 node per wave

    // --- layer 1: props (D=128) then GEMM+LN ---
    hipLaunchKernelGGL(prop_kernel, dim3(gridW), dim3(TPB), 0, stream,
                       (const unsigned int*)xb, 64, rowptr, csr,
                       (const unsigned int*)nullptr, 0, 1.0f, 0.0f,
                       (unsigned int*)T1, N);
    hipLaunchKernelGGL(prop_kernel, dim3(gridW), dim3(TPB), 0, stream,
                       (const unsigned int*)T1, 64, rowptr, csr,
                       (const unsigned int*)xb, 64, 2.0f, -1.0f,
                       (unsigned int*)T2, N);
    hipLaunchKernelGGL(gemm1_ln_kernel, dim3((N + 63) / 64), dim3(256), 0, stream,
                       xb, T1, T2, Bt1, b1, g1, bt1, h1b, N);

    // --- layer 2: GEMM first, then props in 128-dim ---
    {
        int nrow = (N + 63) / 64, ncol = 3;
        hipLaunchKernelGGL(gemm2_kernel, dim3(nrow * ncol), dim3(256), 0, stream,
                           h1b, Btc, U, N, ncol);
    }
    // v = L(u2) + u1
    hipLaunchKernelGGL(prop_kernel, dim3(gridW), dim3(TPB), 0, stream,
                       (const unsigned int*)U + 128, 192, rowptr, csr,
                       (const unsigned int*)U + 64, 192, 1.0f, 1.0f,
                       (unsigned int*)V, N);
    // out = LN(L(v) + u0 + b2) -> relu
    hipLaunchKernelGGL(prop_ln_kernel, dim3(gridW), dim3(TPB), 0, stream,
                       (const unsigned int*)V, rowptr, csr,
                       (const unsigned int*)U, b2, g2, bt2, out, N);
}

// Round 12
// 260.318 us; speedup vs baseline: 9.3450x; 1.0680x over previous
//
#include <hip/hip_runtime.h>

#define N_NODES 50000
#define NRANGE 8
#define RNG 6400          // NRANGE*RNG = 51200 >= N
#define TOTR (NRANGE * RNG)
#define NCHUNK 32

using f32x4  = __attribute__((ext_vector_type(4))) float;
using bf16x8 = __attribute__((ext_vector_type(8))) __bf16;

__device__ __forceinline__ unsigned short f2bf(float f) {
    unsigned int b = __float_as_uint(f);
    unsigned int r = (b + 0x7FFFu + ((b >> 16) & 1u)) >> 16;   // RNE
    return (unsigned short)r;
}
__device__ __forceinline__ float bf_lo(unsigned int u) { return __uint_as_float(u << 16); }
__device__ __forceinline__ float bf_hi(unsigned int u) { return __uint_as_float(u & 0xFFFF0000u); }
__device__ __forceinline__ unsigned int packbf(float x, float y) {
    return ((unsigned int)f2bf(y) << 16) | f2bf(x);
}

// ---------------- utility ----------------

__global__ void cvt_bf_kernel(const float* __restrict__ in, unsigned short* __restrict__ out, size_t n4) {
    size_t i = (size_t)blockIdx.x * blockDim.x + threadIdx.x;
    if (i < n4) {
        float4 v = *reinterpret_cast<const float4*>(in + i * 4);
        ushort4 o;
        o.x = f2bf(v.x); o.y = f2bf(v.y); o.z = f2bf(v.z); o.w = f2bf(v.w);
        *reinterpret_cast<ushort4*>(out + i * 4) = o;
    }
}

// W1: [3][128][256] f32 -> Bt1: [256][384] bf16
__global__ void wtrans1_kernel(const float* __restrict__ W, unsigned short* __restrict__ Bt) {
    int i = blockIdx.x * blockDim.x + threadIdx.x;
    if (i < 3 * 128 * 256) {
        int c = i % 256;
        int kg = i / 256;
        Bt[(size_t)c * 384 + kg] = f2bf(W[(size_t)kg * 256 + c]);
    }
}

// W2: [3][256][128] f32 -> Btc: [384][256] bf16 with cols [W0-W2 | W1 | 2*W2]
__global__ void wtrans2_kernel(const float* __restrict__ W, unsigned short* __restrict__ Btc) {
    int i = blockIdx.x * blockDim.x + threadIdx.x;
    if (i < 384 * 256) {
        int k = i % 256;
        int cc = i / 256;
        int seg = cc >> 7, c = cc & 127;
        float v;
        if (seg == 0)      v = W[(size_t)k * 128 + c] - W[(size_t)(2 * 256 + k) * 128 + c];
        else if (seg == 1) v = W[(size_t)(256 + k) * 128 + c];
        else               v = 2.0f * W[(size_t)(2 * 256 + k) * 128 + c];
        Btc[(size_t)cc * 256 + k] = f2bf(v);
    }
}

// ---------------- edge preprocessing: privatized LDS histograms ----------------

__global__ __launch_bounds__(1024) void hist_priv_kernel(
        const int* __restrict__ src, const int* __restrict__ dst, int E, int chunk,
        int* __restrict__ pd, int* __restrict__ pc) {     // [NCHUNK][TOTR] each
    __shared__ int lhS[RNG];
    __shared__ int lhD[RNG];
    int r = blockIdx.x & (NRANGE - 1);
    int c = blockIdx.x >> 3;               // NRANGE == 8
    int lo = r * RNG;
    for (int i = threadIdx.x; i < RNG; i += 1024) { lhS[i] = 0; lhD[i] = 0; }
    __syncthreads();
    int e0 = c * chunk, e1 = min(e0 + chunk, E);
    for (int e = e0 + threadIdx.x; e < e1; e += 1024) {
        int s = src[e], d = dst[e];
        if (s != d) {
            unsigned int sr = (unsigned int)(s - lo);
            unsigned int dr = (unsigned int)(d - lo);
            if (sr < RNG) atomicAdd(&lhS[sr], 1);
            if (dr < RNG) atomicAdd(&lhD[dr], 1);
        }
    }
    __syncthreads();
    int base = c * TOTR + lo;
    for (int i = threadIdx.x; i < RNG; i += 1024) {
        pd[base + i] = lhS[i];
        pc[base + i] = lhD[i];
    }
}

__global__ void reduce_chunks_kernel(int* __restrict__ pd, int* __restrict__ pc,
                                     float* __restrict__ dinv, int* __restrict__ cnt, int n) {
    int i = blockIdx.x * blockDim.x + threadIdx.x;
    if (i >= TOTR) return;
    int degs = 0;
#pragma unroll 8
    for (int c = 0; c < NCHUNK; ++c) degs += pd[c * TOTR + i];
    int run = 0;
#pragma unroll 8
    for (int c = 0; c < NCHUNK; ++c) {
        int v = pc[c * TOTR + i];
        pc[c * TOTR + i] = run;
        run += v;
    }
    if (i < n) {
        dinv[i] = degs > 0 ? rsqrtf((float)degs) : 0.0f;
        cnt[i] = run;
    }
}

// --- 3-phase scan over cnt -> rowptr ---

__global__ __launch_bounds__(1024) void scan1_kernel(const int* __restrict__ cnt,
                                                     int* __restrict__ excl,
                                                     int* __restrict__ bsum, int n) {
    __shared__ int wsum[16];
    int tid = threadIdx.x, lane = tid & 63, wid = tid >> 6;
    int i = blockIdx.x * 1024 + tid;
    int v = (i < n) ? cnt[i] : 0;
    int x = v;
#pragma unroll
    for (int o = 1; o < 64; o <<= 1) { int y = __shfl_up(x, o); if (lane >= o) x += y; }
    if (lane == 63) wsum[wid] = x;
    __syncthreads();
    if (tid < 16) {
        int s = wsum[tid];
#pragma unroll
        for (int o = 1; o < 16; o <<= 1) { int y = __shfl_up(s, o); if (tid >= o) s += y; }
        wsum[tid] = s;
    }
    __syncthreads();
    int base = (wid > 0 ? wsum[wid - 1] : 0);
    if (i < n) excl[i] = base + x - v;
    if (tid == 0) bsum[blockIdx.x] = wsum[15];
}

__global__ void scan2_kernel(int* __restrict__ bsum, int nb) {
    int t = threadIdx.x;                   // single wave, nb <= 64
    int v = (t < nb) ? bsum[t] : 0;
    int x = v;
#pragma unroll
    for (int o = 1; o < 64; o <<= 1) { int y = __shfl_up(x, o); if (t >= o) x += y; }
    if (t < nb) bsum[t] = x - v;           // exclusive
}

__global__ __launch_bounds__(1024) void scan3_kernel(const int* __restrict__ excl,
                                                     const int* __restrict__ bsum,
                                                     const int* __restrict__ cnt,
                                                     int* __restrict__ rowptr, int n) {
    int i = blockIdx.x * 1024 + threadIdx.x;
    if (i < n) {
        int rp = excl[i] + bsum[blockIdx.x];
        rowptr[i] = rp;
        if (i == n - 1) rowptr[n] = rp + cnt[i];
    }
}

// CSR placement with LDS cursors. csr packed as int2 {src, bitcast(w)}.
__global__ __launch_bounds__(1024) void csr_place_kernel(
        const int* __restrict__ src, const int* __restrict__ dst, int E, int chunk,
        const int* __restrict__ pc, const int* __restrict__ rowptr,
        const float* __restrict__ dinv,
        int2* __restrict__ csr, int n) {
    __shared__ int cur[RNG];
    __shared__ float dloc[RNG];
    int r = blockIdx.x & (NRANGE - 1);
    int c = blockIdx.x >> 3;
    int lo = r * RNG;
    for (int i = threadIdx.x; i < RNG; i += 1024) {
        int node = lo + i;
        if (node < n) {
            cur[i] = rowptr[node] + pc[c * TOTR + node];
            dloc[i] = dinv[node];
        }
    }
    __syncthreads();
    int e0 = c * chunk, e1 = min(e0 + chunk, E);
    for (int e = e0 + threadIdx.x; e < e1; e += 1024) {
        int s = src[e], d = dst[e];
        unsigned int dr = (unsigned int)(d - lo);
        if (s != d && dr < RNG) {
            int pos = atomicAdd(&cur[dr], 1);
            csr[pos] = make_int2(s, __float_as_int(-dinv[s] * dloc[dr]));
        }
    }
}

// ---------------- CSR gather propagation, D=128 bf16, f32 accum ----------------
// 8-wide edge unroll: props are gather-LATENCY bound (r4: HBM 41%, VALU 38%,
// nothing saturated; avg deg ~16 -> only ~4 loads in flight with the 4-wide
// loop). 8-wide doubles outstanding loads per lane. Statically indexed
// register arrays (rule #20: full unroll -> no scratch).

__global__ void prop_kernel(const unsigned int* __restrict__ H, int hs,
                            const int* __restrict__ rowptr,
                            const int2* __restrict__ csr,
                            const unsigned int* __restrict__ add, int as_,
                            float scale, float coef,
                            unsigned int* __restrict__ out, int n) {
    int wib = threadIdx.x >> 6;
    int lane = threadIdx.x & 63;
    int node = blockIdx.x * (blockDim.x >> 6) + wib;
    if (node >= n) return;

    float ax = 0.0f, ay = 0.0f;
    int beg = rowptr[node], end = rowptr[node + 1];
    int i = beg;
    for (; i + 8 <= end; i += 8) {
        int2 e[8];
#pragma unroll
        for (int k = 0; k < 8; ++k) e[k] = csr[i + k];
        unsigned int u[8];
#pragma unroll
        for (int k = 0; k < 8; ++k) u[k] = H[(size_t)e[k].x * hs + lane];
#pragma unroll
        for (int k = 0; k < 8; ++k) {
            float wk = __int_as_float(e[k].y);
            ax += wk * bf_lo(u[k]);
            ay += wk * bf_hi(u[k]);
        }
    }
    for (; i + 2 <= end; i += 2) {
        int2 e0 = csr[i], e1 = csr[i + 1];
        unsigned int u0 = H[(size_t)e0.x * hs + lane];
        unsigned int u1 = H[(size_t)e1.x * hs + lane];
        float w0 = __int_as_float(e0.y), w1 = __int_as_float(e1.y);
        ax += w0 * bf_lo(u0) + w1 * bf_lo(u1);
        ay += w0 * bf_hi(u0) + w1 * bf_hi(u1);
    }
    if (i < end) {
        int2 e0 = csr[i];
        unsigned int u0 = H[(size_t)e0.x * hs + lane];
        float w0 = __int_as_float(e0.y);
        ax += w0 * bf_lo(u0);
        ay += w0 * bf_hi(u0);
    }

    float vx = scale * ax, vy = scale * ay;
    if (add) {
        unsigned int au = add[(size_t)node * as_ + lane];
        vx += coef * bf_lo(au);
        vy += coef * bf_hi(au);
    }
    out[(size_t)node * 64 + lane] = packbf(vx, vy);
}

// final prop + bias + LayerNorm + ReLU -> f32 out.  V stride 64, U0 stride 192.
__global__ void prop_ln_kernel(const unsigned int* __restrict__ V,
                               const int* __restrict__ rowptr,
                               const int2* __restrict__ csr,
                               const unsigned int* __restrict__ U0,
                               const float* __restrict__ b,
                               const float* __restrict__ g,
                               const float* __restrict__ bt,
                               float* __restrict__ out, int n) {
    int wib = threadIdx.x >> 6;
    int lane = threadIdx.x & 63;
    int node = blockIdx.x * (blockDim.x >> 6) + wib;
    if (node >= n) return;

    float ax = 0.0f, ay = 0.0f;
    int beg = rowptr[node], end = rowptr[node + 1];
    int i = beg;
    for (; i + 8 <= end; i += 8) {
        int2 e[8];
#pragma unroll
        for (int k = 0; k < 8; ++k) e[k] = csr[i + k];
        unsigned int u[8];
#pragma unroll
        for (int k = 0; k < 8; ++k) u[k] = V[(size_t)e[k].x * 64 + lane];
#pragma unroll
        for (int k = 0; k < 8; ++k) {
            float wk = __int_as_float(e[k].y);
            ax += wk * bf_lo(u[k]);
            ay += wk * bf_hi(u[k]);
        }
    }
    for (; i + 2 <= end; i += 2) {
        int2 e0 = csr[i], e1 = csr[i + 1];
        unsigned int u0 = V[(size_t)e0.x * 64 + lane];
        unsigned int u1 = V[(size_t)e1.x * 64 + lane];
        float w0 = __int_as_float(e0.y), w1 = __int_as_float(e1.y);
        ax += w0 * bf_lo(u0) + w1 * bf_lo(u1);
        ay += w0 * bf_hi(u0) + w1 * bf_hi(u1);
    }
    if (i < end) {
        int2 e0 = csr[i];
        unsigned int u0 = V[(size_t)e0.x * 64 + lane];
        float w0 = __int_as_float(e0.y);
        ax += w0 * bf_lo(u0);
        ay += w0 * bf_hi(u0);
    }

    unsigned int au = U0[(size_t)node * 192 + lane];
    float px = ax + bf_lo(au) + b[2 * lane];
    float py = ay + bf_hi(au) + b[2 * lane + 1];

    float s = px + py;
#pragma unroll
    for (int o = 1; o < 64; o <<= 1) s += __shfl_xor(s, o);
    float mu = s * (1.0f / 128.0f);
    float dx = px - mu, dy = py - mu;
    float q = dx * dx + dy * dy;
#pragma unroll
    for (int o = 1; o < 64; o <<= 1) q += __shfl_xor(q, o);
    float rs = rsqrtf(q * (1.0f / 128.0f) + 1e-5f);

    float yx = dx * rs * g[2 * lane] + bt[2 * lane];
    float yy = dy * rs * g[2 * lane + 1] + bt[2 * lane + 1];
    yx = yx > 0.0f ? yx : 0.0f;
    yy = yy > 0.0f ? yy : 0.0f;
    float2 o2 = make_float2(yx, yy);
    *reinterpret_cast<float2*>(out + (size_t)node * 128 + 2 * lane) = o2;
}

// ---------------- gemm1: [x|T1|T2] @ Bt1^T + b1 -> LN -> ReLU -> bf16 h1 ----------------
// EXACT round-8 kernel (validated: passed first-call + post-timing).
// 256 threads = 4 waves; BM=64, BN=256, BK=32; 1-barrier double-buffered
// prefetch. NOTE: the 512-thread reorganizations (rounds 9-11) all failed
// validation with small replay-varying errors — reverted; do not re-attempt
// without a wave-count-invariant derivation.

__global__ __launch_bounds__(256) void gemm1_ln_kernel(
        const unsigned short* __restrict__ A0, const unsigned short* __restrict__ A1,
        const unsigned short* __restrict__ A2, const unsigned short* __restrict__ Bt,
        const float* __restrict__ bias, const float* __restrict__ g,
        const float* __restrict__ bt, unsigned short* __restrict__ Hout, int N) {
    __shared__ __align__(16) unsigned short As[2][64][40];
    __shared__ __align__(16) unsigned short Bs[2][256][40];
    __shared__ float redS[4][64];
    __shared__ float redQ[4][64];

    int row0 = blockIdx.x * 64;
    int tid = threadIdx.x;
    int lane = tid & 63;
    int wave = tid >> 6;
    int wc = wave * 64;

    f32x4 acc[4][4];
#pragma unroll
    for (int i = 0; i < 4; ++i)
#pragma unroll
        for (int j = 0; j < 4; ++j) acc[i][j] = (f32x4)0.0f;

    int srow = tid >> 2;
    int sch = (tid & 3) * 8;
    int gra = min(row0 + srow, N - 1);   // clamp: OOB rows computed, never stored

    uint4 ra, rb0, rb1, rb2, rb3;
    auto issue = [&](int ks) {
        int kg = ks * 32;
        int seg = kg >> 7;
        int kk = kg & 127;
        const unsigned short* Aseg = (seg == 0) ? A0 : (seg == 1 ? A1 : A2);
        ra = *reinterpret_cast<const uint4*>(Aseg + (size_t)gra * 128 + kk + sch);
        const unsigned short* bp = Bt + (size_t)srow * 384 + kg + sch;
        rb0 = *reinterpret_cast<const uint4*>(bp);
        rb1 = *reinterpret_cast<const uint4*>(bp + (size_t)64 * 384);
        rb2 = *reinterpret_cast<const uint4*>(bp + (size_t)128 * 384);
        rb3 = *reinterpret_cast<const uint4*>(bp + (size_t)192 * 384);
    };

    issue(0);
    for (int ks = 0; ks < 12; ++ks) {
        int cb = ks & 1;
        *reinterpret_cast<uint4*>(&As[cb][srow][sch]) = ra;
        *reinterpret_cast<uint4*>(&Bs[cb][srow][sch]) = rb0;
        *reinterpret_cast<uint4*>(&Bs[cb][64 + srow][sch]) = rb1;
        *reinterpret_cast<uint4*>(&Bs[cb][128 + srow][sch]) = rb2;
        *reinterpret_cast<uint4*>(&Bs[cb][192 + srow][sch]) = rb3;
        __syncthreads();
        if (ks < 11) issue(ks + 1);     // overlaps with frag reads + MFMA below

        int fr = lane & 15;
        int kh = (lane >> 4) * 8;
        bf16x8 af[4], bfr[4];
#pragma unroll
        for (int i = 0; i < 4; ++i)
            af[i] = *reinterpret_cast<const bf16x8*>(&As[cb][i * 16 + fr][kh]);
#pragma unroll
        for (int j = 0; j < 4; ++j)
            bfr[j] = *reinterpret_cast<const bf16x8*>(&Bs[cb][wc + j * 16 + fr][kh]);
#pragma unroll
        for (int i = 0; i < 4; ++i)
#pragma unroll
            for (int j = 0; j < 4; ++j)
                acc[i][j] = __builtin_amdgcn_mfma_f32_16x16x32_bf16(af[i], bfr[j], acc[i][j], 0, 0, 0);
        // no trailing barrier: double buffer + the single barrier above order
        // write(t+2,buf) after read(t,buf) across waves.
    }

    int fc = lane & 15;
    int fq = lane >> 4;
    float bcol[4], gcol[4], btcol[4];
#pragma unroll
    for (int j = 0; j < 4; ++j) {
        int c = wc + j * 16 + fc;
        bcol[j] = bias[c];
        gcol[j] = g[c];
        btcol[j] = bt[c];
    }
#pragma unroll
    for (int i = 0; i < 4; ++i)
#pragma unroll
        for (int j = 0; j < 4; ++j)
#pragma unroll
            for (int v = 0; v < 4; ++v) acc[i][j][v] += bcol[j];

#pragma unroll
    for (int i = 0; i < 4; ++i) {
#pragma unroll
        for (int v = 0; v < 4; ++v) {
            float s = 0.0f, q = 0.0f;
#pragma unroll
            for (int j = 0; j < 4; ++j) {
                float val = acc[i][j][v];
                s += val;
                q += val * val;
            }
#pragma unroll
            for (int o = 1; o < 16; o <<= 1) {
                s += __shfl_xor(s, o);
                q += __shfl_xor(q, o);
            }
            if (fc == 0) {
                int r = i * 16 + fq * 4 + v;
                redS[wave][r] = s;
                redQ[wave][r] = q;
            }
        }
    }
    __syncthreads();

#pragma unroll
    for (int i = 0; i < 4; ++i) {
#pragma unroll
        for (int v = 0; v < 4; ++v) {
            int r = i * 16 + fq * 4 + v;
            float S = redS[0][r] + redS[1][r] + redS[2][r] + redS[3][r];
            float Q = redQ[0][r] + redQ[1][r] + redQ[2][r] + redQ[3][r];
            float mu = S * (1.0f / 256.0f);
            float var = Q * (1.0f / 256.0f) - mu * mu;
            float rsg = rsqrtf(var + 1e-5f);
            int gr = row0 + r;
            if (gr < N) {
#pragma unroll
                for (int j = 0; j < 4; ++j) {
                    float y = (acc[i][j][v] - mu) * rsg * gcol[j] + btcol[j];
                    y = y > 0.0f ? y : 0.0f;
                    Hout[(size_t)gr * 256 + wc + j * 16 + fc] = f2bf(y);
                }
            }
        }
    }
}

// ---------------- gemm2: h1 @ Btc^T -> U [N][384] bf16 (EXACT round-8 kernel) ----------

__global__ __launch_bounds__(256) void gemm2_kernel(
        const unsigned short* __restrict__ A, const unsigned short* __restrict__ Btc,
        unsigned short* __restrict__ U, int N, int ncol) {
    __shared__ __align__(16) unsigned short As[2][64][40];
    __shared__ __align__(16) unsigned short Bs[2][128][40];

    int nwg = gridDim.x;
    int q = nwg >> 3, r = nwg & 7;
    int xcd = blockIdx.x & 7, idx = blockIdx.x >> 3;
    int wgid = (xcd < r ? xcd * (q + 1) : r * (q + 1) + (xcd - r) * q) + idx;

    int row0 = (wgid / ncol) * 64;
    int col0 = (wgid % ncol) * 128;

    int tid = threadIdx.x;
    int lane = tid & 63;
    int wave = tid >> 6;
    int wc = wave * 32;

    f32x4 acc[4][2];
#pragma unroll
    for (int i = 0; i < 4; ++i)
#pragma unroll
        for (int j = 0; j < 2; ++j) acc[i][j] = (f32x4)0.0f;

    int srow = tid >> 2;
    int sch = (tid & 3) * 8;
    int gra = min(row0 + srow, N - 1);

    uint4 ra, rb0, rb1;
    auto issue = [&](int ks) {
        int kg = ks * 32;
        ra = *reinterpret_cast<const uint4*>(A + (size_t)gra * 256 + kg + sch);
        const unsigned short* bp = Btc + (size_t)(col0 + srow) * 256 + kg + sch;
        rb0 = *reinterpret_cast<const uint4*>(bp);
        rb1 = *reinterpret_cast<const uint4*>(bp + (size_t)64 * 256);
    };

    issue(0);
    for (int ks = 0; ks < 8; ++ks) {
        int cb = ks & 1;
        *reinterpret_cast<uint4*>(&As[cb][srow][sch]) = ra;
        *reinterpret_cast<uint4*>(&Bs[cb][srow][sch]) = rb0;
        *reinterpret_cast<uint4*>(&Bs[cb][64 + srow][sch]) = rb1;
        __syncthreads();
        if (ks < 7) issue(ks + 1);

        int fr = lane & 15;
        int kh = (lane >> 4) * 8;
        bf16x8 af[4], bfr[2];
#pragma unroll
        for (int i = 0; i < 4; ++i)
            af[i] = *reinterpret_cast<const bf16x8*>(&As[cb][i * 16 + fr][kh]);
#pragma unroll
        for (int j = 0; j < 2; ++j)
            bfr[j] = *reinterpret_cast<const bf16x8*>(&Bs[cb][wc + j * 16 + fr][kh]);
#pragma unroll
        for (int i = 0; i < 4; ++i)
#pragma unroll
            for (int j = 0; j < 2; ++j)
                acc[i][j] = __builtin_amdgcn_mfma_f32_16x16x32_bf16(af[i], bfr[j], acc[i][j], 0, 0, 0);
    }

    int fc = lane & 15;
    int frr = (lane >> 4) * 4;
#pragma unroll
    for (int i = 0; i < 4; ++i) {
#pragma unroll
        for (int v = 0; v < 4; ++v) {
            int gr = row0 + i * 16 + frr + v;
            if (gr < N) {
#pragma unroll
                for (int j = 0; j < 2; ++j) {
                    int gc = col0 + wc + j * 16 + fc;
                    U[(size_t)gr * 384 + gc] = f2bf(acc[i][j][v]);
                }
            }
        }
    }
}

// ---------------- host launch ----------------

extern "C" void kernel_launch(void* const* d_in, const int* in_sizes, int n_in,
                              void* d_out, int out_size, void* d_ws, size_t ws_size,
                              hipStream_t stream) {
    const int N = N_NODES;
    const float* x  = (const float*)d_in[0];
    const int*  ei  = (const int*)d_in[1];
    const float* W1 = (const float*)d_in[2];
    const float* b1 = (const float*)d_in[3];
    const float* g1 = (const float*)d_in[4];
    const float* bt1 = (const float*)d_in[5];
    const float* W2 = (const float*)d_in[6];
    const float* b2 = (const float*)d_in[7];
    const float* g2 = (const float*)d_in[8];
    const float* bt2 = (const float*)d_in[9];
    float* out = (float*)d_out;

    const int E = in_sizes[1] / 2;
    const int* src = ei;
    const int* dst = ei + E;
    const int chunk = (E + NCHUNK - 1) / NCHUNK;

    // workspace carve (256B aligned)
    char* w = (char*)d_ws;
    auto alloc = [&](size_t bytes) { char* p = w; w += (bytes + 255) & ~(size_t)255; return p; };
    int* pd      = (int*)alloc((size_t)NCHUNK * TOTR * 4);
    int* pc      = (int*)alloc((size_t)NCHUNK * TOTR * 4);
    int* cnt     = (int*)alloc((size_t)N * 4);
    int* excl    = (int*)alloc((size_t)N * 4);
    int* bsum    = (int*)alloc(64 * 4);
    int* rowptr  = (int*)alloc((size_t)(N + 1) * 4);
    int2* csr    = (int2*)alloc((size_t)E * 8);
    float* dinv  = (float*)alloc((size_t)N * 4);
    unsigned short* xb  = (unsigned short*)alloc((size_t)N * 128 * 2);
    unsigned short* T1  = (unsigned short*)alloc((size_t)N * 128 * 2);
    unsigned short* T2  = (unsigned short*)alloc((size_t)N * 128 * 2);
    unsigned short* h1b = (unsigned short*)alloc((size_t)N * 256 * 2);
    unsigned short* U   = (unsigned short*)alloc((size_t)N * 384 * 2);
    unsigned short* V   = (unsigned short*)alloc((size_t)N * 128 * 2);
    unsigned short* Bt1 = (unsigned short*)alloc((size_t)256 * 384 * 2);
    unsigned short* Btc = (unsigned short*)alloc((size_t)384 * 256 * 2);
    (void)ws_size;

    const int TPB = 256;
    const int NB = (N + 1023) / 1024;

    // --- preprocessing: privatized histograms + atomic-free CSR placement ---
    hipLaunchKernelGGL(hist_priv_kernel, dim3(NCHUNK * NRANGE), dim3(1024), 0, stream,
                       src, dst, E, chunk, pd, pc);
    hipLaunchKernelGGL(reduce_chunks_kernel, dim3((TOTR + TPB - 1) / TPB), dim3(TPB), 0, stream,
                       pd, pc, dinv, cnt, N);
    hipLaunchKernelGGL(scan1_kernel, dim3(NB), dim3(1024), 0, stream, cnt, excl, bsum, N);
    hipLaunchKernelGGL(scan2_kernel, dim3(1), dim3(64), 0, stream, bsum, NB);
    hipLaunchKernelGGL(scan3_kernel, dim3(NB), dim3(1024), 0, stream, excl, bsum, cnt, rowptr, N);
    hipLaunchKernelGGL(csr_place_kernel, dim3(NCHUNK * NRANGE), dim3(1024), 0, stream,
                       src, dst, E, chunk, pc, rowptr, dinv, csr, N);
    hipLaunchKernelGGL(cvt_bf_kernel, dim3((N * 128 / 4 + TPB - 1) / TPB), dim3(TPB), 0, stream,
                       x, xb, (size_t)N * 128 / 4);
    hipLaunchKernelGGL(wtrans1_kernel, dim3((3 * 128 * 256 + TPB - 1) / TPB), dim3(TPB), 0, stream, W1, Bt1);
    hipLaunchKernelGGL(wtrans2_kernel, dim3((384 * 256 + TPB - 1) / TPB), dim3(TPB), 0, stream, W2, Btc);

    const int gridW = (N + 3) / 4;   // 4 waves per block, 1 node per wave

    // --- layer 1: props (D=128) then GEMM+LN ---
    hipLaunchKernelGGL(prop_kernel, dim3(gridW), dim3(TPB), 0, stream,
                       (const unsigned int*)xb, 64, rowptr, csr,
                       (const unsigned int*)nullptr, 0, 1.0f, 0.0f,
                       (unsigned int*)T1, N);
    hipLaunchKernelGGL(prop_kernel, dim3(gridW), dim3(TPB), 0, stream,
                       (const unsigned int*)T1, 64, rowptr, csr,
                       (const unsigned int*)xb, 64, 2.0f, -1.0f,
                       (unsigned int*)T2, N);
    hipLaunchKernelGGL(gemm1_ln_kernel, dim3((N + 63) / 64), dim3(256), 0, stream,
                       xb, T1, T2, Bt1, b1, g1, bt1, h1b, N);

    // --- layer 2: GEMM first, then props in 128-dim ---
    {
        int nrow = (N + 63) / 64, ncol = 3;
        hipLaunchKernelGGL(gemm2_kernel, dim3(nrow * ncol), dim3(256), 0, stream,
                           h1b, Btc, U, N, ncol);
    }
    // v = L(u2) + u1
    hipLaunchKernelGGL(prop_kernel, dim3(gridW), dim3(TPB), 0, stream,
                       (const unsigned int*)U + 128, 192, rowptr, csr,
                       (const unsigned int*)U + 64, 192, 1.0f, 1.0f,
                       (unsigned int*)V, N);
    // out = LN(L(v) + u0 + b2) -> relu
    hipLaunchKernelGGL(prop_ln_kernel, dim3(gridW), dim3(TPB), 0, stream,
                       (const unsigned int*)V, rowptr, csr,
                       (const unsigned int*)U, b2, g2, bt2, out, N);
}

// Round 14
// 254.676 us; speedup vs baseline: 9.5521x; 1.0222x over previous
//
#include <hip/hip_runtime.h>

#define N_NODES 50000
#define NRANGE 8
#define RNG 6400          // NRANGE*RNG = 51200 >= N
#define TOTR (NRANGE * RNG)
#define NCHUNK 32

using f32x4  = __attribute__((ext_vector_type(4))) float;
using bf16x8 = __attribute__((ext_vector_type(8))) __bf16;

__device__ __forceinline__ unsigned short f2bf(float f) {
    unsigned int b = __float_as_uint(f);
    unsigned int r = (b + 0x7FFFu + ((b >> 16) & 1u)) >> 16;   // RNE
    return (unsigned short)r;
}
__device__ __forceinline__ float bf_lo(unsigned int u) { return __uint_as_float(u << 16); }
__device__ __forceinline__ float bf_hi(unsigned int u) { return __uint_as_float(u & 0xFFFF0000u); }
__device__ __forceinline__ unsigned int packbf(float x, float y) {
    return ((unsigned int)f2bf(y) << 16) | f2bf(x);
}

// ---------------- utility ----------------

__global__ void cvt_bf_kernel(const float* __restrict__ in, unsigned short* __restrict__ out, size_t n4) {
    size_t i = (size_t)blockIdx.x * blockDim.x + threadIdx.x;
    if (i < n4) {
        float4 v = *reinterpret_cast<const float4*>(in + i * 4);
        ushort4 o;
        o.x = f2bf(v.x); o.y = f2bf(v.y); o.z = f2bf(v.z); o.w = f2bf(v.w);
        *reinterpret_cast<ushort4*>(out + i * 4) = o;
    }
}

// W1: [3][128][256] f32 -> Bt1: [256][384] bf16
__global__ void wtrans1_kernel(const float* __restrict__ W, unsigned short* __restrict__ Bt) {
    int i = blockIdx.x * blockDim.x + threadIdx.x;
    if (i < 3 * 128 * 256) {
        int c = i % 256;
        int kg = i / 256;
        Bt[(size_t)c * 384 + kg] = f2bf(W[(size_t)kg * 256 + c]);
    }
}

// W2: [3][256][128] f32 -> Btc: [384][256] bf16 with cols [W0-W2 | W1 | 2*W2]
__global__ void wtrans2_kernel(const float* __restrict__ W, unsigned short* __restrict__ Btc) {
    int i = blockIdx.x * blockDim.x + threadIdx.x;
    if (i < 384 * 256) {
        int k = i % 256;
        int cc = i / 256;
        int seg = cc >> 7, c = cc & 127;
        float v;
        if (seg == 0)      v = W[(size_t)k * 128 + c] - W[(size_t)(2 * 256 + k) * 128 + c];
        else if (seg == 1) v = W[(size_t)(256 + k) * 128 + c];
        else               v = 2.0f * W[(size_t)(2 * 256 + k) * 128 + c];
        Btc[(size_t)cc * 256 + k] = f2bf(v);
    }
}

// ---------------- edge preprocessing: privatized LDS histograms ----------------

__global__ __launch_bounds__(1024) void hist_priv_kernel(
        const int* __restrict__ src, const int* __restrict__ dst, int E, int chunk,
        int* __restrict__ pd, int* __restrict__ pc) {     // [NCHUNK][TOTR] each
    __shared__ int lhS[RNG];
    __shared__ int lhD[RNG];
    int r = blockIdx.x & (NRANGE - 1);
    int c = blockIdx.x >> 3;               // NRANGE == 8
    int lo = r * RNG;
    for (int i = threadIdx.x; i < RNG; i += 1024) { lhS[i] = 0; lhD[i] = 0; }
    __syncthreads();
    int e0 = c * chunk, e1 = min(e0 + chunk, E);
    for (int e = e0 + threadIdx.x; e < e1; e += 1024) {
        int s = src[e], d = dst[e];
        if (s != d) {
            unsigned int sr = (unsigned int)(s - lo);
            unsigned int dr = (unsigned int)(d - lo);
            if (sr < RNG) atomicAdd(&lhS[sr], 1);
            if (dr < RNG) atomicAdd(&lhD[dr], 1);
        }
    }
    __syncthreads();
    int base = c * TOTR + lo;
    for (int i = threadIdx.x; i < RNG; i += 1024) {
        pd[base + i] = lhS[i];
        pc[base + i] = lhD[i];
    }
}

__global__ void reduce_chunks_kernel(int* __restrict__ pd, int* __restrict__ pc,
                                     float* __restrict__ dinv, int* __restrict__ cnt, int n) {
    int i = blockIdx.x * blockDim.x + threadIdx.x;
    if (i >= TOTR) return;
    int degs = 0;
#pragma unroll 8
    for (int c = 0; c < NCHUNK; ++c) degs += pd[c * TOTR + i];
    int run = 0;
#pragma unroll 8
    for (int c = 0; c < NCHUNK; ++c) {
        int v = pc[c * TOTR + i];
        pc[c * TOTR + i] = run;
        run += v;
    }
    if (i < n) {
        dinv[i] = degs > 0 ? rsqrtf((float)degs) : 0.0f;
        cnt[i] = run;
    }
}

// --- 3-phase scan over cnt -> rowptr ---

__global__ __launch_bounds__(1024) void scan1_kernel(const int* __restrict__ cnt,
                                                     int* __restrict__ excl,
                                                     int* __restrict__ bsum, int n) {
    __shared__ int wsum[16];
    int tid = threadIdx.x, lane = tid & 63, wid = tid >> 6;
    int i = blockIdx.x * 1024 + tid;
    int v = (i < n) ? cnt[i] : 0;
    int x = v;
#pragma unroll
    for (int o = 1; o < 64; o <<= 1) { int y = __shfl_up(x, o); if (lane >= o) x += y; }
    if (lane == 63) wsum[wid] = x;
    __syncthreads();
    if (tid < 16) {
        int s = wsum[tid];
#pragma unroll
        for (int o = 1; o < 16; o <<= 1) { int y = __shfl_up(s, o); if (tid >= o) s += y; }
        wsum[tid] = s;
    }
    __syncthreads();
    int base = (wid > 0 ? wsum[wid - 1] : 0);
    if (i < n) excl[i] = base + x - v;
    if (tid == 0) bsum[blockIdx.x] = wsum[15];
}

__global__ void scan2_kernel(int* __restrict__ bsum, int nb) {
    int t = threadIdx.x;                   // single wave, nb <= 64
    int v = (t < nb) ? bsum[t] : 0;
    int x = v;
#pragma unroll
    for (int o = 1; o < 64; o <<= 1) { int y = __shfl_up(x, o); if (t >= o) x += y; }
    if (t < nb) bsum[t] = x - v;           // exclusive
}

__global__ __launch_bounds__(1024) void scan3_kernel(const int* __restrict__ excl,
                                                     const int* __restrict__ bsum,
                                                     const int* __restrict__ cnt,
                                                     int* __restrict__ rowptr, int n) {
    int i = blockIdx.x * 1024 + threadIdx.x;
    if (i < n) {
        int rp = excl[i] + bsum[blockIdx.x];
        rowptr[i] = rp;
        if (i == n - 1) rowptr[n] = rp + cnt[i];
    }
}

// CSR placement with LDS cursors. csr packed as int2 {src, bitcast(w)}.
__global__ __launch_bounds__(1024) void csr_place_kernel(
        const int* __restrict__ src, const int* __restrict__ dst, int E, int chunk,
        const int* __restrict__ pc, const int* __restrict__ rowptr,
        const float* __restrict__ dinv,
        int2* __restrict__ csr, int n) {
    __shared__ int cur[RNG];
    __shared__ float dloc[RNG];
    int r = blockIdx.x & (NRANGE - 1);
    int c = blockIdx.x >> 3;
    int lo = r * RNG;
    for (int i = threadIdx.x; i < RNG; i += 1024) {
        int node = lo + i;
        if (node < n) {
            cur[i] = rowptr[node] + pc[c * TOTR + node];
            dloc[i] = dinv[node];
        }
    }
    __syncthreads();
    int e0 = c * chunk, e1 = min(e0 + chunk, E);
    for (int e = e0 + threadIdx.x; e < e1; e += 1024) {
        int s = src[e], d = dst[e];
        unsigned int dr = (unsigned int)(d - lo);
        if (s != d && dr < RNG) {
            int pos = atomicAdd(&cur[dr], 1);
            csr[pos] = make_int2(s, __float_as_int(-dinv[s] * dloc[dr]));
        }
    }
}

// ---------------- CSR gather propagation, D=128 bf16, f32 accum ----------------
// 8-wide edge unroll (validated round 12).

__global__ void prop_kernel(const unsigned int* __restrict__ H, int hs,
                            const int* __restrict__ rowptr,
                            const int2* __restrict__ csr,
                            const unsigned int* __restrict__ add, int as_,
                            float scale, float coef,
                            unsigned int* __restrict__ out, int n) {
    int wib = threadIdx.x >> 6;
    int lane = threadIdx.x & 63;
    int node = blockIdx.x * (blockDim.x >> 6) + wib;
    if (node >= n) return;

    float ax = 0.0f, ay = 0.0f;
    int beg = rowptr[node], end = rowptr[node + 1];
    int i = beg;
    for (; i + 8 <= end; i += 8) {
        int2 e[8];
#pragma unroll
        for (int k = 0; k < 8; ++k) e[k] = csr[i + k];
        unsigned int u[8];
#pragma unroll
        for (int k = 0; k < 8; ++k) u[k] = H[(size_t)e[k].x * hs + lane];
#pragma unroll
        for (int k = 0; k < 8; ++k) {
            float wk = __int_as_float(e[k].y);
            ax += wk * bf_lo(u[k]);
            ay += wk * bf_hi(u[k]);
        }
    }
    for (; i + 2 <= end; i += 2) {
        int2 e0 = csr[i], e1 = csr[i + 1];
        unsigned int u0 = H[(size_t)e0.x * hs + lane];
        unsigned int u1 = H[(size_t)e1.x * hs + lane];
        float w0 = __int_as_float(e0.y), w1 = __int_as_float(e1.y);
        ax += w0 * bf_lo(u0) + w1 * bf_lo(u1);
        ay += w0 * bf_hi(u0) + w1 * bf_hi(u1);
    }
    if (i < end) {
        int2 e0 = csr[i];
        unsigned int u0 = H[(size_t)e0.x * hs + lane];
        float w0 = __int_as_float(e0.y);
        ax += w0 * bf_lo(u0);
        ay += w0 * bf_hi(u0);
    }

    float vx = scale * ax, vy = scale * ay;
    if (add) {
        unsigned int au = add[(size_t)node * as_ + lane];
        vx += coef * bf_lo(au);
        vy += coef * bf_hi(au);
    }
    out[(size_t)node * 64 + lane] = packbf(vx, vy);
}

// final prop + bias + LayerNorm + ReLU -> f32 out.  V stride 64, U0 stride 192.
__global__ void prop_ln_kernel(const unsigned int* __restrict__ V,
                               const int* __restrict__ rowptr,
                               const int2* __restrict__ csr,
                               const unsigned int* __restrict__ U0,
                               const float* __restrict__ b,
                               const float* __restrict__ g,
                               const float* __restrict__ bt,
                               float* __restrict__ out, int n) {
    int wib = threadIdx.x >> 6;
    int lane = threadIdx.x & 63;
    int node = blockIdx.x * (blockDim.x >> 6) + wib;
    if (node >= n) return;

    float ax = 0.0f, ay = 0.0f;
    int beg = rowptr[node], end = rowptr[node + 1];
    int i = beg;
    for (; i + 8 <= end; i += 8) {
        int2 e[8];
#pragma unroll
        for (int k = 0; k < 8; ++k) e[k] = csr[i + k];
        unsigned int u[8];
#pragma unroll
        for (int k = 0; k < 8; ++k) u[k] = V[(size_t)e[k].x * 64 + lane];
#pragma unroll
        for (int k = 0; k < 8; ++k) {
            float wk = __int_as_float(e[k].y);
            ax += wk * bf_lo(u[k]);
            ay += wk * bf_hi(u[k]);
        }
    }
    for (; i + 2 <= end; i += 2) {
        int2 e0 = csr[i], e1 = csr[i + 1];
        unsigned int u0 = V[(size_t)e0.x * 64 + lane];
        unsigned int u1 = V[(size_t)e1.x * 64 + lane];
        float w0 = __int_as_float(e0.y), w1 = __int_as_float(e1.y);
        ax += w0 * bf_lo(u0) + w1 * bf_lo(u1);
        ay += w0 * bf_hi(u0) + w1 * bf_hi(u1);
    }
    if (i < end) {
        int2 e0 = csr[i];
        unsigned int u0 = V[(size_t)e0.x * 64 + lane];
        float w0 = __int_as_float(e0.y);
        ax += w0 * bf_lo(u0);
        ay += w0 * bf_hi(u0);
    }

    unsigned int au = U0[(size_t)node * 192 + lane];
    float px = ax + bf_lo(au) + b[2 * lane];
    float py = ay + bf_hi(au) + b[2 * lane + 1];

    float s = px + py;
#pragma unroll
    for (int o = 1; o < 64; o <<= 1) s += __shfl_xor(s, o);
    float mu = s * (1.0f / 128.0f);
    float dx = px - mu, dy = py - mu;
    float q = dx * dx + dy * dy;
#pragma unroll
    for (int o = 1; o < 64; o <<= 1) q += __shfl_xor(q, o);
    float rs = rsqrtf(q * (1.0f / 128.0f) + 1e-5f);

    float yx = dx * rs * g[2 * lane] + bt[2 * lane];
    float yy = dy * rs * g[2 * lane + 1] + bt[2 * lane + 1];
    yx = yx > 0.0f ? yx : 0.0f;
    yy = yy > 0.0f ? yy : 0.0f;
    float2 o2 = make_float2(yx, yy);
    *reinterpret_cast<float2*>(out + (size_t)node * 128 + 2 * lane) = o2;
}

// ---------------- gemm1: [x|T1|T2] @ Bt1^T + b1 -> LN -> ReLU -> bf16 h1 ----------------
// 256 thr / 4 waves, BM=64 BN=256, single-buffer 2-barrier loop (the r4-r7
// structure that never failed), with BK=64: 6 iterations instead of 12.
// Rationale: __syncthreads() drains vmcnt(0) (compiler-emitted), so every
// barrier costs ~1 exposed load latency regardless of prefetching — r13's
// cross-barrier prefetch was structurally impossible (and failed). Halving
// the barrier count halves that fixed cost; 32 MFMA per iteration instead
// of 16. K-order unchanged -> bit-identical accumulation vs r12.
// Pad 72 shorts = 144 B (16B-aligned rows; bank stride 36 dwords -> free
// 2-way). LDS 50 KB -> 3 blocks/CU (same occupancy as r12).
// DO NOT re-attempt 512-thread blocks or cross-barrier prefetch (r9-r11,r13).

__global__ __launch_bounds__(256) void gemm1_ln_kernel(
        const unsigned short* __restrict__ A0, const unsigned short* __restrict__ A1,
        const unsigned short* __restrict__ A2, const unsigned short* __restrict__ Bt,
        const float* __restrict__ bias, const float* __restrict__ g,
        const float* __restrict__ bt, unsigned short* __restrict__ Hout, int N) {
    __shared__ __align__(16) unsigned short As[64][72];
    __shared__ __align__(16) unsigned short Bs[256][72];
    __shared__ float redS[4][64];
    __shared__ float redQ[4][64];

    int row0 = blockIdx.x * 64;
    int tid = threadIdx.x;
    int lane = tid & 63;
    int wave = tid >> 6;
    int wc = wave * 64;

    f32x4 acc[4][4];
#pragma unroll
    for (int i = 0; i < 4; ++i)
#pragma unroll
        for (int j = 0; j < 4; ++j) acc[i][j] = (f32x4)0.0f;

    int arow = tid >> 2;            // 0..63
    int ach = (tid & 3) * 16;       // 0,16,32,48 (shorts)
    int brow = tid >> 3;            // 0..31
    int bch = (tid & 7) * 8;        // 0..56 (shorts)
    int gra = min(row0 + arow, N - 1);   // clamp: OOB rows computed, never stored

    for (int ks = 0; ks < 6; ++ks) {
        int kg = ks * 64;                 // global K offset (0..320)
        int seg = kg >> 7;                // 0,0,1,1,2,2
        int kk = kg & 127;                // 0,64 within segment
        const unsigned short* Aseg = (seg == 0) ? A0 : (seg == 1 ? A1 : A2);
        // A tile: 64 rows x 64 shorts, 2 uint4 per thread
        *reinterpret_cast<uint4*>(&As[arow][ach]) =
            *reinterpret_cast<const uint4*>(Aseg + (size_t)gra * 128 + kk + ach);
        *reinterpret_cast<uint4*>(&As[arow][ach + 8]) =
            *reinterpret_cast<const uint4*>(Aseg + (size_t)gra * 128 + kk + ach + 8);
        // B tile: 256 rows x 64 shorts, 8 uint4 per thread (rows p*32+brow)
#pragma unroll
        for (int p = 0; p < 8; ++p) {
            int r = p * 32 + brow;
            *reinterpret_cast<uint4*>(&Bs[r][bch]) =
                *reinterpret_cast<const uint4*>(Bt + (size_t)r * 384 + kg + bch);
        }
        __syncthreads();

        int fr = lane & 15;
        int kh = (lane >> 4) * 8;
        bf16x8 af[4], af2[4], bfr[4], bfr2[4];
#pragma unroll
        for (int i = 0; i < 4; ++i) {
            af[i]  = *reinterpret_cast<const bf16x8*>(&As[i * 16 + fr][kh]);
            af2[i] = *reinterpret_cast<const bf16x8*>(&As[i * 16 + fr][32 + kh]);
        }
#pragma unroll
        for (int j = 0; j < 4; ++j) {
            bfr[j]  = *reinterpret_cast<const bf16x8*>(&Bs[wc + j * 16 + fr][kh]);
            bfr2[j] = *reinterpret_cast<const bf16x8*>(&Bs[wc + j * 16 + fr][32 + kh]);
        }
#pragma unroll
        for (int i = 0; i < 4; ++i)
#pragma unroll
            for (int j = 0; j < 4; ++j) {
                acc[i][j] = __builtin_amdgcn_mfma_f32_16x16x32_bf16(af[i],  bfr[j],  acc[i][j], 0, 0, 0);
                acc[i][j] = __builtin_amdgcn_mfma_f32_16x16x32_bf16(af2[i], bfr2[j], acc[i][j], 0, 0, 0);
            }
        __syncthreads();
    }

    int fc = lane & 15;
    int fq = lane >> 4;
    float bcol[4], gcol[4], btcol[4];
#pragma unroll
    for (int j = 0; j < 4; ++j) {
        int c = wc + j * 16 + fc;
        bcol[j] = bias[c];
        gcol[j] = g[c];
        btcol[j] = bt[c];
    }
#pragma unroll
    for (int i = 0; i < 4; ++i)
#pragma unroll
        for (int j = 0; j < 4; ++j)
#pragma unroll
            for (int v = 0; v < 4; ++v) acc[i][j][v] += bcol[j];

#pragma unroll
    for (int i = 0; i < 4; ++i) {
#pragma unroll
        for (int v = 0; v < 4; ++v) {
            float s = 0.0f, q = 0.0f;
#pragma unroll
            for (int j = 0; j < 4; ++j) {
                float val = acc[i][j][v];
                s += val;
                q += val * val;
            }
#pragma unroll
            for (int o = 1; o < 16; o <<= 1) {
                s += __shfl_xor(s, o);
                q += __shfl_xor(q, o);
            }
            if (fc == 0) {
                int r = i * 16 + fq * 4 + v;
                redS[wave][r] = s;
                redQ[wave][r] = q;
            }
        }
    }
    __syncthreads();

#pragma unroll
    for (int i = 0; i < 4; ++i) {
#pragma unroll
        for (int v = 0; v < 4; ++v) {
            int r = i * 16 + fq * 4 + v;
            float S = redS[0][r] + redS[1][r] + redS[2][r] + redS[3][r];
            float Q = redQ[0][r] + redQ[1][r] + redQ[2][r] + redQ[3][r];
            float mu = S * (1.0f / 256.0f);
            float var = Q * (1.0f / 256.0f) - mu * mu;
            float rsg = rsqrtf(var + 1e-5f);
            int gr = row0 + r;
            if (gr < N) {
#pragma unroll
                for (int j = 0; j < 4; ++j) {
                    float y = (acc[i][j][v] - mu) * rsg * gcol[j] + btcol[j];
                    y = y > 0.0f ? y : 0.0f;
                    Hout[(size_t)gr * 256 + wc + j * 16 + fc] = f2bf(y);
                }
            }
        }
    }
}

// ---------------- gemm2: h1 @ Btc^T -> U [N][384] bf16 ----------------
// 256 thr / 4 waves, BM=64 BN=128, single-buffer 2-barrier, BK=64 (4 iters).
// LDS 27.6 KB -> 5 blocks/CU (20 waves/CU, up from r12's 3 blocks).

__global__ __launch_bounds__(256) void gemm2_kernel(
        const unsigned short* __restrict__ A, const unsigned short* __restrict__ Btc,
        unsigned short* __restrict__ U, int N, int ncol) {
    __shared__ __align__(16) unsigned short As[64][72];
    __shared__ __align__(16) unsigned short Bs[128][72];

    int nwg = gridDim.x;
    int q = nwg >> 3, r = nwg & 7;
    int xcd = blockIdx.x & 7, idx = blockIdx.x >> 3;
    int wgid = (xcd < r ? xcd * (q + 1) : r * (q + 1) + (xcd - r) * q) + idx;

    int row0 = (wgid / ncol) * 64;
    int col0 = (wgid % ncol) * 128;

    int tid = threadIdx.x;
    int lane = tid & 63;
    int wave = tid >> 6;
    int wc = wave * 32;

    f32x4 acc[4][2];
#pragma unroll
    for (int i = 0; i < 4; ++i)
#pragma unroll
        for (int j = 0; j < 2; ++j) acc[i][j] = (f32x4)0.0f;

    int arow = tid >> 2;            // 0..63
    int ach = (tid & 3) * 16;       // 0,16,32,48
    int brow = tid >> 3;            // 0..31
    int bch = (tid & 7) * 8;        // 0..56
    int gra = min(row0 + arow, N - 1);

    for (int ks = 0; ks < 4; ++ks) {
        int kg = ks * 64;
        *reinterpret_cast<uint4*>(&As[arow][ach]) =
            *reinterpret_cast<const uint4*>(A + (size_t)gra * 256 + kg + ach);
        *reinterpret_cast<uint4*>(&As[arow][ach + 8]) =
            *reinterpret_cast<const uint4*>(A + (size_t)gra * 256 + kg + ach + 8);
#pragma unroll
        for (int p = 0; p < 4; ++p) {
            int rr = p * 32 + brow;
            *reinterpret_cast<uint4*>(&Bs[rr][bch]) =
                *reinterpret_cast<const uint4*>(Btc + (size_t)(col0 + rr) * 256 + kg + bch);
        }
        __syncthreads();

        int fr = lane & 15;
        int kh = (lane >> 4) * 8;
        bf16x8 af[4], af2[4], bfr[2], bfr2[2];
#pragma unroll
        for (int i = 0; i < 4; ++i) {
            af[i]  = *reinterpret_cast<const bf16x8*>(&As[i * 16 + fr][kh]);
            af2[i] = *reinterpret_cast<const bf16x8*>(&As[i * 16 + fr][32 + kh]);
        }
#pragma unroll
        for (int j = 0; j < 2; ++j) {
            bfr[j]  = *reinterpret_cast<const bf16x8*>(&Bs[wc + j * 16 + fr][kh]);
            bfr2[j] = *reinterpret_cast<const bf16x8*>(&Bs[wc + j * 16 + fr][32 + kh]);
        }
#pragma unroll
        for (int i = 0; i < 4; ++i)
#pragma unroll
            for (int j = 0; j < 2; ++j) {
                acc[i][j] = __builtin_amdgcn_mfma_f32_16x16x32_bf16(af[i],  bfr[j],  acc[i][j], 0, 0, 0);
                acc[i][j] = __builtin_amdgcn_mfma_f32_16x16x32_bf16(af2[i], bfr2[j], acc[i][j], 0, 0, 0);
            }
        __syncthreads();
    }

    int fc = lane & 15;
    int frr = (lane >> 4) * 4;
#pragma unroll
    for (int i = 0; i < 4; ++i) {
#pragma unroll
        for (int v = 0; v < 4; ++v) {
            int gr = row0 + i * 16 + frr + v;
            if (gr < N) {
#pragma unroll
                for (int j = 0; j < 2; ++j) {
                    int gc = col0 + wc + j * 16 + fc;
                    U[(size_t)gr * 384 + gc] = f2bf(acc[i][j][v]);
                }
            }
        }
    }
}

// ---------------- host launch ----------------

extern "C" void kernel_launch(void* const* d_in, const int* in_sizes, int n_in,
                              void* d_out, int out_size, void* d_ws, size_t ws_size,
                              hipStream_t stream) {
    const int N = N_NODES;
    const float* x  = (const float*)d_in[0];
    const int*  ei  = (const int*)d_in[1];
    const float* W1 = (const float*)d_in[2];
    const float* b1 = (const float*)d_in[3];
    const float* g1 = (const float*)d_in[4];
    const float* bt1 = (const float*)d_in[5];
    const float* W2 = (const float*)d_in[6];
    const float* b2 = (const float*)d_in[7];
    const float* g2 = (const float*)d_in[8];
    const float* bt2 = (const float*)d_in[9];
    float* out = (float*)d_out;

    const int E = in_sizes[1] / 2;
    const int* src = ei;
    const int* dst = ei + E;
    const int chunk = (E + NCHUNK - 1) / NCHUNK;

    // workspace carve (256B aligned)
    char* w = (char*)d_ws;
    auto alloc = [&](size_t bytes) { char* p = w; w += (bytes + 255) & ~(size_t)255; return p; };
    int* pd      = (int*)alloc((size_t)NCHUNK * TOTR * 4);
    int* pc      = (int*)alloc((size_t)NCHUNK * TOTR * 4);
    int* cnt     = (int*)alloc((size_t)N * 4);
    int* excl    = (int*)alloc((size_t)N * 4);
    int* bsum    = (int*)alloc(64 * 4);
    int* rowptr  = (int*)alloc((size_t)(N + 1) * 4);
    int2* csr    = (int2*)alloc((size_t)E * 8);
    float* dinv  = (float*)alloc((size_t)N * 4);
    unsigned short* xb  = (unsigned short*)alloc((size_t)N * 128 * 2);
    unsigned short* T1  = (unsigned short*)alloc((size_t)N * 128 * 2);
    unsigned short* T2  = (unsigned short*)alloc((size_t)N * 128 * 2);
    unsigned short* h1b = (unsigned short*)alloc((size_t)N * 256 * 2);
    unsigned short* U   = (unsigned short*)alloc((size_t)N * 384 * 2);
    unsigned short* V   = (unsigned short*)alloc((size_t)N * 128 * 2);
    unsigned short* Bt1 = (unsigned short*)alloc((size_t)256 * 384 * 2);
    unsigned short* Btc = (unsigned short*)alloc((size_t)384 * 256 * 2);
    (void)ws_size;

    const int TPB = 256;
    const int NB = (N + 1023) / 1024;

    // --- preprocessing: privatized histograms + atomic-free CSR placement ---
    hipLaunchKernelGGL(hist_priv_kernel, dim3(NCHUNK * NRANGE), dim3(1024), 0, stream,
                       src, dst, E, chunk, pd, pc);
    hipLaunchKernelGGL(reduce_chunks_kernel, dim3((TOTR + TPB - 1) / TPB), dim3(TPB), 0, stream,
                       pd, pc, dinv, cnt, N);
    hipLaunchKernelGGL(scan1_kernel, dim3(NB), dim3(1024), 0, stream, cnt, excl, bsum, N);
    hipLaunchKernelGGL(scan2_kernel, dim3(1), dim3(64), 0, stream, bsum, NB);
    hipLaunchKernelGGL(scan3_kernel, dim3(NB), dim3(1024), 0, stream, excl, bsum, cnt, rowptr, N);
    hipLaunchKernelGGL(csr_place_kernel, dim3(NCHUNK * NRANGE), dim3(1024), 0, stream,
                       src, dst, E, chunk, pc, rowptr, dinv, csr, N);
    hipLaunchKernelGGL(cvt_bf_kernel, dim3((N * 128 / 4 + TPB - 1) / TPB), dim3(TPB), 0, stream,
                       x, xb, (size_t)N * 128 / 4);
    hipLaunchKernelGGL(wtrans1_kernel, dim3((3 * 128 * 256 + TPB - 1) / TPB), dim3(TPB), 0, stream, W1, Bt1);
    hipLaunchKernelGGL(wtrans2_kernel, dim3((384 * 256 + TPB - 1) / TPB), dim3(TPB), 0, stream, W2, Btc);

    const int gridW = (N + 3) / 4;   // 4 waves per block, 1 node per wave

    // --- layer 1: props (D=128) then GEMM+LN ---
    hipLaunchKernelGGL(prop_kernel, dim3(gridW), dim3(TPB), 0, stream,
                       (const unsigned int*)xb, 64, rowptr, csr,
                       (const unsigned int*)nullptr, 0, 1.0f, 0.0f,
                       (unsigned int*)T1, N);
    hipLaunchKernelGGL(prop_kernel, dim3(gridW), dim3(TPB), 0, stream,
                       (const unsigned int*)T1, 64, rowptr, csr,
                       (const unsigned int*)xb, 64, 2.0f, -1.0f,
                       (unsigned int*)T2, N);
    hipLaunchKernelGGL(gemm1_ln_kernel, dim3((N + 63) / 64), dim3(256), 0, stream,
                       xb, T1, T2, Bt1, b1, g1, bt1, h1b, N);

    // --- layer 2: GEMM first, then props in 128-dim ---
    {
        int nrow = (N + 63) / 64, ncol = 3;
        hipLaunchKernelGGL(gemm2_kernel, dim3(nrow * ncol), dim3(256), 0, stream,
                           h1b, Btc, U, N, ncol);
    }
    // v = L(u2) + u1
    hipLaunchKernelGGL(prop_kernel, dim3(gridW), dim3(TPB), 0, stream,
                       (const unsigned int*)U + 128, 192, rowptr, csr,
                       (const unsigned int*)U + 64, 192, 1.0f, 1.0f,
                       (unsigned int*)V, N);
    // out = LN(L(v) + u0 + b2) -> relu
    hipLaunchKernelGGL(prop_ln_kernel, dim3(gridW), dim3(TPB), 0, stream,
                       (const unsigned int*)V, rowptr, csr,
                       (const unsigned int*)U, b2, g2, bt2, out, N);
}